// Round 3
// baseline (4160.625 us; speedup 1.0000x reference)
//
#include <hip/hip_runtime.h>
#include <math.h>

// Problem dims
#define NB 256
#define DM 126       // D_MODEL
#define DE 128       // D_EMB
#define NH 6
#define DHd 21
#define DFF 2048
#define CIN 75
#define L0 128
#define NTOP 25

// PRNG variant: 0 = partitionable, low word (modern JAX default)
//               1 = partitionable, high word
//               2 = original (pair counts), low word
//               3 = original, high word
#ifndef IDX_MODE
#define IDX_MODE 0
#endif

typedef const float* fp;

__device__ __forceinline__ void tf2(unsigned k0, unsigned k1, unsigned x0, unsigned x1,
                                    unsigned &o0, unsigned &o1){
  unsigned ks2 = k0 ^ k1 ^ 0x1BD11BDAu;
  x0 += k0; x1 += k1;
  #define RR(r) { x0 += x1; x1 = (x1 << (r)) | (x1 >> (32 - (r))); x1 ^= x0; }
  RR(13) RR(15) RR(26) RR(6)
  x0 += k1;  x1 += ks2 + 1u;
  RR(17) RR(29) RR(16) RR(24)
  x0 += ks2; x1 += k0 + 2u;
  RR(13) RR(15) RR(26) RR(6)
  x0 += k0;  x1 += k1 + 3u;
  RR(17) RR(29) RR(16) RR(24)
  x0 += k1;  x1 += ks2 + 4u;
  RR(13) RR(15) RR(26) RR(6)
  x0 += ks2; x1 += k0 + 5u;
  #undef RR
  o0 = x0; o1 = x1;
}

// ---------------- fallback: zero output (ws too small diagnostic) ----------------
__global__ __launch_bounds__(256) void k_zero(float* out, int n){
  int i = blockIdx.x*256 + threadIdx.x;
  if (i < n) out[i] = 0.f;
}

// ---------------- idx precompute ----------------
__global__ __launch_bounds__(256) void k_idx(int* idx0, int* idx1){
  int tid = threadIdx.x;
  unsigned a0,a1,c0,c1;
  tf2(0u,42u, 0u,0u, a0,a1);   // fold_in(key(42), 0)
  tf2(0u,42u, 0u,1u, c0,c1);   // fold_in(key(42), 1)
  for (int f = tid; f < 3200; f += 256){
    unsigned y0,y1;
#if IDX_MODE==0
    tf2(a0,a1, 0u, (unsigned)(3200+f), y0,y1); idx0[f] = (int)(y1 & 127u);
#elif IDX_MODE==1
    tf2(a0,a1, 0u, (unsigned)(3200+f), y0,y1); idx0[f] = (int)(y0 & 127u);
#elif IDX_MODE==2
    tf2(a0,a1, (unsigned)f, (unsigned)(3200+f), y0,y1); idx0[f] = (int)(y1 & 127u);
#else
    tf2(a0,a1, (unsigned)f, (unsigned)(3200+f), y0,y1); idx0[f] = (int)(y0 & 127u);
#endif
  }
  for (int f = tid; f < 1600; f += 256){
    unsigned y0,y1;
#if IDX_MODE==0
    tf2(c0,c1, 0u, (unsigned)(1600+f), y0,y1); idx1[f] = (int)(y1 & 63u);
#elif IDX_MODE==1
    tf2(c0,c1, 0u, (unsigned)(1600+f), y0,y1); idx1[f] = (int)(y0 & 63u);
#elif IDX_MODE==2
    tf2(c0,c1, (unsigned)f, (unsigned)(1600+f), y0,y1); idx1[f] = (int)(y1 & 63u);
#else
    tf2(c0,c1, (unsigned)f, (unsigned)(1600+f), y0,y1); idx1[f] = (int)(y0 & 63u);
#endif
  }
}

// ---------------- token conv + pos + time embed, transposed out ----------------
// embT[b][e][l], e in [0,128), l in [0,128)
__global__ __launch_bounds__(128) void k_embT(fp x_enc, fp x_mark, fp token_w,
                                              fp time_w, fp time_b, float* embT){
  int b = blockIdx.x >> 7, l = blockIdx.x & 127, e = threadIdx.x;
  int lm = (l + 127) & 127, lp = (l + 1) & 127;
  const float* xr0 = x_enc + (size_t)(b*L0 + lm)*CIN;
  const float* xr1 = x_enc + (size_t)(b*L0 + l )*CIN;
  const float* xr2 = x_enc + (size_t)(b*L0 + lp)*CIN;
  const float* w   = token_w + (size_t)e*CIN*3;
  float acc = 0.f;
  for (int c = 0; c < CIN; c++){
    acc += xr0[c]*w[c*3+0] + xr1[c]*w[c*3+1] + xr2[c]*w[c*3+2];
  }
  int i = e >> 1;
  float div = expf((float)(2*i) * (-9.210340371976184f / 128.f));
  float ang = (float)l * div;
  float pe = (e & 1) ? cosf(ang) : sinf(ang);
  const float* mk = x_mark + (size_t)(b*L0 + l)*3;
  float tm = mk[0]*time_w[0*DE+e] + mk[1]*time_w[1*DE+e]
           + mk[2]*time_w[2*DE+e] + time_b[e];
  embT[((size_t)b*DE + e)*L0 + l] = acc + pe + tm;
}

// ---------------- per-batch attention scalars ----------------
__global__ __launch_bounds__(128) void k_scalars(const float* embT, fp fcw, fp bng, fp bnb,
                                                 fp chw, fp chb, fp filw, fp filb,
                                                 fp spw, fp spb, fp kerw, fp kerb,
                                                 float* ch, float* fil, float* sp, float* ker){
  __shared__ float gap[DE];
  __shared__ float a[16];
  int b = blockIdx.x, t = threadIdx.x;
  const float* row = embT + ((size_t)b*DE + t)*L0;
  float s = 0.f;
  for (int l = 0; l < L0; l++) s += row[l];
  gap[t] = s / (float)L0;
  __syncthreads();
  if (t < 16){
    float acc = 0.f;
    for (int e = 0; e < DE; e++) acc += gap[e]*fcw[e*16 + t];
    acc = acc * (bng[t] / sqrtf(1.f + 1e-5f)) + bnb[t];
    a[t] = fmaxf(acc, 0.f);
  }
  __syncthreads();
  float accc = 0.f, accf = 0.f;
  for (int c = 0; c < 16; c++){ accc += a[c]*chw[c*DE + t]; accf += a[c]*filw[c*DE + t]; }
  ch[b*DE + t]  = 1.f/(1.f + expf(-(accc + chb[t])));
  fil[b*DE + t] = 1.f/(1.f + expf(-(accf + filb[t])));
  if (t < 3){
    float acc = 0.f;
    for (int c = 0; c < 16; c++) acc += a[c]*spw[c*3 + t];
    sp[b*4 + t] = 1.f/(1.f + expf(-(acc + spb[t])));
  }
  if (t == 0){
    float v[4]; float mx = -1e30f;
    for (int n = 0; n < 4; n++){
      float acc = 0.f;
      for (int c = 0; c < 16; c++) acc += a[c]*kerw[c*4 + n];
      v[n] = acc + kerb[n]; mx = fmaxf(mx, v[n]);
    }
    float ss = 0.f;
    for (int n = 0; n < 4; n++){ v[n] = expf(v[n]-mx); ss += v[n]; }
    for (int n = 0; n < 4; n++) ker[b*4 + n] = v[n]/ss;
  }
}

// ---------------- ODConv ----------------
// out[b][o][t] (o in [0,128), t in [0,126))
__global__ __launch_bounds__(256) void k_odconv(const float* embT, fp odw,
                                                const float* ch, const float* fil,
                                                const float* sp, const float* ker, float* xout){
  __shared__ float xc[DE][66];      // 65 cols used
  __shared__ float W[4][DE*3];
  int b = blockIdx.x >> 1, half = blockIdx.x & 1;
  int tid = threadIdx.x;
  int c0 = half * 63;
  for (int p = tid; p < DE*65; p += 256){
    int i = p / 65, c = p % 65;
    xc[i][c] = embT[((size_t)b*DE + i)*L0 + (c0 + c)] * ch[b*DE + i];
  }
  float kr[4]; for (int n = 0; n < 4; n++) kr[n] = ker[b*4 + n];
  float spv[3]; for (int j = 0; j < 3; j++) spv[j] = sp[b*4 + j];
  int tq = tid & 63;       // local t (0..62 valid)
  int oq = tid >> 6;       // 0..3
  for (int obase = 0; obase < DE; obase += 4){
    __syncthreads();
    for (int p = tid; p < 4*DE*3; p += 256){
      int oo = p / (DE*3), q = p % (DE*3);
      int o = obase + oo;
      float acc = kr[0]*odw[o*384 + q] + kr[1]*odw[49152 + o*384 + q]
                + kr[2]*odw[98304 + o*384 + q] + kr[3]*odw[147456 + o*384 + q];
      W[oo][q] = acc * spv[q % 3];
    }
    __syncthreads();
    if (tq < 63){
      int t = c0 + tq;
      float acc = 0.f;
      const float* Wp = W[oq];
      for (int i = 0; i < DE; i++){
        acc += Wp[i*3+0]*xc[i][tq] + Wp[i*3+1]*xc[i][tq+1] + Wp[i*3+2]*xc[i][tq+2];
      }
      int o = obase + oq;
      xout[((size_t)b*DE + o)*DM + t] = fil[b*DE + o] * acc;
    }
  }
}

// ---------------- QKV projection ----------------
__global__ __launch_bounds__(128) void k_qkv(const float* xin, fp qw, fp qb, fp kw, fp kb,
                                             fp vw, fp vb, int layer, int L,
                                             float* Q, float* K, float* V){
  __shared__ float xr[DM];
  int b = blockIdx.x / L, l = blockIdx.x % L, t = threadIdx.x;
  const float* row = xin + ((size_t)b*L + l)*DM;
  if (t < DM) xr[t] = row[t];
  __syncthreads();
  if (t >= DM) return;
  const float* qwp = qw + (size_t)layer*DM*DM + t;
  const float* kwp = kw + (size_t)layer*DM*DM + t;
  const float* vwp = vw + (size_t)layer*DM*DM + t;
  float aq = 0.f, ak = 0.f, av = 0.f;
  for (int k2 = 0; k2 < DM; k2++){
    float xv = xr[k2];
    aq += xv * qwp[k2*DM];
    ak += xv * kwp[k2*DM];
    av += xv * vwp[k2*DM];
  }
  aq += qb[layer*DM + t]; ak += kb[layer*DM + t]; av += vb[layer*DM + t];
  int h = t / DHd, d = t % DHd;
  size_t off = (((size_t)b*NH + h)*L + l)*DHd + d;
  Q[off] = aq; K[off] = ak; V[off] = av;
}

// ---------------- fused sparse attention: meas + top-k + softmax-attn ----------------
// per (b,h): writes vmean[bh][21], posmap[bh][L0] (-1 or slot), upd[bh][25][21]
__global__ __launch_bounds__(128) void k_attn_fused(const float* Q, const float* K, const float* V,
                                                    const int* idx, int L,
                                                    float* vmean, int* posmap, float* upd){
  __shared__ float sQ[L0*DHd];
  __shared__ float sK[L0*DHd];
  __shared__ float sV[L0*DHd];
  __shared__ float qks[L0*NTOP];
  __shared__ float sM[L0];
  __shared__ float rv[L0];
  __shared__ int   ri[L0];
  __shared__ int   sel[L0];
  __shared__ int   stop[NTOP];
  __shared__ float red[128];
  int bh = blockIdx.x, t = threadIdx.x;
  const float* Qp = Q + (size_t)bh*L*DHd;
  const float* Kp = K + (size_t)bh*L*DHd;
  const float* Vp = V + (size_t)bh*L*DHd;
  for (int p = t; p < L*DHd; p += 128){ sQ[p] = Qp[p]; sK[p] = Kp[p]; sV[p] = Vp[p]; }
  posmap[bh*L0 + t] = -1;
  sel[t] = 0;
  __syncthreads();
  // V mean
  if (t < DHd){
    float s = 0.f;
    for (int l = 0; l < L; l++) s += sV[l*DHd + t];
    vmean[bh*DHd + t] = s / (float)L;
  }
  // sampled scores
  for (int p = t; p < L*NTOP; p += 128){
    int l = p / NTOP;
    int kk = idx[p];
    const float* q = sQ + l*DHd;
    const float* k = sK + kk*DHd;
    float acc = 0.f;
    for (int d = 0; d < DHd; d++) acc += q[d]*k[d];
    qks[p] = acc;
  }
  __syncthreads();
  if (t < L){
    float mx = -1e30f, sm = 0.f;
    for (int u = 0; u < NTOP; u++){ float v = qks[t*NTOP + u]; mx = fmaxf(mx, v); sm += v; }
    sM[t] = mx - sm / (float)L;
  } else {
    sM[t] = -1e30f;
  }
  __syncthreads();
  // top-k (set semantics, ties -> smaller index)
  for (int it = 0; it < NTOP; it++){
    rv[t] = sel[t] ? -1e30f : sM[t];
    ri[t] = t;
    __syncthreads();
    for (int off = 64; off > 0; off >>= 1){
      if (t < off){
        float v2 = rv[t+off]; int i2 = ri[t+off];
        if (v2 > rv[t] || (v2 == rv[t] && i2 < ri[t])){ rv[t] = v2; ri[t] = i2; }
      }
      __syncthreads();
    }
    if (t == 0){ int w = ri[0]; sel[w] = 1; stop[it] = w; posmap[bh*L0 + w] = it; }
    __syncthreads();
  }
  // full attention per selected row
  for (int u = 0; u < NTOP; u++){
    int ls = stop[u];
    float s = -1e30f;
    if (t < L){
      const float* q = sQ + ls*DHd;
      const float* k = sK + t*DHd;
      float acc = 0.f;
      for (int d = 0; d < DHd; d++) acc += q[d]*k[d];
      s = acc / 4.58257569479392f;   // sqrt(21)
    }
    red[t] = s;
    __syncthreads();
    for (int off = 64; off > 0; off >>= 1){ if (t < off) red[t] = fmaxf(red[t], red[t+off]); __syncthreads(); }
    float mx = red[0];
    __syncthreads();
    float e = (t < L) ? expf(s - mx) : 0.f;
    rv[t] = e; red[t] = e;
    __syncthreads();
    for (int off = 64; off > 0; off >>= 1){ if (t < off) red[t] += red[t+off]; __syncthreads(); }
    float denom = red[0];
    __syncthreads();
    if (t < DHd){
      float acc = 0.f;
      for (int k2 = 0; k2 < L; k2++) acc += rv[k2]*sV[k2*DHd + t];
      upd[((size_t)bh*NTOP + u)*DHd + t] = acc / denom;
    }
    __syncthreads();
  }
}

// ---------------- O-proj + residual + LN1 (gathers ctx from vmean/upd) ----------------
__global__ __launch_bounds__(128) void k_oproj_ln1(const float* xin, const float* vmean,
                                                   const int* posmap, const float* upd,
                                                   fp ow, fp ob, fp g, fp bb,
                                                   int layer, int L, float* xmid){
  __shared__ float cr[DM];
  __shared__ float red[128];
  int b = blockIdx.x / L, l = blockIdx.x % L, t = threadIdx.x;
  if (t < DM){
    int h = t / DHd, d = t % DHd;
    int bh = b*NH + h;
    int pos = posmap[bh*L0 + l];
    cr[t] = (pos >= 0) ? upd[((size_t)bh*NTOP + pos)*DHd + d] : vmean[bh*DHd + d];
  }
  __syncthreads();
  float v = 0.f;
  if (t < DM){
    const float* wp = ow + (size_t)layer*DM*DM + t;
    float acc = 0.f;
    for (int m = 0; m < DM; m++) acc += cr[m]*wp[m*DM];
    v = xin[((size_t)b*L + l)*DM + t] + acc + ob[layer*DM + t];
  }
  red[t] = (t < DM) ? v : 0.f;
  __syncthreads();
  for (int off = 64; off > 0; off >>= 1){ if (t < off) red[t] += red[t+off]; __syncthreads(); }
  float mean = red[0] / (float)DM;
  __syncthreads();
  float dv = (t < DM) ? (v - mean) : 0.f;
  red[t] = dv*dv;
  __syncthreads();
  for (int off = 64; off > 0; off >>= 1){ if (t < off) red[t] += red[t+off]; __syncthreads(); }
  float var = red[0] / (float)DM;
  if (t < DM){
    xmid[((size_t)b*L + l)*DM + t] =
        (v - mean)*rsqrtf(var + 1e-5f)*g[layer*DM + t] + bb[layer*DM + t];
  }
}

// ---------------- fused FFN + residual + LN2 (4 rows / block) ----------------
__device__ __forceinline__ float gelu_exact(float x){
  return 0.5f * x * (1.f + erff(x * 0.7071067811865475f));
}

__global__ __launch_bounds__(128) void k_ffn(const float* xmid, fp w1, fp b1, fp w2, fp b2w,
                                             fp g, fp bb, int layer, int L, float* xout){
  __shared__ float xr[4][DM];
  __shared__ float y[4][DFF];
  __shared__ float red[128];
  int r0 = blockIdx.x * 4;
  int t = threadIdx.x;
  for (int p = t; p < 4*DM; p += 128){
    int r = p / DM, c = p % DM;
    xr[r][c] = xmid[(size_t)(r0 + r)*DM + c];
  }
  __syncthreads();
  const float* w1p = w1 + (size_t)layer*DM*DFF;
  const float* b1p = b1 + (size_t)layer*DFF;
  for (int j = 0; j < DFF/128; j++){
    int f = t + j*128;
    float a0=0.f, a1=0.f, a2=0.f, a3=0.f;
    for (int k2 = 0; k2 < DM; k2++){
      float w = w1p[(size_t)k2*DFF + f];
      a0 += xr[0][k2]*w; a1 += xr[1][k2]*w; a2 += xr[2][k2]*w; a3 += xr[3][k2]*w;
    }
    float bv = b1p[f];
    y[0][f] = gelu_exact(a0 + bv);
    y[1][f] = gelu_exact(a1 + bv);
    y[2][f] = gelu_exact(a2 + bv);
    y[3][f] = gelu_exact(a3 + bv);
  }
  __syncthreads();
  float o0=0.f, o1=0.f, o2=0.f, o3=0.f;
  if (t < DM){
    const float* w2p = w2 + (size_t)layer*DFF*DM + t;
    for (int f = 0; f < DFF; f++){
      float w = w2p[(size_t)f*DM];
      o0 += y[0][f]*w; o1 += y[1][f]*w; o2 += y[2][f]*w; o3 += y[3][f]*w;
    }
    float bv = b2w[layer*DM + t];
    o0 += bv + xr[0][t]; o1 += bv + xr[1][t]; o2 += bv + xr[2][t]; o3 += bv + xr[3][t];
  }
  float gv = (t < DM) ? g[layer*DM + t] : 0.f;
  float bv2 = (t < DM) ? bb[layer*DM + t] : 0.f;
  float ov[4] = {o0, o1, o2, o3};
  for (int r = 0; r < 4; r++){
    red[t] = (t < DM) ? ov[r] : 0.f;
    __syncthreads();
    for (int off = 64; off > 0; off >>= 1){ if (t < off) red[t] += red[t+off]; __syncthreads(); }
    float mean = red[0] / (float)DM;
    __syncthreads();
    float dv = (t < DM) ? (ov[r] - mean) : 0.f;
    red[t] = dv*dv;
    __syncthreads();
    for (int off = 64; off > 0; off >>= 1){ if (t < off) red[t] += red[t+off]; __syncthreads(); }
    float var = red[0] / (float)DM;
    __syncthreads();
    if (t < DM){
      xout[(size_t)(r0 + r)*DM + t] = (ov[r] - mean)*rsqrtf(var + 1e-5f)*gv + bv2;
    }
  }
}

// ---------------- distil: conv1d(wrap) + BN + ELU + maxpool(3,2,pad1) ----------------
__global__ __launch_bounds__(256) void k_distill(const float* xin, fp clw, fp clb,
                                                 fp bng, fp bnb, float* xout){
  __shared__ float xs[L0][DM];    // 64512 B
  int b = blockIdx.x, t = threadIdx.x;
  for (int p = t; p < L0*DM; p += 256){ xs[p/DM][p%DM] = xin[(size_t)b*L0*DM + p]; }
  __syncthreads();
  float bnscale = 1.f / sqrtf(1.f + 1e-5f);
  for (int p = t; p < DM*64; p += 256){
    int co = p / 64, j = p % 64;
    const float* wp = clw + (size_t)co*DM*3;
    float cb = clb[co];
    float gg = bng[co] * bnscale, bbv = bnb[co];
    float best = -1e30f;
    for (int dt = -1; dt <= 1; dt++){
      int tt = 2*j + dt;
      if (tt < 0 || tt >= L0) continue;
      int s0 = (tt + L0 - 1) & 127, s1 = tt, s2 = (tt + 1) & 127;
      float acc = 0.f;
      for (int ci = 0; ci < DM; ci++){
        acc += xs[s0][ci]*wp[ci*3+0] + xs[s1][ci]*wp[ci*3+1] + xs[s2][ci]*wp[ci*3+2];
      }
      float z = (acc + cb)*gg + bbv;
      z = (z > 0.f) ? z : expm1f(z);
      best = fmaxf(best, z);
    }
    xout[((size_t)b*64 + j)*DM + co] = best;
  }
}

// ---------------- final LN + fc ----------------
__global__ __launch_bounds__(128) void k_final(const float* xin, fp g, fp bb,
                                               fp fcw, fp fcb, float* out){
  __shared__ float xs[64][DM];
  __shared__ float mean_s[64], rstd_s[64];
  int b = blockIdx.x, t = threadIdx.x;
  for (int p = t; p < 64*DM; p += 128){ xs[p/DM][p%DM] = xin[(size_t)b*64*DM + p]; }
  __syncthreads();
  if (t < 64){
    float s = 0.f;
    for (int m = 0; m < DM; m++) s += xs[t][m];
    float mn = s / (float)DM;
    float v = 0.f;
    for (int m = 0; m < DM; m++){ float d = xs[t][m] - mn; v += d*d; }
    mean_s[t] = mn; rstd_s[t] = rsqrtf(v / (float)DM + 1e-5f);
  }
  __syncthreads();
  if (t < DM){
    float gv = g[t], bv = bb[t];
    float acc = fcb[0];
    for (int l = 0; l < 64; l++){
      float xn = (xs[l][t] - mean_s[l])*rstd_s[l]*gv + bv;
      acc += xn * fcw[l];
    }
    out[b*DM + t] = acc;
  }
}

// ---------------- host launcher ----------------
extern "C" void kernel_launch(void* const* d_in, const int* in_sizes, int n_in,
                              void* d_out, int out_size, void* d_ws, size_t ws_size,
                              hipStream_t stream) {
  fp x_enc   = (fp)d_in[0];
  fp x_mark  = (fp)d_in[1];
  fp token_w = (fp)d_in[2];
  fp time_w  = (fp)d_in[3];
  fp time_b  = (fp)d_in[4];
  fp od_fc_w = (fp)d_in[5];
  fp od_bn_g = (fp)d_in[6];
  fp od_bn_b = (fp)d_in[7];
  fp od_ch_w = (fp)d_in[8];
  fp od_ch_b = (fp)d_in[9];
  fp od_fil_w= (fp)d_in[10];
  fp od_fil_b= (fp)d_in[11];
  fp od_sp_w = (fp)d_in[12];
  fp od_sp_b = (fp)d_in[13];
  fp od_ker_w= (fp)d_in[14];
  fp od_ker_b= (fp)d_in[15];
  fp od_wt   = (fp)d_in[16];
  fp q_w = (fp)d_in[17]; fp q_b = (fp)d_in[18];
  fp k_w = (fp)d_in[19]; fp k_b = (fp)d_in[20];
  fp v_w = (fp)d_in[21]; fp v_b = (fp)d_in[22];
  fp o_w = (fp)d_in[23]; fp o_b = (fp)d_in[24];
  fp f1w = (fp)d_in[25]; fp f1b = (fp)d_in[26];
  fp f2w = (fp)d_in[27]; fp f2b = (fp)d_in[28];
  fp ln1g= (fp)d_in[29]; fp ln1b= (fp)d_in[30];
  fp ln2g= (fp)d_in[31]; fp ln2b= (fp)d_in[32];
  fp cl_w= (fp)d_in[33]; fp cl_b= (fp)d_in[34];
  fp clbg= (fp)d_in[35]; fp clbb= (fp)d_in[36];
  fp elng= (fp)d_in[37]; fp elnb= (fp)d_in[38];
  fp fc_w= (fp)d_in[39]; fp fc_b= (fp)d_in[40];

  // ---- workspace layout (floats) ----
  const size_t OFF_IDX0 = 0;                                  // 3200 int
  const size_t OFF_IDX1 = OFF_IDX0 + 3200;                    // 1600 int
  const size_t OFF_CH   = OFF_IDX1 + 1600;                    // NB*DE
  const size_t OFF_FIL  = OFF_CH  + (size_t)NB*DE;
  const size_t OFF_SP   = OFF_FIL + (size_t)NB*DE;            // NB*4
  const size_t OFF_KER  = OFF_SP  + (size_t)NB*4;             // NB*4
  const size_t OFF_VM   = OFF_KER + (size_t)NB*4;             // NB*NH*DHd
  const size_t OFF_POS  = OFF_VM  + (size_t)NB*NH*DHd;        // NB*NH*L0 int
  const size_t OFF_UPD  = OFF_POS + (size_t)NB*NH*L0;         // NB*NH*NTOP*DHd
  const size_t OFF_BIG  = (OFF_UPD + (size_t)NB*NH*NTOP*DHd + 255) & ~(size_t)255;
  const size_t SBUF     = (size_t)NB*DE*L0;                   // 4,194,304 floats
  const size_t TOTAL    = OFF_BIG + 4*SBUF;                   // ~17.9M floats = 71.5 MB

  if (ws_size < TOTAL*sizeof(float)){
    // diagnostic fallback: deterministic zero output (error would read 2.3125)
    hipLaunchKernelGGL(k_zero, dim3((out_size+255)/256), dim3(256), 0, stream,
                       (float*)d_out, out_size);
    return;
  }

  float* ws = (float*)d_ws;
  int* idx0 = (int*)(ws + OFF_IDX0);
  int* idx1 = (int*)(ws + OFF_IDX1);
  float* chv = ws + OFF_CH;
  float* filv= ws + OFF_FIL;
  float* spv = ws + OFF_SP;
  float* kerv= ws + OFF_KER;
  float* vme = ws + OFF_VM;
  int* posm  = (int*)(ws + OFF_POS);
  float* updb= ws + OFF_UPD;
  float* BA = ws + OFF_BIG;          // embT -> Q
  float* BB = BA + SBUF;             // x (both layers)
  float* BC = BB + SBUF;             // K -> xmid
  float* BD = BC + SBUF;             // V -> ffn_out

  hipLaunchKernelGGL(k_idx, dim3(1), dim3(256), 0, stream, idx0, idx1);
  hipLaunchKernelGGL(k_embT, dim3(NB*L0), dim3(128), 0, stream,
                     x_enc, x_mark, token_w, time_w, time_b, BA);
  hipLaunchKernelGGL(k_scalars, dim3(NB), dim3(128), 0, stream,
                     BA, od_fc_w, od_bn_g, od_bn_b, od_ch_w, od_ch_b, od_fil_w, od_fil_b,
                     od_sp_w, od_sp_b, od_ker_w, od_ker_b, chv, filv, spv, kerv);
  hipLaunchKernelGGL(k_odconv, dim3(NB*2), dim3(256), 0, stream,
                     BA, od_wt, chv, filv, spv, kerv, BB);

  // ----- layer 0 (L=128) -----
  hipLaunchKernelGGL(k_qkv, dim3(NB*L0), dim3(128), 0, stream,
                     BB, q_w, q_b, k_w, k_b, v_w, v_b, 0, L0, BA, BC, BD);
  hipLaunchKernelGGL(k_attn_fused, dim3(NB*NH), dim3(128), 0, stream,
                     BA, BC, BD, idx0, L0, vme, posm, updb);
  hipLaunchKernelGGL(k_oproj_ln1, dim3(NB*L0), dim3(128), 0, stream,
                     BB, vme, posm, updb, o_w, o_b, ln1g, ln1b, 0, L0, BC);
  hipLaunchKernelGGL(k_ffn, dim3(NB*L0/4), dim3(128), 0, stream,
                     BC, f1w, f1b, f2w, f2b, ln2g, ln2b, 0, L0, BD);

  // ----- distil -----
  hipLaunchKernelGGL(k_distill, dim3(NB), dim3(256), 0, stream, BD, cl_w, cl_b, clbg, clbb, BB);

  // ----- layer 1 (L=64) -----
  hipLaunchKernelGGL(k_qkv, dim3(NB*64), dim3(128), 0, stream,
                     BB, q_w, q_b, k_w, k_b, v_w, v_b, 1, 64, BA, BC, BD);
  hipLaunchKernelGGL(k_attn_fused, dim3(NB*NH), dim3(128), 0, stream,
                     BA, BC, BD, idx1, 64, vme, posm, updb);
  hipLaunchKernelGGL(k_oproj_ln1, dim3(NB*64), dim3(128), 0, stream,
                     BB, vme, posm, updb, o_w, o_b, ln1g, ln1b, 1, 64, BC);
  hipLaunchKernelGGL(k_ffn, dim3(NB*64/4), dim3(128), 0, stream,
                     BC, f1w, f1b, f2w, f2b, ln2g, ln2b, 1, 64, BD);

  hipLaunchKernelGGL(k_final, dim3(NB), dim3(128), 0, stream,
                     BD, elng, elnb, fc_w, fc_b, (float*)d_out);
  (void)in_sizes; (void)n_in; (void)out_size; (void)ws_size;
}

// Round 4
// 2762.817 us; speedup vs baseline: 1.5059x; 1.5059x over previous
//
#include <hip/hip_runtime.h>
#include <math.h>

// Problem dims
#define NB 256
#define DM 126       // D_MODEL
#define DE 128       // D_EMB
#define NH 6
#define DHd 21
#define DFF 2048
#define CIN 75
#define L0 128
#define NTOP 25

#ifndef IDX_MODE
#define IDX_MODE 0
#endif

typedef const float* fp;
typedef unsigned short u16;
typedef short s8v __attribute__((ext_vector_type(8)));
typedef float f4v __attribute__((ext_vector_type(4)));

__device__ __forceinline__ u16 f2bf(float x){
  unsigned u = __float_as_uint(x);
  unsigned r = (u + 0x7FFFu + ((u >> 16) & 1u)) >> 16;
  return (u16)r;
}

__device__ __forceinline__ void tf2(unsigned k0, unsigned k1, unsigned x0, unsigned x1,
                                    unsigned &o0, unsigned &o1){
  unsigned ks2 = k0 ^ k1 ^ 0x1BD11BDAu;
  x0 += k0; x1 += k1;
  #define RR(r) { x0 += x1; x1 = (x1 << (r)) | (x1 >> (32 - (r))); x1 ^= x0; }
  RR(13) RR(15) RR(26) RR(6)
  x0 += k1;  x1 += ks2 + 1u;
  RR(17) RR(29) RR(16) RR(24)
  x0 += ks2; x1 += k0 + 2u;
  RR(13) RR(15) RR(26) RR(6)
  x0 += k0;  x1 += k1 + 3u;
  RR(17) RR(29) RR(16) RR(24)
  x0 += k1;  x1 += ks2 + 4u;
  RR(13) RR(15) RR(26) RR(6)
  x0 += ks2; x1 += k0 + 5u;
  #undef RR
  o0 = x0; o1 = x1;
}

// ---------------- fallback: zero output (ws too small diagnostic) ----------------
__global__ __launch_bounds__(256) void k_zero(float* out, int n){
  int i = blockIdx.x*256 + threadIdx.x;
  if (i < n) out[i] = 0.f;
}

// ---------------- idx precompute ----------------
__global__ __launch_bounds__(256) void k_idx(int* idx0, int* idx1){
  int tid = threadIdx.x;
  unsigned a0,a1,c0,c1;
  tf2(0u,42u, 0u,0u, a0,a1);   // fold_in(key(42), 0)
  tf2(0u,42u, 0u,1u, c0,c1);   // fold_in(key(42), 1)
  for (int f = tid; f < 3200; f += 256){
    unsigned y0,y1;
#if IDX_MODE==0
    tf2(a0,a1, 0u, (unsigned)(3200+f), y0,y1); idx0[f] = (int)(y1 & 127u);
#elif IDX_MODE==1
    tf2(a0,a1, 0u, (unsigned)(3200+f), y0,y1); idx0[f] = (int)(y0 & 127u);
#elif IDX_MODE==2
    tf2(a0,a1, (unsigned)f, (unsigned)(3200+f), y0,y1); idx0[f] = (int)(y1 & 127u);
#else
    tf2(a0,a1, (unsigned)f, (unsigned)(3200+f), y0,y1); idx0[f] = (int)(y0 & 127u);
#endif
  }
  for (int f = tid; f < 1600; f += 256){
    unsigned y0,y1;
#if IDX_MODE==0
    tf2(c0,c1, 0u, (unsigned)(1600+f), y0,y1); idx1[f] = (int)(y1 & 63u);
#elif IDX_MODE==1
    tf2(c0,c1, 0u, (unsigned)(1600+f), y0,y1); idx1[f] = (int)(y0 & 63u);
#elif IDX_MODE==2
    tf2(c0,c1, (unsigned)f, (unsigned)(1600+f), y0,y1); idx1[f] = (int)(y1 & 63u);
#else
    tf2(c0,c1, (unsigned)f, (unsigned)(1600+f), y0,y1); idx1[f] = (int)(y0 & 63u);
#endif
  }
}

// ---------------- token conv + pos + time embed, transposed out ----------------
__global__ __launch_bounds__(128) void k_embT(fp x_enc, fp x_mark, fp token_w,
                                              fp time_w, fp time_b, float* embT){
  int b = blockIdx.x >> 7, l = blockIdx.x & 127, e = threadIdx.x;
  int lm = (l + 127) & 127, lp = (l + 1) & 127;
  const float* xr0 = x_enc + (size_t)(b*L0 + lm)*CIN;
  const float* xr1 = x_enc + (size_t)(b*L0 + l )*CIN;
  const float* xr2 = x_enc + (size_t)(b*L0 + lp)*CIN;
  const float* w   = token_w + (size_t)e*CIN*3;
  float acc = 0.f;
  for (int c = 0; c < CIN; c++){
    acc += xr0[c]*w[c*3+0] + xr1[c]*w[c*3+1] + xr2[c]*w[c*3+2];
  }
  int i = e >> 1;
  float div = expf((float)(2*i) * (-9.210340371976184f / 128.f));
  float ang = (float)l * div;
  float pe = (e & 1) ? cosf(ang) : sinf(ang);
  const float* mk = x_mark + (size_t)(b*L0 + l)*3;
  float tm = mk[0]*time_w[0*DE+e] + mk[1]*time_w[1*DE+e]
           + mk[2]*time_w[2*DE+e] + time_b[e];
  embT[((size_t)b*DE + e)*L0 + l] = acc + pe + tm;
}

// ---------------- per-batch attention scalars ----------------
__global__ __launch_bounds__(128) void k_scalars(const float* embT, fp fcw, fp bng, fp bnb,
                                                 fp chw, fp chb, fp filw, fp filb,
                                                 fp spw, fp spb, fp kerw, fp kerb,
                                                 float* ch, float* fil, float* sp, float* ker){
  __shared__ float gap[DE];
  __shared__ float a[16];
  int b = blockIdx.x, t = threadIdx.x;
  const float* row = embT + ((size_t)b*DE + t)*L0;
  float s = 0.f;
  for (int l = 0; l < L0; l++) s += row[l];
  gap[t] = s / (float)L0;
  __syncthreads();
  if (t < 16){
    float acc = 0.f;
    for (int e = 0; e < DE; e++) acc += gap[e]*fcw[e*16 + t];
    acc = acc * (bng[t] / sqrtf(1.f + 1e-5f)) + bnb[t];
    a[t] = fmaxf(acc, 0.f);
  }
  __syncthreads();
  float accc = 0.f, accf = 0.f;
  for (int c = 0; c < 16; c++){ accc += a[c]*chw[c*DE + t]; accf += a[c]*filw[c*DE + t]; }
  ch[b*DE + t]  = 1.f/(1.f + expf(-(accc + chb[t])));
  fil[b*DE + t] = 1.f/(1.f + expf(-(accf + filb[t])));
  if (t < 3){
    float acc = 0.f;
    for (int c = 0; c < 16; c++) acc += a[c]*spw[c*3 + t];
    sp[b*4 + t] = 1.f/(1.f + expf(-(acc + spb[t])));
  }
  if (t == 0){
    float v[4]; float mx = -1e30f;
    for (int n = 0; n < 4; n++){
      float acc = 0.f;
      for (int c = 0; c < 16; c++) acc += a[c]*kerw[c*4 + n];
      v[n] = acc + kerb[n]; mx = fmaxf(mx, v[n]);
    }
    float ss = 0.f;
    for (int n = 0; n < 4; n++){ v[n] = expf(v[n]-mx); ss += v[n]; }
    for (int n = 0; n < 4; n++) ker[b*4 + n] = v[n]/ss;
  }
}

// ---------------- ODConv ----------------
__global__ __launch_bounds__(256) void k_odconv(const float* embT, fp odw,
                                                const float* ch, const float* fil,
                                                const float* sp, const float* ker, float* xout){
  __shared__ float xc[DE][66];
  __shared__ float W[4][DE*3];
  int b = blockIdx.x >> 1, half = blockIdx.x & 1;
  int tid = threadIdx.x;
  int c0 = half * 63;
  for (int p = tid; p < DE*65; p += 256){
    int i = p / 65, c = p % 65;
    xc[i][c] = embT[((size_t)b*DE + i)*L0 + (c0 + c)] * ch[b*DE + i];
  }
  float kr[4]; for (int n = 0; n < 4; n++) kr[n] = ker[b*4 + n];
  float spv[3]; for (int j = 0; j < 3; j++) spv[j] = sp[b*4 + j];
  int tq = tid & 63;
  int oq = tid >> 6;
  for (int obase = 0; obase < DE; obase += 4){
    __syncthreads();
    for (int p = tid; p < 4*DE*3; p += 256){
      int oo = p / (DE*3), q = p % (DE*3);
      int o = obase + oo;
      float acc = kr[0]*odw[o*384 + q] + kr[1]*odw[49152 + o*384 + q]
                + kr[2]*odw[98304 + o*384 + q] + kr[3]*odw[147456 + o*384 + q];
      W[oo][q] = acc * spv[q % 3];
    }
    __syncthreads();
    if (tq < 63){
      int t = c0 + tq;
      float acc = 0.f;
      const float* Wp = W[oq];
      for (int i = 0; i < DE; i++){
        acc += Wp[i*3+0]*xc[i][tq] + Wp[i*3+1]*xc[i][tq+1] + Wp[i*3+2]*xc[i][tq+2];
      }
      int o = obase + oq;
      xout[((size_t)b*DE + o)*DM + t] = fil[b*DE + o] * acc;
    }
  }
}

// ---------------- QKV projection ----------------
__global__ __launch_bounds__(128) void k_qkv(const float* xin, fp qw, fp qb, fp kw, fp kb,
                                             fp vw, fp vb, int layer, int L,
                                             float* Q, float* K, float* V){
  __shared__ float xr[DM];
  int b = blockIdx.x / L, l = blockIdx.x % L, t = threadIdx.x;
  const float* row = xin + ((size_t)b*L + l)*DM;
  if (t < DM) xr[t] = row[t];
  __syncthreads();
  if (t >= DM) return;
  const float* qwp = qw + (size_t)layer*DM*DM + t;
  const float* kwp = kw + (size_t)layer*DM*DM + t;
  const float* vwp = vw + (size_t)layer*DM*DM + t;
  float aq = 0.f, ak = 0.f, av = 0.f;
  for (int k2 = 0; k2 < DM; k2++){
    float xv = xr[k2];
    aq += xv * qwp[k2*DM];
    ak += xv * kwp[k2*DM];
    av += xv * vwp[k2*DM];
  }
  aq += qb[layer*DM + t]; ak += kb[layer*DM + t]; av += vb[layer*DM + t];
  int h = t / DHd, d = t % DHd;
  size_t off = (((size_t)b*NH + h)*L + l)*DHd + d;
  Q[off] = aq; K[off] = ak; V[off] = av;
}

// ---------------- fused sparse attention ----------------
__global__ __launch_bounds__(128) void k_attn_fused(const float* Q, const float* K, const float* V,
                                                    const int* idx, int L,
                                                    float* vmean, int* posmap, float* upd){
  __shared__ float sQ[L0*DHd];
  __shared__ float sK[L0*DHd];
  __shared__ float sV[L0*DHd];
  __shared__ float qks[L0*NTOP];
  __shared__ float sM[L0];
  __shared__ float rv[L0];
  __shared__ int   ri[L0];
  __shared__ int   sel[L0];
  __shared__ int   stop[NTOP];
  __shared__ float red[128];
  int bh = blockIdx.x, t = threadIdx.x;
  const float* Qp = Q + (size_t)bh*L*DHd;
  const float* Kp = K + (size_t)bh*L*DHd;
  const float* Vp = V + (size_t)bh*L*DHd;
  for (int p = t; p < L*DHd; p += 128){ sQ[p] = Qp[p]; sK[p] = Kp[p]; sV[p] = Vp[p]; }
  posmap[bh*L0 + t] = -1;
  sel[t] = 0;
  __syncthreads();
  if (t < DHd){
    float s = 0.f;
    for (int l = 0; l < L; l++) s += sV[l*DHd + t];
    vmean[bh*DHd + t] = s / (float)L;
  }
  for (int p = t; p < L*NTOP; p += 128){
    int l = p / NTOP;
    int kk = idx[p];
    const float* q = sQ + l*DHd;
    const float* k = sK + kk*DHd;
    float acc = 0.f;
    for (int d = 0; d < DHd; d++) acc += q[d]*k[d];
    qks[p] = acc;
  }
  __syncthreads();
  if (t < L){
    float mx = -1e30f, sm = 0.f;
    for (int u = 0; u < NTOP; u++){ float v = qks[t*NTOP + u]; mx = fmaxf(mx, v); sm += v; }
    sM[t] = mx - sm / (float)L;
  } else {
    sM[t] = -1e30f;
  }
  __syncthreads();
  for (int it = 0; it < NTOP; it++){
    rv[t] = sel[t] ? -1e30f : sM[t];
    ri[t] = t;
    __syncthreads();
    for (int off = 64; off > 0; off >>= 1){
      if (t < off){
        float v2 = rv[t+off]; int i2 = ri[t+off];
        if (v2 > rv[t] || (v2 == rv[t] && i2 < ri[t])){ rv[t] = v2; ri[t] = i2; }
      }
      __syncthreads();
    }
    if (t == 0){ int w = ri[0]; sel[w] = 1; stop[it] = w; posmap[bh*L0 + w] = it; }
    __syncthreads();
  }
  for (int u = 0; u < NTOP; u++){
    int ls = stop[u];
    float s = -1e30f;
    if (t < L){
      const float* q = sQ + ls*DHd;
      const float* k = sK + t*DHd;
      float acc = 0.f;
      for (int d = 0; d < DHd; d++) acc += q[d]*k[d];
      s = acc / 4.58257569479392f;   // sqrt(21)
    }
    red[t] = s;
    __syncthreads();
    for (int off = 64; off > 0; off >>= 1){ if (t < off) red[t] = fmaxf(red[t], red[t+off]); __syncthreads(); }
    float mx = red[0];
    __syncthreads();
    float e = (t < L) ? expf(s - mx) : 0.f;
    rv[t] = e; red[t] = e;
    __syncthreads();
    for (int off = 64; off > 0; off >>= 1){ if (t < off) red[t] += red[t+off]; __syncthreads(); }
    float denom = red[0];
    __syncthreads();
    if (t < DHd){
      float acc = 0.f;
      for (int k2 = 0; k2 < L; k2++) acc += rv[k2]*sV[k2*DHd + t];
      upd[((size_t)bh*NTOP + u)*DHd + t] = acc / denom;
    }
    __syncthreads();
  }
}

// ---------------- O-proj + residual + LN1 ----------------
__global__ __launch_bounds__(128) void k_oproj_ln1(const float* xin, const float* vmean,
                                                   const int* posmap, const float* upd,
                                                   fp ow, fp ob, fp g, fp bb,
                                                   int layer, int L, float* xmid){
  __shared__ float cr[DM];
  __shared__ float red[128];
  int b = blockIdx.x / L, l = blockIdx.x % L, t = threadIdx.x;
  if (t < DM){
    int h = t / DHd, d = t % DHd;
    int bh = b*NH + h;
    int pos = posmap[bh*L0 + l];
    cr[t] = (pos >= 0) ? upd[((size_t)bh*NTOP + pos)*DHd + d] : vmean[bh*DHd + d];
  }
  __syncthreads();
  float v = 0.f;
  if (t < DM){
    const float* wp = ow + (size_t)layer*DM*DM + t;
    float acc = 0.f;
    for (int m = 0; m < DM; m++) acc += cr[m]*wp[m*DM];
    v = xin[((size_t)b*L + l)*DM + t] + acc + ob[layer*DM + t];
  }
  red[t] = (t < DM) ? v : 0.f;
  __syncthreads();
  for (int off = 64; off > 0; off >>= 1){ if (t < off) red[t] += red[t+off]; __syncthreads(); }
  float mean = red[0] / (float)DM;
  __syncthreads();
  float dv = (t < DM) ? (v - mean) : 0.f;
  red[t] = dv*dv;
  __syncthreads();
  for (int off = 64; off > 0; off >>= 1){ if (t < off) red[t] += red[t+off]; __syncthreads(); }
  float var = red[0] / (float)DM;
  if (t < DM){
    xmid[((size_t)b*L + l)*DM + t] =
        (v - mean)*rsqrtf(var + 1e-5f)*g[layer*DM + t] + bb[layer*DM + t];
  }
}

// ---------------- weight convert: fp32 -> bf16, transposed, K/N padded ----------------
// w1t[n][k] (n<2048, k<128): = w1[layer][k][n], k>=126 -> 0
// w2t[n][f] (n<128, f<2048): = w2[layer][f][n], n>=126 -> 0
__global__ __launch_bounds__(256) void k_wconv(fp w1, fp w2, int layer, u16* w1t, u16* w2t){
  int i = blockIdx.x*256 + threadIdx.x;
  if (i < 2048*128){
    int n = i >> 7, k = i & 127;
    float v = (k < DM) ? w1[((size_t)layer*DM + k)*DFF + n] : 0.f;
    w1t[(size_t)n*128 + k] = f2bf(v);
  } else {
    int j = i - 2048*128;
    int n = j >> 11, f = j & 2047;
    float v = (n < DM) ? w2[((size_t)layer*DFF + f)*DM + n] : 0.f;
    w2t[(size_t)n*2048 + f] = f2bf(v);
  }
}

// GELU exact via Abramowitz-Stegun 7.1.26 erf (max err ~1.5e-7)
__device__ __forceinline__ float gelu_as(float x){
  float z  = 0.7071067811865475f * x;
  float zn = fabsf(z);
  float t  = 1.f / (1.f + 0.3275911f * zn);
  float p  = ((((1.061405429f*t - 1.453152027f)*t + 1.421413741f)*t - 0.284496736f)*t + 0.254829592f)*t;
  float ea = 1.f - p * __expf(-zn*zn);
  float er = (z < 0.f) ? -ea : ea;
  return 0.5f * x * (1.f + er);
}

// ---------------- MFMA FFN + residual + LN2 (64 rows / block, 4 waves) ----------------
__global__ __launch_bounds__(256) void k_ffn_mfma(const float* xmid, const u16* w1t, const u16* w2t,
                                                  fp b1, fp b2w, fp g, fp bb, int layer, float* xout){
  __shared__ __align__(16) u16 sXY[2*64*136];   // X then Y, row stride 136 bf16 (16B-aligned)
  __shared__ float prs[128];
  __shared__ float smean[64], srstd[64];
  u16* sX = sXY;
  u16* sY = sXY + 64*136;
  const int tid  = threadIdx.x;
  const int wave = tid >> 6, lane = tid & 63, quad = lane >> 4, l15 = lane & 15;
  const int m0 = wave * 16;
  const size_t rows0 = (size_t)blockIdx.x * 64;

  for (int p = tid; p < 64*128; p += 256){
    int r = p >> 7, c = p & 127;
    float v = (c < DM) ? xmid[(rows0 + r)*DM + c] : 0.f;
    sX[r*136 + c] = f2bf(v);
  }
  __syncthreads();

  const float* b1l = b1 + (size_t)layer*DFF;
  const f4v z4 = {0.f, 0.f, 0.f, 0.f};
  f4v acc2[8];
  #pragma unroll
  for (int t = 0; t < 8; t++) acc2[t] = z4;

  for (int ch = 0; ch < 16; ch++){
    const int f0 = ch * 128;
    f4v acc1[8];
    #pragma unroll
    for (int t = 0; t < 8; t++) acc1[t] = z4;
    #pragma unroll
    for (int ks = 0; ks < 4; ks++){
      s8v a = *reinterpret_cast<const s8v*>(sX + (m0 + l15)*136 + ks*32 + quad*8);
      const u16* wb = w1t + ((size_t)(f0 + l15))*128 + ks*32 + quad*8;
      #pragma unroll
      for (int t = 0; t < 8; t++){
        s8v b = *reinterpret_cast<const s8v*>(wb + (size_t)t*16*128);
        acc1[t] = __builtin_amdgcn_mfma_f32_16x16x32_bf16(a, b, acc1[t], 0, 0, 0);
      }
    }
    #pragma unroll
    for (int t = 0; t < 8; t++){
      float bv = b1l[f0 + t*16 + l15];
      #pragma unroll
      for (int r = 0; r < 4; r++){
        float v = gelu_as(acc1[t][r] + bv);
        sY[(m0 + quad*4 + r)*136 + t*16 + l15] = f2bf(v);   // wave-private rows: no barrier
      }
    }
    #pragma unroll
    for (int ks = 0; ks < 4; ks++){
      s8v a2 = *reinterpret_cast<const s8v*>(sY + (m0 + l15)*136 + ks*32 + quad*8);
      const u16* wb2 = w2t + (size_t)l15*2048 + f0 + ks*32 + quad*8;
      #pragma unroll
      for (int t = 0; t < 8; t++){
        s8v b = *reinterpret_cast<const s8v*>(wb2 + (size_t)t*16*2048);
        acc2[t] = __builtin_amdgcn_mfma_f32_16x16x32_bf16(a2, b, acc2[t], 0, 0, 0);
      }
    }
  }

  __syncthreads();                       // about to reuse sXY as fp32 out
  float* sO = reinterpret_cast<float*>(sXY);   // [64][129]
  #pragma unroll
  for (int t = 0; t < 8; t++){
    int col = t*16 + l15;
    #pragma unroll
    for (int r = 0; r < 4; r++){
      sO[(m0 + quad*4 + r)*129 + col] = acc2[t][r];
    }
  }
  __syncthreads();
  const float* b2l = b2w + (size_t)layer*DM;
  for (int p = tid; p < 64*DM; p += 256){
    int r = p / DM, c = p - r*DM;
    sO[r*129 + c] += b2l[c] + xmid[(rows0 + r)*DM + c];   // bias + fp32 residual
  }
  __syncthreads();
  if (tid < 128){
    int row = tid >> 1, half = tid & 1;
    float s = 0.f;
    for (int c = half*63; c < half*63 + 63; c++) s += sO[row*129 + c];
    prs[tid] = s;
  }
  __syncthreads();
  if (tid < 128 && (tid & 1) == 0) smean[tid>>1] = (prs[tid] + prs[tid+1]) / (float)DM;
  __syncthreads();
  if (tid < 128){
    int row = tid >> 1, half = tid & 1;
    float mn = smean[row];
    float s = 0.f;
    for (int c = half*63; c < half*63 + 63; c++){ float d = sO[row*129 + c] - mn; s += d*d; }
    prs[tid] = s;
  }
  __syncthreads();
  if (tid < 128 && (tid & 1) == 0) srstd[tid>>1] = rsqrtf((prs[tid] + prs[tid+1])/(float)DM + 1e-5f);
  __syncthreads();
  const float* gl = g  + (size_t)layer*DM;
  const float* bl = bb + (size_t)layer*DM;
  for (int p = tid; p < 64*DM; p += 256){
    int r = p / DM, c = p - r*DM;
    xout[(rows0 + r)*DM + c] = (sO[r*129 + c] - smean[r])*srstd[r]*gl[c] + bl[c];
  }
}

// ---------------- distil: conv1d(wrap) + BN + ELU + maxpool(3,2,pad1) ----------------
__global__ __launch_bounds__(256) void k_distill(const float* xin, fp clw, fp clb,
                                                 fp bng, fp bnb, float* xout){
  __shared__ float xs[L0][DM];
  int b = blockIdx.x, t = threadIdx.x;
  for (int p = t; p < L0*DM; p += 256){ xs[p/DM][p%DM] = xin[(size_t)b*L0*DM + p]; }
  __syncthreads();
  float bnscale = 1.f / sqrtf(1.f + 1e-5f);
  for (int p = t; p < DM*64; p += 256){
    int co = p / 64, j = p % 64;
    const float* wp = clw + (size_t)co*DM*3;
    float cb = clb[co];
    float gg = bng[co] * bnscale, bbv = bnb[co];
    float best = -1e30f;
    for (int dt = -1; dt <= 1; dt++){
      int tt = 2*j + dt;
      if (tt < 0 || tt >= L0) continue;
      int s0 = (tt + L0 - 1) & 127, s1 = tt, s2 = (tt + 1) & 127;
      float acc = 0.f;
      for (int ci = 0; ci < DM; ci++){
        acc += xs[s0][ci]*wp[ci*3+0] + xs[s1][ci]*wp[ci*3+1] + xs[s2][ci]*wp[ci*3+2];
      }
      float z = (acc + cb)*gg + bbv;
      z = (z > 0.f) ? z : expm1f(z);
      best = fmaxf(best, z);
    }
    xout[((size_t)b*64 + j)*DM + co] = best;
  }
}

// ---------------- final LN + fc ----------------
__global__ __launch_bounds__(128) void k_final(const float* xin, fp g, fp bb,
                                               fp fcw, fp fcb, float* out){
  __shared__ float xs[64][DM];
  __shared__ float mean_s[64], rstd_s[64];
  int b = blockIdx.x, t = threadIdx.x;
  for (int p = t; p < 64*DM; p += 128){ xs[p/DM][p%DM] = xin[(size_t)b*64*DM + p]; }
  __syncthreads();
  if (t < 64){
    float s = 0.f;
    for (int m = 0; m < DM; m++) s += xs[t][m];
    float mn = s / (float)DM;
    float v = 0.f;
    for (int m = 0; m < DM; m++){ float d = xs[t][m] - mn; v += d*d; }
    mean_s[t] = mn; rstd_s[t] = rsqrtf(v / (float)DM + 1e-5f);
  }
  __syncthreads();
  if (t < DM){
    float gv = g[t], bv = bb[t];
    float acc = fcb[0];
    for (int l = 0; l < 64; l++){
      float xn = (xs[l][t] - mean_s[l])*rstd_s[l]*gv + bv;
      acc += xn * fcw[l];
    }
    out[b*DM + t] = acc;
  }
}

// ---------------- host launcher ----------------
extern "C" void kernel_launch(void* const* d_in, const int* in_sizes, int n_in,
                              void* d_out, int out_size, void* d_ws, size_t ws_size,
                              hipStream_t stream) {
  fp x_enc   = (fp)d_in[0];
  fp x_mark  = (fp)d_in[1];
  fp token_w = (fp)d_in[2];
  fp time_w  = (fp)d_in[3];
  fp time_b  = (fp)d_in[4];
  fp od_fc_w = (fp)d_in[5];
  fp od_bn_g = (fp)d_in[6];
  fp od_bn_b = (fp)d_in[7];
  fp od_ch_w = (fp)d_in[8];
  fp od_ch_b = (fp)d_in[9];
  fp od_fil_w= (fp)d_in[10];
  fp od_fil_b= (fp)d_in[11];
  fp od_sp_w = (fp)d_in[12];
  fp od_sp_b = (fp)d_in[13];
  fp od_ker_w= (fp)d_in[14];
  fp od_ker_b= (fp)d_in[15];
  fp od_wt   = (fp)d_in[16];
  fp q_w = (fp)d_in[17]; fp q_b = (fp)d_in[18];
  fp k_w = (fp)d_in[19]; fp k_b = (fp)d_in[20];
  fp v_w = (fp)d_in[21]; fp v_b = (fp)d_in[22];
  fp o_w = (fp)d_in[23]; fp o_b = (fp)d_in[24];
  fp f1w = (fp)d_in[25]; fp f1b = (fp)d_in[26];
  fp f2w = (fp)d_in[27]; fp f2b = (fp)d_in[28];
  fp ln1g= (fp)d_in[29]; fp ln1b= (fp)d_in[30];
  fp ln2g= (fp)d_in[31]; fp ln2b= (fp)d_in[32];
  fp cl_w= (fp)d_in[33]; fp cl_b= (fp)d_in[34];
  fp clbg= (fp)d_in[35]; fp clbb= (fp)d_in[36];
  fp elng= (fp)d_in[37]; fp elnb= (fp)d_in[38];
  fp fc_w= (fp)d_in[39]; fp fc_b= (fp)d_in[40];

  // ---- workspace layout (floats) ----
  const size_t OFF_IDX0 = 0;
  const size_t OFF_IDX1 = OFF_IDX0 + 3200;
  const size_t OFF_CH   = OFF_IDX1 + 1600;
  const size_t OFF_FIL  = OFF_CH  + (size_t)NB*DE;
  const size_t OFF_SP   = OFF_FIL + (size_t)NB*DE;
  const size_t OFF_KER  = OFF_SP  + (size_t)NB*4;
  const size_t OFF_VM   = OFF_KER + (size_t)NB*4;
  const size_t OFF_POS  = OFF_VM  + (size_t)NB*NH*DHd;
  const size_t OFF_UPD  = OFF_POS + (size_t)NB*NH*L0;
  const size_t OFF_BIG  = (OFF_UPD + (size_t)NB*NH*NTOP*DHd + 255) & ~(size_t)255;
  const size_t SBUF     = (size_t)NB*DE*L0;
  const size_t TOTAL    = OFF_BIG + 4*SBUF;

  if (ws_size < TOTAL*sizeof(float)){
    hipLaunchKernelGGL(k_zero, dim3((out_size+255)/256), dim3(256), 0, stream,
                       (float*)d_out, out_size);
    return;
  }

  float* ws = (float*)d_ws;
  int* idx0 = (int*)(ws + OFF_IDX0);
  int* idx1 = (int*)(ws + OFF_IDX1);
  float* chv = ws + OFF_CH;
  float* filv= ws + OFF_FIL;
  float* spv = ws + OFF_SP;
  float* kerv= ws + OFF_KER;
  float* vme = ws + OFF_VM;
  int* posm  = (int*)(ws + OFF_POS);
  float* updb= ws + OFF_UPD;
  float* BA = ws + OFF_BIG;          // embT -> Q -> (bf16 FFN weights during k_ffn)
  float* BB = BA + SBUF;             // x (both layers)
  float* BC = BB + SBUF;             // K -> xmid
  float* BD = BC + SBUF;             // V -> ffn_out

  u16* w1tb = (u16*)BA;              // 2048*128 bf16
  u16* w2tb = w1tb + 2048*128;       // 128*2048 bf16  (total 1 MB inside BA, Q dead by then)

  hipLaunchKernelGGL(k_idx, dim3(1), dim3(256), 0, stream, idx0, idx1);
  hipLaunchKernelGGL(k_embT, dim3(NB*L0), dim3(128), 0, stream,
                     x_enc, x_mark, token_w, time_w, time_b, BA);
  hipLaunchKernelGGL(k_scalars, dim3(NB), dim3(128), 0, stream,
                     BA, od_fc_w, od_bn_g, od_bn_b, od_ch_w, od_ch_b, od_fil_w, od_fil_b,
                     od_sp_w, od_sp_b, od_ker_w, od_ker_b, chv, filv, spv, kerv);
  hipLaunchKernelGGL(k_odconv, dim3(NB*2), dim3(256), 0, stream,
                     BA, od_wt, chv, filv, spv, kerv, BB);

  // ----- layer 0 (L=128) -----
  hipLaunchKernelGGL(k_qkv, dim3(NB*L0), dim3(128), 0, stream,
                     BB, q_w, q_b, k_w, k_b, v_w, v_b, 0, L0, BA, BC, BD);
  hipLaunchKernelGGL(k_attn_fused, dim3(NB*NH), dim3(128), 0, stream,
                     BA, BC, BD, idx0, L0, vme, posm, updb);
  hipLaunchKernelGGL(k_oproj_ln1, dim3(NB*L0), dim3(128), 0, stream,
                     BB, vme, posm, updb, o_w, o_b, ln1g, ln1b, 0, L0, BC);
  hipLaunchKernelGGL(k_wconv, dim3(2048), dim3(256), 0, stream, f1w, f2w, 0, w1tb, w2tb);
  hipLaunchKernelGGL(k_ffn_mfma, dim3(NB*L0/64), dim3(256), 0, stream,
                     BC, w1tb, w2tb, f1b, f2b, ln2g, ln2b, 0, BD);

  // ----- distil -----
  hipLaunchKernelGGL(k_distill, dim3(NB), dim3(256), 0, stream, BD, cl_w, cl_b, clbg, clbb, BB);

  // ----- layer 1 (L=64) -----
  hipLaunchKernelGGL(k_qkv, dim3(NB*64), dim3(128), 0, stream,
                     BB, q_w, q_b, k_w, k_b, v_w, v_b, 1, 64, BA, BC, BD);
  hipLaunchKernelGGL(k_attn_fused, dim3(NB*NH), dim3(128), 0, stream,
                     BA, BC, BD, idx1, 64, vme, posm, updb);
  hipLaunchKernelGGL(k_oproj_ln1, dim3(NB*64), dim3(128), 0, stream,
                     BB, vme, posm, updb, o_w, o_b, ln1g, ln1b, 1, 64, BC);
  hipLaunchKernelGGL(k_wconv, dim3(2048), dim3(256), 0, stream, f1w, f2w, 1, w1tb, w2tb);
  hipLaunchKernelGGL(k_ffn_mfma, dim3(NB*64/64), dim3(256), 0, stream,
                     BC, w1tb, w2tb, f1b, f2b, ln2g, ln2b, 1, BD);

  hipLaunchKernelGGL(k_final, dim3(NB), dim3(128), 0, stream,
                     BD, elng, elnb, fc_w, fc_b, (float*)d_out);
  (void)in_sizes; (void)n_in; (void)out_size; (void)ws_size;
}

// Round 5
// 2043.089 us; speedup vs baseline: 2.0364x; 1.3523x over previous
//
#include <hip/hip_runtime.h>
#include <math.h>

// Problem dims
#define NB 256
#define DM 126       // D_MODEL
#define DE 128       // D_EMB
#define NH 6
#define DHd 21
#define DFF 2048
#define CIN 75
#define L0 128
#define NTOP 25

#ifndef IDX_MODE
#define IDX_MODE 0
#endif

typedef const float* fp;
typedef unsigned short u16;
typedef short s8v __attribute__((ext_vector_type(8)));
typedef float f4v __attribute__((ext_vector_type(4)));

__device__ __forceinline__ u16 f2bf(float x){
  unsigned u = __float_as_uint(x);
  unsigned r = (u + 0x7FFFu + ((u >> 16) & 1u)) >> 16;
  return (u16)r;
}

__device__ __forceinline__ void tf2(unsigned k0, unsigned k1, unsigned x0, unsigned x1,
                                    unsigned &o0, unsigned &o1){
  unsigned ks2 = k0 ^ k1 ^ 0x1BD11BDAu;
  x0 += k0; x1 += k1;
  #define RR(r) { x0 += x1; x1 = (x1 << (r)) | (x1 >> (32 - (r))); x1 ^= x0; }
  RR(13) RR(15) RR(26) RR(6)
  x0 += k1;  x1 += ks2 + 1u;
  RR(17) RR(29) RR(16) RR(24)
  x0 += ks2; x1 += k0 + 2u;
  RR(13) RR(15) RR(26) RR(6)
  x0 += k0;  x1 += k1 + 3u;
  RR(17) RR(29) RR(16) RR(24)
  x0 += k1;  x1 += ks2 + 4u;
  RR(13) RR(15) RR(26) RR(6)
  x0 += ks2; x1 += k0 + 5u;
  #undef RR
  o0 = x0; o1 = x1;
}

// ---------------- fallback: zero output (ws too small diagnostic) ----------------
__global__ __launch_bounds__(256) void k_zero(float* out, int n){
  int i = blockIdx.x*256 + threadIdx.x;
  if (i < n) out[i] = 0.f;
}

// ---------------- idx precompute ----------------
__global__ __launch_bounds__(256) void k_idx(int* idx0, int* idx1){
  int tid = threadIdx.x;
  unsigned a0,a1,c0,c1;
  tf2(0u,42u, 0u,0u, a0,a1);   // fold_in(key(42), 0)
  tf2(0u,42u, 0u,1u, c0,c1);   // fold_in(key(42), 1)
  for (int f = tid; f < 3200; f += 256){
    unsigned y0,y1;
#if IDX_MODE==0
    tf2(a0,a1, 0u, (unsigned)(3200+f), y0,y1); idx0[f] = (int)(y1 & 127u);
#elif IDX_MODE==1
    tf2(a0,a1, 0u, (unsigned)(3200+f), y0,y1); idx0[f] = (int)(y0 & 127u);
#elif IDX_MODE==2
    tf2(a0,a1, (unsigned)f, (unsigned)(3200+f), y0,y1); idx0[f] = (int)(y1 & 127u);
#else
    tf2(a0,a1, (unsigned)f, (unsigned)(3200+f), y0,y1); idx0[f] = (int)(y0 & 127u);
#endif
  }
  for (int f = tid; f < 1600; f += 256){
    unsigned y0,y1;
#if IDX_MODE==0
    tf2(c0,c1, 0u, (unsigned)(1600+f), y0,y1); idx1[f] = (int)(y1 & 63u);
#elif IDX_MODE==1
    tf2(c0,c1, 0u, (unsigned)(1600+f), y0,y1); idx1[f] = (int)(y0 & 63u);
#elif IDX_MODE==2
    tf2(c0,c1, (unsigned)f, (unsigned)(1600+f), y0,y1); idx1[f] = (int)(y1 & 63u);
#else
    tf2(c0,c1, (unsigned)f, (unsigned)(1600+f), y0,y1); idx1[f] = (int)(y0 & 63u);
#endif
  }
}

// ---------------- token conv + pos + time embed, transposed out ----------------
__global__ __launch_bounds__(128) void k_embT(fp x_enc, fp x_mark, fp token_w,
                                              fp time_w, fp time_b, float* embT){
  int b = blockIdx.x >> 7, l = blockIdx.x & 127, e = threadIdx.x;
  int lm = (l + 127) & 127, lp = (l + 1) & 127;
  const float* xr0 = x_enc + (size_t)(b*L0 + lm)*CIN;
  const float* xr1 = x_enc + (size_t)(b*L0 + l )*CIN;
  const float* xr2 = x_enc + (size_t)(b*L0 + lp)*CIN;
  const float* w   = token_w + (size_t)e*CIN*3;
  float acc = 0.f;
  for (int c = 0; c < CIN; c++){
    acc += xr0[c]*w[c*3+0] + xr1[c]*w[c*3+1] + xr2[c]*w[c*3+2];
  }
  int i = e >> 1;
  float div = expf((float)(2*i) * (-9.210340371976184f / 128.f));
  float ang = (float)l * div;
  float pe = (e & 1) ? cosf(ang) : sinf(ang);
  const float* mk = x_mark + (size_t)(b*L0 + l)*3;
  float tm = mk[0]*time_w[0*DE+e] + mk[1]*time_w[1*DE+e]
           + mk[2]*time_w[2*DE+e] + time_b[e];
  embT[((size_t)b*DE + e)*L0 + l] = acc + pe + tm;
}

// ---------------- per-batch attention scalars ----------------
__global__ __launch_bounds__(128) void k_scalars(const float* embT, fp fcw, fp bng, fp bnb,
                                                 fp chw, fp chb, fp filw, fp filb,
                                                 fp spw, fp spb, fp kerw, fp kerb,
                                                 float* ch, float* fil, float* sp, float* ker){
  __shared__ float gap[DE];
  __shared__ float a[16];
  int b = blockIdx.x, t = threadIdx.x;
  const float* row = embT + ((size_t)b*DE + t)*L0;
  float s = 0.f;
  for (int l = 0; l < L0; l++) s += row[l];
  gap[t] = s / (float)L0;
  __syncthreads();
  if (t < 16){
    float acc = 0.f;
    for (int e = 0; e < DE; e++) acc += gap[e]*fcw[e*16 + t];
    acc = acc * (bng[t] / sqrtf(1.f + 1e-5f)) + bnb[t];
    a[t] = fmaxf(acc, 0.f);
  }
  __syncthreads();
  float accc = 0.f, accf = 0.f;
  for (int c = 0; c < 16; c++){ accc += a[c]*chw[c*DE + t]; accf += a[c]*filw[c*DE + t]; }
  ch[b*DE + t]  = 1.f/(1.f + expf(-(accc + chb[t])));
  fil[b*DE + t] = 1.f/(1.f + expf(-(accf + filb[t])));
  if (t < 3){
    float acc = 0.f;
    for (int c = 0; c < 16; c++) acc += a[c]*spw[c*3 + t];
    sp[b*4 + t] = 1.f/(1.f + expf(-(acc + spb[t])));
  }
  if (t == 0){
    float v[4]; float mx = -1e30f;
    for (int n = 0; n < 4; n++){
      float acc = 0.f;
      for (int c = 0; c < 16; c++) acc += a[c]*kerw[c*4 + n];
      v[n] = acc + kerb[n]; mx = fmaxf(mx, v[n]);
    }
    float ss = 0.f;
    for (int n = 0; n < 4; n++){ v[n] = expf(v[n]-mx); ss += v[n]; }
    for (int n = 0; n < 4; n++) ker[b*4 + n] = v[n]/ss;
  }
}

// ---------------- ODConv ----------------
__global__ __launch_bounds__(256) void k_odconv(const float* embT, fp odw,
                                                const float* ch, const float* fil,
                                                const float* sp, const float* ker, float* xout){
  __shared__ float xc[DE][66];
  __shared__ float W[4][DE*3];
  int b = blockIdx.x >> 1, half = blockIdx.x & 1;
  int tid = threadIdx.x;
  int c0 = half * 63;
  for (int p = tid; p < DE*65; p += 256){
    int i = p / 65, c = p % 65;
    xc[i][c] = embT[((size_t)b*DE + i)*L0 + (c0 + c)] * ch[b*DE + i];
  }
  float kr[4]; for (int n = 0; n < 4; n++) kr[n] = ker[b*4 + n];
  float spv[3]; for (int j = 0; j < 3; j++) spv[j] = sp[b*4 + j];
  int tq = tid & 63;
  int oq = tid >> 6;
  for (int obase = 0; obase < DE; obase += 4){
    __syncthreads();
    for (int p = tid; p < 4*DE*3; p += 256){
      int oo = p / (DE*3), q = p % (DE*3);
      int o = obase + oo;
      float acc = kr[0]*odw[o*384 + q] + kr[1]*odw[49152 + o*384 + q]
                + kr[2]*odw[98304 + o*384 + q] + kr[3]*odw[147456 + o*384 + q];
      W[oo][q] = acc * spv[q % 3];
    }
    __syncthreads();
    if (tq < 63){
      int t = c0 + tq;
      float acc = 0.f;
      const float* Wp = W[oq];
      for (int i = 0; i < DE; i++){
        acc += Wp[i*3+0]*xc[i][tq] + Wp[i*3+1]*xc[i][tq+1] + Wp[i*3+2]*xc[i][tq+2];
      }
      int o = obase + oq;
      xout[((size_t)b*DE + o)*DM + t] = fil[b*DE + o] * acc;
    }
  }
}

// ---------------- QKV weights -> bf16 [n][k] + bias ----------------
__global__ __launch_bounds__(256) void k_wqkv(fp qw, fp qb, fp kw, fp kb, fp vw, fp vb,
                                              int layer, u16* wq, float* qbias){
  int i = blockIdx.x*256 + threadIdx.x;
  if (i < 384*128){
    int n = i >> 7, k = i & 127;
    int sec = n >> 7, nn = n & 127;
    const float* w = (sec == 0) ? qw : ((sec == 1) ? kw : vw);
    float v = (nn < DM && k < DM) ? w[((size_t)layer*DM + k)*DM + nn] : 0.f;
    wq[(size_t)n*128 + k] = f2bf(v);
  } else if (i < 384*128 + 384){
    int n = i - 384*128;
    int sec = n >> 7, nn = n & 127;
    const float* bp = (sec == 0) ? qb : ((sec == 1) ? kb : vb);
    qbias[n] = (nn < DM) ? bp[layer*DM + nn] : 0.f;
  }
}

// ---------------- fused QKV GEMM: qkv[M][384] = X[M][128] * Wqkv^T + bias ----------------
__global__ __launch_bounds__(256) void k_qkv_mfma(const float* xin, const u16* wqkv,
                                                  const float* qkvb, float* qkv){
  __shared__ __align__(16) u16 sX[64*136];
  const int tid = threadIdx.x;
  const int wave = tid >> 6, lane = tid & 63, quad = lane >> 4, l15 = lane & 15;
  const size_t rows0 = (size_t)blockIdx.x * 64;
  for (int p = tid; p < 64*128; p += 256){
    int r = p >> 7, c = p & 127;
    float v = (c < DM) ? xin[(rows0 + r)*DM + c] : 0.f;
    sX[r*136 + c] = f2bf(v);
  }
  __syncthreads();
  const f4v z4 = {0.f,0.f,0.f,0.f};
  f4v acc[24];
  #pragma unroll
  for (int t = 0; t < 24; t++) acc[t] = z4;
  const int m0 = wave * 16;
  #pragma unroll
  for (int ks = 0; ks < 4; ks++){
    s8v a = *reinterpret_cast<const s8v*>(sX + (m0 + l15)*136 + ks*32 + quad*8);
    const u16* wb = wqkv + (size_t)l15*128 + ks*32 + quad*8;
    #pragma unroll
    for (int t = 0; t < 24; t++){
      s8v b = *reinterpret_cast<const s8v*>(wb + (size_t)t*16*128);
      acc[t] = __builtin_amdgcn_mfma_f32_16x16x32_bf16(a, b, acc[t], 0, 0, 0);
    }
  }
  #pragma unroll
  for (int t = 0; t < 24; t++){
    int col = t*16 + l15;
    float bv = qkvb[col];
    #pragma unroll
    for (int r = 0; r < 4; r++){
      int row = m0 + quad*4 + r;
      qkv[(rows0 + row)*384 + col] = acc[t][r] + bv;
    }
  }
}

// ---------------- fused sparse attention (reads qkv[M][384] layout) ----------------
__global__ __launch_bounds__(128) void k_attn_fused(const float* qkv, const int* idx, int L,
                                                    float* vmean, int* posmap, float* upd){
  __shared__ float sQ[L0*DHd];
  __shared__ float sK[L0*DHd];
  __shared__ float sV[L0*DHd];
  __shared__ float qks[L0*NTOP];
  __shared__ float sM[L0];
  __shared__ float rv[L0];
  __shared__ int   ri[L0];
  __shared__ int   sel[L0];
  __shared__ int   stop[NTOP];
  __shared__ float red[128];
  int bh = blockIdx.x, t = threadIdx.x;
  int b = bh / NH, h = bh - b*NH;
  for (int p = t; p < L*DHd; p += 128){
    int l = p / DHd, d = p - l*DHd;
    const float* base = qkv + ((size_t)(b*L + l))*384 + h*DHd + d;
    sQ[p] = base[0]; sK[p] = base[128]; sV[p] = base[256];
  }
  posmap[bh*L0 + t] = -1;
  sel[t] = 0;
  __syncthreads();
  if (t < DHd){
    float s = 0.f;
    for (int l = 0; l < L; l++) s += sV[l*DHd + t];
    vmean[bh*DHd + t] = s / (float)L;
  }
  for (int p = t; p < L*NTOP; p += 128){
    int l = p / NTOP;
    int kk = idx[p];
    const float* q = sQ + l*DHd;
    const float* k = sK + kk*DHd;
    float acc = 0.f;
    for (int d = 0; d < DHd; d++) acc += q[d]*k[d];
    qks[p] = acc;
  }
  __syncthreads();
  if (t < L){
    float mx = -1e30f, sm = 0.f;
    for (int u = 0; u < NTOP; u++){ float v = qks[t*NTOP + u]; mx = fmaxf(mx, v); sm += v; }
    sM[t] = mx - sm / (float)L;
  } else {
    sM[t] = -1e30f;
  }
  __syncthreads();
  for (int it = 0; it < NTOP; it++){
    rv[t] = sel[t] ? -1e30f : sM[t];
    ri[t] = t;
    __syncthreads();
    for (int off = 64; off > 0; off >>= 1){
      if (t < off){
        float v2 = rv[t+off]; int i2 = ri[t+off];
        if (v2 > rv[t] || (v2 == rv[t] && i2 < ri[t])){ rv[t] = v2; ri[t] = i2; }
      }
      __syncthreads();
    }
    if (t == 0){ int w = ri[0]; sel[w] = 1; stop[it] = w; posmap[bh*L0 + w] = it; }
    __syncthreads();
  }
  for (int u = 0; u < NTOP; u++){
    int ls = stop[u];
    float s = -1e30f;
    if (t < L){
      const float* q = sQ + ls*DHd;
      const float* k = sK + t*DHd;
      float acc = 0.f;
      for (int d = 0; d < DHd; d++) acc += q[d]*k[d];
      s = acc / 4.58257569479392f;   // sqrt(21)
    }
    red[t] = s;
    __syncthreads();
    for (int off = 64; off > 0; off >>= 1){ if (t < off) red[t] = fmaxf(red[t], red[t+off]); __syncthreads(); }
    float mx = red[0];
    __syncthreads();
    float e = (t < L) ? expf(s - mx) : 0.f;
    rv[t] = e; red[t] = e;
    __syncthreads();
    for (int off = 64; off > 0; off >>= 1){ if (t < off) red[t] += red[t+off]; __syncthreads(); }
    float denom = red[0];
    __syncthreads();
    if (t < DHd){
      float acc = 0.f;
      for (int k2 = 0; k2 < L; k2++) acc += rv[k2]*sV[k2*DHd + t];
      upd[((size_t)bh*NTOP + u)*DHd + t] = acc / denom;
    }
    __syncthreads();
  }
}

// ---------------- O-proj + residual + LN1 ----------------
__global__ __launch_bounds__(128) void k_oproj_ln1(const float* xin, const float* vmean,
                                                   const int* posmap, const float* upd,
                                                   fp ow, fp ob, fp g, fp bb,
                                                   int layer, int L, float* xmid){
  __shared__ float cr[DM];
  __shared__ float red[128];
  int b = blockIdx.x / L, l = blockIdx.x % L, t = threadIdx.x;
  if (t < DM){
    int h = t / DHd, d = t % DHd;
    int bh = b*NH + h;
    int pos = posmap[bh*L0 + l];
    cr[t] = (pos >= 0) ? upd[((size_t)bh*NTOP + pos)*DHd + d] : vmean[bh*DHd + d];
  }
  __syncthreads();
  float v = 0.f;
  if (t < DM){
    const float* wp = ow + (size_t)layer*DM*DM + t;
    float acc = 0.f;
    for (int m = 0; m < DM; m++) acc += cr[m]*wp[m*DM];
    v = xin[((size_t)b*L + l)*DM + t] + acc + ob[layer*DM + t];
  }
  red[t] = (t < DM) ? v : 0.f;
  __syncthreads();
  for (int off = 64; off > 0; off >>= 1){ if (t < off) red[t] += red[t+off]; __syncthreads(); }
  float mean = red[0] / (float)DM;
  __syncthreads();
  float dv = (t < DM) ? (v - mean) : 0.f;
  red[t] = dv*dv;
  __syncthreads();
  for (int off = 64; off > 0; off >>= 1){ if (t < off) red[t] += red[t+off]; __syncthreads(); }
  float var = red[0] / (float)DM;
  if (t < DM){
    xmid[((size_t)b*L + l)*DM + t] =
        (v - mean)*rsqrtf(var + 1e-5f)*g[layer*DM + t] + bb[layer*DM + t];
  }
}

// ---------------- FFN weights conversion ----------------
__global__ __launch_bounds__(256) void k_wconv(fp w1, fp w2, int layer, u16* w1t, u16* w2t){
  int i = blockIdx.x*256 + threadIdx.x;
  if (i < 2048*128){
    int n = i >> 7, k = i & 127;
    float v = (k < DM) ? w1[((size_t)layer*DM + k)*DFF + n] : 0.f;
    w1t[(size_t)n*128 + k] = f2bf(v);
  } else {
    int j = i - 2048*128;
    int n = j >> 11, f = j & 2047;
    float v = (n < DM) ? w2[((size_t)layer*DFF + f)*DM + n] : 0.f;
    w2t[(size_t)n*2048 + f] = f2bf(v);
  }
}

// GELU exact via Abramowitz-Stegun 7.1.26 erf (max err ~1.5e-7)
__device__ __forceinline__ float gelu_as(float x){
  float z  = 0.7071067811865475f * x;
  float zn = fabsf(z);
  float t  = 1.f / (1.f + 0.3275911f * zn);
  float p  = ((((1.061405429f*t - 1.453152027f)*t + 1.421413741f)*t - 0.284496736f)*t + 0.254829592f)*t;
  float ea = 1.f - p * __expf(-zn*zn);
  float er = (z < 0.f) ? -ea : ea;
  return 0.5f * x * (1.f + er);
}

// ---------------- MFMA FFN + residual + LN2 (64 rows / block, 4 waves) ----------------
__global__ __launch_bounds__(256) void k_ffn_mfma(const float* xmid, const u16* w1t, const u16* w2t,
                                                  fp b1, fp b2w, fp g, fp bb, int layer, float* xout){
  __shared__ __align__(16) u16 sXY[2*64*136];
  __shared__ float prs[128];
  __shared__ float smean[64], srstd[64];
  u16* sX = sXY;
  u16* sY = sXY + 64*136;
  const int tid  = threadIdx.x;
  const int wave = tid >> 6, lane = tid & 63, quad = lane >> 4, l15 = lane & 15;
  const int m0 = wave * 16;
  const size_t rows0 = (size_t)blockIdx.x * 64;

  for (int p = tid; p < 64*128; p += 256){
    int r = p >> 7, c = p & 127;
    float v = (c < DM) ? xmid[(rows0 + r)*DM + c] : 0.f;
    sX[r*136 + c] = f2bf(v);
  }
  __syncthreads();

  const float* b1l = b1 + (size_t)layer*DFF;
  const f4v z4 = {0.f, 0.f, 0.f, 0.f};
  f4v acc2[8];
  #pragma unroll
  for (int t = 0; t < 8; t++) acc2[t] = z4;

  for (int ch = 0; ch < 16; ch++){
    const int f0 = ch * 128;
    f4v acc1[8];
    #pragma unroll
    for (int t = 0; t < 8; t++) acc1[t] = z4;
    #pragma unroll
    for (int ks = 0; ks < 4; ks++){
      s8v a = *reinterpret_cast<const s8v*>(sX + (m0 + l15)*136 + ks*32 + quad*8);
      const u16* wb = w1t + ((size_t)(f0 + l15))*128 + ks*32 + quad*8;
      #pragma unroll
      for (int t = 0; t < 8; t++){
        s8v b = *reinterpret_cast<const s8v*>(wb + (size_t)t*16*128);
        acc1[t] = __builtin_amdgcn_mfma_f32_16x16x32_bf16(a, b, acc1[t], 0, 0, 0);
      }
    }
    #pragma unroll
    for (int t = 0; t < 8; t++){
      float bv = b1l[f0 + t*16 + l15];
      #pragma unroll
      for (int r = 0; r < 4; r++){
        float v = gelu_as(acc1[t][r] + bv);
        sY[(m0 + quad*4 + r)*136 + t*16 + l15] = f2bf(v);
      }
    }
    #pragma unroll
    for (int ks = 0; ks < 4; ks++){
      s8v a2 = *reinterpret_cast<const s8v*>(sY + (m0 + l15)*136 + ks*32 + quad*8);
      const u16* wb2 = w2t + (size_t)l15*2048 + f0 + ks*32 + quad*8;
      #pragma unroll
      for (int t = 0; t < 8; t++){
        s8v b = *reinterpret_cast<const s8v*>(wb2 + (size_t)t*16*2048);
        acc2[t] = __builtin_amdgcn_mfma_f32_16x16x32_bf16(a2, b, acc2[t], 0, 0, 0);
      }
    }
  }

  __syncthreads();
  float* sO = reinterpret_cast<float*>(sXY);   // [64][129]
  #pragma unroll
  for (int t = 0; t < 8; t++){
    int col = t*16 + l15;
    #pragma unroll
    for (int r = 0; r < 4; r++){
      sO[(m0 + quad*4 + r)*129 + col] = acc2[t][r];
    }
  }
  __syncthreads();
  const float* b2l = b2w + (size_t)layer*DM;
  for (int p = tid; p < 64*DM; p += 256){
    int r = p / DM, c = p - r*DM;
    sO[r*129 + c] += b2l[c] + xmid[(rows0 + r)*DM + c];
  }
  __syncthreads();
  if (tid < 128){
    int row = tid >> 1, half = tid & 1;
    float s = 0.f;
    for (int c = half*63; c < half*63 + 63; c++) s += sO[row*129 + c];
    prs[tid] = s;
  }
  __syncthreads();
  if (tid < 128 && (tid & 1) == 0) smean[tid>>1] = (prs[tid] + prs[tid+1]) / (float)DM;
  __syncthreads();
  if (tid < 128){
    int row = tid >> 1, half = tid & 1;
    float mn = smean[row];
    float s = 0.f;
    for (int c = half*63; c < half*63 + 63; c++){ float d = sO[row*129 + c] - mn; s += d*d; }
    prs[tid] = s;
  }
  __syncthreads();
  if (tid < 128 && (tid & 1) == 0) srstd[tid>>1] = rsqrtf((prs[tid] + prs[tid+1])/(float)DM + 1e-5f);
  __syncthreads();
  const float* gl = g  + (size_t)layer*DM;
  const float* bl = bb + (size_t)layer*DM;
  for (int p = tid; p < 64*DM; p += 256){
    int r = p / DM, c = p - r*DM;
    xout[(rows0 + r)*DM + c] = (sO[r*129 + c] - smean[r])*srstd[r]*gl[c] + bl[c];
  }
}

// ---------------- distil weights -> bf16 [n=co][k=q*126+ci] ----------------
__global__ __launch_bounds__(256) void k_wdist(fp clw, u16* wd){
  int i = blockIdx.x*256 + threadIdx.x;
  if (i < 128*384){
    int n = i / 384, k = i - n*384;
    float v = 0.f;
    if (n < DM && k < 378){
      int q = k / 126, ci = k - q*126;
      v = clw[((size_t)n*DM + ci)*3 + q];
    }
    wd[i] = f2bf(v);
  }
}

// ---------------- MFMA distil: conv(K=378) + BN + ELU + maxpool ----------------
__global__ __launch_bounds__(256) void k_distill_mfma(const float* xin, const u16* wdist,
                                                      fp clb, fp bng, fp bnb, float* xout){
  __shared__ __align__(16) u16 sA[128*392];   // 100,352 B; reused as float zsh[128][130]
  const int tid = threadIdx.x;
  const int wave = tid >> 6, lane = tid & 63, quad = lane >> 4, l15 = lane & 15;
  const int b = blockIdx.x;
  // stage A: row tt, k = q*126+ci -> x[b][(tt-1+q) wrap][ci]
  for (int row = wave; row < 128; row += 4){
    #pragma unroll
    for (int e = 0; e < 6; e++){
      int kk = lane + e*64;
      float v = 0.f;
      if (kk < 378){
        int q = kk / 126, ci = kk - q*126;
        int sr = (row - 1 + q + 128) & 127;
        v = xin[((size_t)b*128 + sr)*DM + ci];
      }
      sA[row*392 + kk] = f2bf(v);
    }
  }
  __syncthreads();
  const f4v z4 = {0.f,0.f,0.f,0.f};
  f4v acc[2][8];
  #pragma unroll
  for (int m = 0; m < 2; m++)
    #pragma unroll
    for (int t = 0; t < 8; t++) acc[m][t] = z4;
  const int mBase = wave * 32;
  for (int ks = 0; ks < 12; ks++){
    s8v a0 = *reinterpret_cast<const s8v*>(sA + (mBase + l15)*392 + ks*32 + quad*8);
    s8v a1 = *reinterpret_cast<const s8v*>(sA + (mBase + 16 + l15)*392 + ks*32 + quad*8);
    const u16* wb = wdist + (size_t)l15*384 + ks*32 + quad*8;
    #pragma unroll
    for (int t = 0; t < 8; t++){
      s8v bfr = *reinterpret_cast<const s8v*>(wb + (size_t)t*16*384);
      acc[0][t] = __builtin_amdgcn_mfma_f32_16x16x32_bf16(a0, bfr, acc[0][t], 0, 0, 0);
      acc[1][t] = __builtin_amdgcn_mfma_f32_16x16x32_bf16(a1, bfr, acc[1][t], 0, 0, 0);
    }
  }
  __syncthreads();     // all waves done reading sA
  float* zsh = reinterpret_cast<float*>(sA);   // [128][130]
  const float bnscale = 1.f / sqrtf(1.f + 1e-5f);
  #pragma unroll
  for (int t = 0; t < 8; t++){
    int co = t*16 + l15;
    if (co < DM){
      float cb = clb[co];
      float gg = bng[co] * bnscale, bv = bnb[co];
      #pragma unroll
      for (int m = 0; m < 2; m++){
        #pragma unroll
        for (int r = 0; r < 4; r++){
          int row = mBase + m*16 + quad*4 + r;
          float z = (acc[m][t][r] + cb)*gg + bv;
          z = (z > 0.f) ? z : expm1f(z);
          zsh[row*130 + co] = z;
        }
      }
    }
  }
  __syncthreads();
  for (int p = tid; p < 64*DM; p += 256){
    int j = p / DM, co = p - j*DM;
    float best = zsh[(2*j)*130 + co];
    if (j > 0) best = fmaxf(best, zsh[(2*j - 1)*130 + co]);
    best = fmaxf(best, zsh[(2*j + 1)*130 + co]);
    xout[((size_t)b*64 + j)*DM + co] = best;
  }
}

// ---------------- final LN + fc ----------------
__global__ __launch_bounds__(128) void k_final(const float* xin, fp g, fp bb,
                                               fp fcw, fp fcb, float* out){
  __shared__ float xs[64][DM];
  __shared__ float mean_s[64], rstd_s[64];
  int b = blockIdx.x, t = threadIdx.x;
  for (int p = t; p < 64*DM; p += 128){ xs[p/DM][p%DM] = xin[(size_t)b*64*DM + p]; }
  __syncthreads();
  if (t < 64){
    float s = 0.f;
    for (int m = 0; m < DM; m++) s += xs[t][m];
    float mn = s / (float)DM;
    float v = 0.f;
    for (int m = 0; m < DM; m++){ float d = xs[t][m] - mn; v += d*d; }
    mean_s[t] = mn; rstd_s[t] = rsqrtf(v / (float)DM + 1e-5f);
  }
  __syncthreads();
  if (t < DM){
    float gv = g[t], bv = bb[t];
    float acc = fcb[0];
    for (int l = 0; l < 64; l++){
      float xn = (xs[l][t] - mean_s[l])*rstd_s[l]*gv + bv;
      acc += xn * fcw[l];
    }
    out[b*DM + t] = acc;
  }
}

// ---------------- host launcher ----------------
extern "C" void kernel_launch(void* const* d_in, const int* in_sizes, int n_in,
                              void* d_out, int out_size, void* d_ws, size_t ws_size,
                              hipStream_t stream) {
  fp x_enc   = (fp)d_in[0];
  fp x_mark  = (fp)d_in[1];
  fp token_w = (fp)d_in[2];
  fp time_w  = (fp)d_in[3];
  fp time_b  = (fp)d_in[4];
  fp od_fc_w = (fp)d_in[5];
  fp od_bn_g = (fp)d_in[6];
  fp od_bn_b = (fp)d_in[7];
  fp od_ch_w = (fp)d_in[8];
  fp od_ch_b = (fp)d_in[9];
  fp od_fil_w= (fp)d_in[10];
  fp od_fil_b= (fp)d_in[11];
  fp od_sp_w = (fp)d_in[12];
  fp od_sp_b = (fp)d_in[13];
  fp od_ker_w= (fp)d_in[14];
  fp od_ker_b= (fp)d_in[15];
  fp od_wt   = (fp)d_in[16];
  fp q_w = (fp)d_in[17]; fp q_b = (fp)d_in[18];
  fp k_w = (fp)d_in[19]; fp k_b = (fp)d_in[20];
  fp v_w = (fp)d_in[21]; fp v_b = (fp)d_in[22];
  fp o_w = (fp)d_in[23]; fp o_b = (fp)d_in[24];
  fp f1w = (fp)d_in[25]; fp f1b = (fp)d_in[26];
  fp f2w = (fp)d_in[27]; fp f2b = (fp)d_in[28];
  fp ln1g= (fp)d_in[29]; fp ln1b= (fp)d_in[30];
  fp ln2g= (fp)d_in[31]; fp ln2b= (fp)d_in[32];
  fp cl_w= (fp)d_in[33]; fp cl_b= (fp)d_in[34];
  fp clbg= (fp)d_in[35]; fp clbb= (fp)d_in[36];
  fp elng= (fp)d_in[37]; fp elnb= (fp)d_in[38];
  fp fc_w= (fp)d_in[39]; fp fc_b= (fp)d_in[40];

  // ---- workspace layout (float units) ----
  const size_t OFF_IDX0 = 0;
  const size_t OFF_IDX1 = OFF_IDX0 + 3200;
  const size_t OFF_CH   = OFF_IDX1 + 1600;
  const size_t OFF_FIL  = OFF_CH  + (size_t)NB*DE;
  const size_t OFF_SP   = OFF_FIL + (size_t)NB*DE;
  const size_t OFF_KER  = OFF_SP  + (size_t)NB*4;
  const size_t OFF_VM   = OFF_KER + (size_t)NB*4;
  const size_t OFF_POS  = OFF_VM  + (size_t)NB*NH*DHd;
  const size_t OFF_UPD  = OFF_POS + (size_t)NB*NH*L0;
  const size_t OFF_WTS  = (OFF_UPD + (size_t)NB*NH*NTOP*DHd + 255) & ~(size_t)255;
  // weights scratch (u16): w1t 262144, w2t 262144, wqkv 49152, wdist 49152, qkvbias 384 f32
  const size_t WTS_FLOATS = (262144 + 262144 + 49152 + 49152)/2 + 384;   // 311,680
  const size_t OFF_BIG  = (OFF_WTS + WTS_FLOATS + 255) & ~(size_t)255;
  const size_t SBUF     = (size_t)NB*DE*L0;        // 4,194,304 floats
  const size_t TOTAL    = OFF_BIG + 4*SBUF;        // ~72.8 MB

  if (ws_size < TOTAL*sizeof(float)){
    hipLaunchKernelGGL(k_zero, dim3((out_size+255)/256), dim3(256), 0, stream,
                       (float*)d_out, out_size);
    return;
  }

  float* ws = (float*)d_ws;
  int* idx0 = (int*)(ws + OFF_IDX0);
  int* idx1 = (int*)(ws + OFF_IDX1);
  float* chv = ws + OFF_CH;
  float* filv= ws + OFF_FIL;
  float* spv = ws + OFF_SP;
  float* kerv= ws + OFF_KER;
  float* vme = ws + OFF_VM;
  int* posm  = (int*)(ws + OFF_POS);
  float* updb= ws + OFF_UPD;
  u16* w1tb  = (u16*)(ws + OFF_WTS);
  u16* w2tb  = w1tb + 262144;
  u16* wqkvb = w2tb + 262144;
  u16* wdistb= wqkvb + 49152;
  float* qkvbias = (float*)(wdistb + 49152);

  float* X    = ws + OFF_BIG;          // x (odconv out; distil out)
  float* QKV  = X + SBUF;              // 3 SBUF: qkv[M][384]; aliases embT & xmid
  float* embT = QKV;                   // alias (dead before qkv gemm)
  float* xmid = QKV;                   // alias (written after attention consumed QKV)
  float* ffno = QKV + SBUF;            // ffn out (both layers)

  hipLaunchKernelGGL(k_idx, dim3(1), dim3(256), 0, stream, idx0, idx1);
  hipLaunchKernelGGL(k_embT, dim3(NB*L0), dim3(128), 0, stream,
                     x_enc, x_mark, token_w, time_w, time_b, embT);
  hipLaunchKernelGGL(k_scalars, dim3(NB), dim3(128), 0, stream,
                     embT, od_fc_w, od_bn_g, od_bn_b, od_ch_w, od_ch_b, od_fil_w, od_fil_b,
                     od_sp_w, od_sp_b, od_ker_w, od_ker_b, chv, filv, spv, kerv);
  hipLaunchKernelGGL(k_odconv, dim3(NB*2), dim3(256), 0, stream,
                     embT, od_wt, chv, filv, spv, kerv, X);
  hipLaunchKernelGGL(k_wdist, dim3(192), dim3(256), 0, stream, cl_w, wdistb);

  // ----- layer 0 (L=128) -----
  hipLaunchKernelGGL(k_wqkv, dim3(194), dim3(256), 0, stream,
                     q_w, q_b, k_w, k_b, v_w, v_b, 0, wqkvb, qkvbias);
  hipLaunchKernelGGL(k_qkv_mfma, dim3(NB*L0/64), dim3(256), 0, stream,
                     X, wqkvb, qkvbias, QKV);
  hipLaunchKernelGGL(k_attn_fused, dim3(NB*NH), dim3(128), 0, stream,
                     QKV, idx0, L0, vme, posm, updb);
  hipLaunchKernelGGL(k_oproj_ln1, dim3(NB*L0), dim3(128), 0, stream,
                     X, vme, posm, updb, o_w, o_b, ln1g, ln1b, 0, L0, xmid);
  hipLaunchKernelGGL(k_wconv, dim3(2048), dim3(256), 0, stream, f1w, f2w, 0, w1tb, w2tb);
  hipLaunchKernelGGL(k_ffn_mfma, dim3(NB*L0/64), dim3(256), 0, stream,
                     xmid, w1tb, w2tb, f1b, f2b, ln2g, ln2b, 0, ffno);

  // ----- distil -----
  hipLaunchKernelGGL(k_distill_mfma, dim3(NB), dim3(256), 0, stream,
                     ffno, wdistb, cl_b, clbg, clbb, X);

  // ----- layer 1 (L=64) -----
  hipLaunchKernelGGL(k_wqkv, dim3(194), dim3(256), 0, stream,
                     q_w, q_b, k_w, k_b, v_w, v_b, 1, wqkvb, qkvbias);
  hipLaunchKernelGGL(k_qkv_mfma, dim3(NB*64/64), dim3(256), 0, stream,
                     X, wqkvb, qkvbias, QKV);
  hipLaunchKernelGGL(k_attn_fused, dim3(NB*NH), dim3(128), 0, stream,
                     QKV, idx1, 64, vme, posm, updb);
  hipLaunchKernelGGL(k_oproj_ln1, dim3(NB*64), dim3(128), 0, stream,
                     X, vme, posm, updb, o_w, o_b, ln1g, ln1b, 1, 64, xmid);
  hipLaunchKernelGGL(k_wconv, dim3(2048), dim3(256), 0, stream, f1w, f2w, 1, w1tb, w2tb);
  hipLaunchKernelGGL(k_ffn_mfma, dim3(NB*64/64), dim3(256), 0, stream,
                     xmid, w1tb, w2tb, f1b, f2b, ln2g, ln2b, 1, ffno);

  hipLaunchKernelGGL(k_final, dim3(NB), dim3(128), 0, stream,
                     ffno, elng, elnb, fc_w, fc_b, (float*)d_out);
  (void)in_sizes; (void)n_in; (void)out_size; (void)ws_size;
}

// Round 6
// 1664.024 us; speedup vs baseline: 2.5003x; 1.2278x over previous
//
#include <hip/hip_runtime.h>
#include <math.h>

// Problem dims
#define NB 256
#define DM 126       // D_MODEL
#define DE 128       // D_EMB
#define NH 6
#define DHd 21
#define DFF 2048
#define CIN 75
#define L0 128
#define NTOP 25

#ifndef IDX_MODE
#define IDX_MODE 0
#endif

typedef const float* fp;
typedef unsigned short u16;
typedef short s8v __attribute__((ext_vector_type(8)));
typedef float f4v __attribute__((ext_vector_type(4)));

__device__ __forceinline__ u16 f2bf(float x){
  unsigned u = __float_as_uint(x);
  unsigned r = (u + 0x7FFFu + ((u >> 16) & 1u)) >> 16;
  return (u16)r;
}

__device__ __forceinline__ void tf2(unsigned k0, unsigned k1, unsigned x0, unsigned x1,
                                    unsigned &o0, unsigned &o1){
  unsigned ks2 = k0 ^ k1 ^ 0x1BD11BDAu;
  x0 += k0; x1 += k1;
  #define RR(r) { x0 += x1; x1 = (x1 << (r)) | (x1 >> (32 - (r))); x1 ^= x0; }
  RR(13) RR(15) RR(26) RR(6)
  x0 += k1;  x1 += ks2 + 1u;
  RR(17) RR(29) RR(16) RR(24)
  x0 += ks2; x1 += k0 + 2u;
  RR(13) RR(15) RR(26) RR(6)
  x0 += k0;  x1 += k1 + 3u;
  RR(17) RR(29) RR(16) RR(24)
  x0 += k1;  x1 += ks2 + 4u;
  RR(13) RR(15) RR(26) RR(6)
  x0 += ks2; x1 += k0 + 5u;
  #undef RR
  o0 = x0; o1 = x1;
}

// ---------------- fallback: zero output (ws too small diagnostic) ----------------
__global__ __launch_bounds__(256) void k_zero(float* out, int n){
  int i = blockIdx.x*256 + threadIdx.x;
  if (i < n) out[i] = 0.f;
}

// ---------------- idx precompute ----------------
__global__ __launch_bounds__(256) void k_idx(int* idx0, int* idx1){
  int tid = threadIdx.x;
  unsigned a0,a1,c0,c1;
  tf2(0u,42u, 0u,0u, a0,a1);
  tf2(0u,42u, 0u,1u, c0,c1);
  for (int f = tid; f < 3200; f += 256){
    unsigned y0,y1;
#if IDX_MODE==0
    tf2(a0,a1, 0u, (unsigned)(3200+f), y0,y1); idx0[f] = (int)(y1 & 127u);
#elif IDX_MODE==1
    tf2(a0,a1, 0u, (unsigned)(3200+f), y0,y1); idx0[f] = (int)(y0 & 127u);
#elif IDX_MODE==2
    tf2(a0,a1, (unsigned)f, (unsigned)(3200+f), y0,y1); idx0[f] = (int)(y1 & 127u);
#else
    tf2(a0,a1, (unsigned)f, (unsigned)(3200+f), y0,y1); idx0[f] = (int)(y0 & 127u);
#endif
  }
  for (int f = tid; f < 1600; f += 256){
    unsigned y0,y1;
#if IDX_MODE==0
    tf2(c0,c1, 0u, (unsigned)(1600+f), y0,y1); idx1[f] = (int)(y1 & 63u);
#elif IDX_MODE==1
    tf2(c0,c1, 0u, (unsigned)(1600+f), y0,y1); idx1[f] = (int)(y0 & 63u);
#elif IDX_MODE==2
    tf2(c0,c1, (unsigned)f, (unsigned)(1600+f), y0,y1); idx1[f] = (int)(y1 & 63u);
#else
    tf2(c0,c1, (unsigned)f, (unsigned)(1600+f), y0,y1); idx1[f] = (int)(y0 & 63u);
#endif
  }
}

// ---------------- token_w -> bf16 [n=e][k=q*75+c] (K padded to 256) ----------------
__global__ __launch_bounds__(256) void k_wemb(fp token_w, u16* we){
  int i = blockIdx.x*256 + threadIdx.x;
  if (i < 128*256){
    int n = i >> 8, k = i & 255;
    float v = 0.f;
    if (k < 225){
      int q = k / 75, c = k - q*75;
      v = token_w[(size_t)n*225 + c*3 + q];
    }
    we[i] = f2bf(v);
  }
}

// ---------------- MFMA token-embed: conv(K=225) + pos + time, out emb[b][l][e] ----------------
__global__ __launch_bounds__(256) void k_emb_mfma(fp x_enc, fp x_mark, const u16* wemb,
                                                  fp time_w, fp time_b, float* emb){
  __shared__ __align__(16) u16 sA[128*264];   // 67,584 B
  const int tid = threadIdx.x;
  const int wave = tid >> 6, lane = tid & 63, quad = lane >> 4, l15 = lane & 15;
  const int b = blockIdx.x;
  for (int p = tid; p < 128*256; p += 256){
    int kk = p & 255, row = p >> 8;
    float v = 0.f;
    if (kk < 225){
      int q = kk / 75, c = kk - q*75;
      int sr = (row - 1 + q + 128) & 127;
      v = x_enc[((size_t)b*L0 + sr)*CIN + c];
    }
    sA[row*264 + kk] = f2bf(v);
  }
  __syncthreads();
  const f4v z4 = {0.f,0.f,0.f,0.f};
  f4v acc[2][8];
  #pragma unroll
  for (int m = 0; m < 2; m++)
    #pragma unroll
    for (int t = 0; t < 8; t++) acc[m][t] = z4;
  const int mBase = wave * 32;
  for (int ks = 0; ks < 8; ks++){
    s8v a0 = *reinterpret_cast<const s8v*>(sA + (mBase + l15)*264 + ks*32 + quad*8);
    s8v a1 = *reinterpret_cast<const s8v*>(sA + (mBase + 16 + l15)*264 + ks*32 + quad*8);
    const u16* wb = wemb + (size_t)l15*256 + ks*32 + quad*8;
    #pragma unroll
    for (int t = 0; t < 8; t++){
      s8v bfr = *reinterpret_cast<const s8v*>(wb + (size_t)t*16*256);
      acc[0][t] = __builtin_amdgcn_mfma_f32_16x16x32_bf16(a0, bfr, acc[0][t], 0, 0, 0);
      acc[1][t] = __builtin_amdgcn_mfma_f32_16x16x32_bf16(a1, bfr, acc[1][t], 0, 0, 0);
    }
  }
  // epilogue: + pos embed (fp32) + time embed (fp32), coalesced store
  #pragma unroll
  for (int t = 0; t < 8; t++){
    int col = t*16 + l15;             // e
    int i2 = col >> 1;
    float div = __expf((float)(2*i2) * (-9.210340371976184f / 128.f));
    float tw0 = time_w[col], tw1 = time_w[128 + col], tw2 = time_w[256 + col];
    float tb = time_b[col];
    #pragma unroll
    for (int m = 0; m < 2; m++){
      #pragma unroll
      for (int r = 0; r < 4; r++){
        int row = mBase + m*16 + quad*4 + r;   // l
        float ang = (float)row * div;
        float pe = (col & 1) ? cosf(ang) : sinf(ang);
        const float* mk = x_mark + ((size_t)b*L0 + row)*3;
        float tm = mk[0]*tw0 + mk[1]*tw1 + mk[2]*tw2 + tb;
        emb[((size_t)b*L0 + row)*DE + col] = acc[m][t][r] + pe + tm;
      }
    }
  }
}

// ---------------- per-batch attention scalars (emb layout [b][l][e]) ----------------
__global__ __launch_bounds__(128) void k_scalars(const float* emb, fp fcw, fp bng, fp bnb,
                                                 fp chw, fp chb, fp filw, fp filb,
                                                 fp spw, fp spb, fp kerw, fp kerb,
                                                 float* ch, float* fil, float* sp, float* ker){
  __shared__ float gap[DE];
  __shared__ float a[16];
  int b = blockIdx.x, t = threadIdx.x;
  float s = 0.f;
  for (int l = 0; l < L0; l++) s += emb[((size_t)b*L0 + l)*DE + t];
  gap[t] = s / (float)L0;
  __syncthreads();
  if (t < 16){
    float acc = 0.f;
    for (int e = 0; e < DE; e++) acc += gap[e]*fcw[e*16 + t];
    acc = acc * (bng[t] / sqrtf(1.f + 1e-5f)) + bnb[t];
    a[t] = fmaxf(acc, 0.f);
  }
  __syncthreads();
  float accc = 0.f, accf = 0.f;
  for (int c = 0; c < 16; c++){ accc += a[c]*chw[c*DE + t]; accf += a[c]*filw[c*DE + t]; }
  ch[b*DE + t]  = 1.f/(1.f + expf(-(accc + chb[t])));
  fil[b*DE + t] = 1.f/(1.f + expf(-(accf + filb[t])));
  if (t < 3){
    float acc = 0.f;
    for (int c = 0; c < 16; c++) acc += a[c]*spw[c*3 + t];
    sp[b*4 + t] = 1.f/(1.f + expf(-(acc + spb[t])));
  }
  if (t == 0){
    float v[4]; float mx = -1e30f;
    for (int n = 0; n < 4; n++){
      float acc = 0.f;
      for (int c = 0; c < 16; c++) acc += a[c]*kerw[c*4 + n];
      v[n] = acc + kerb[n]; mx = fmaxf(mx, v[n]);
    }
    float ss = 0.f;
    for (int n = 0; n < 4; n++){ v[n] = expf(v[n]-mx); ss += v[n]; }
    for (int n = 0; n < 4; n++) ker[b*4 + n] = v[n]/ss;
  }
}

// ---------------- ODConv (emb layout [b][l][e]) ----------------
__global__ __launch_bounds__(256) void k_odconv(const float* emb, fp odw,
                                                const float* ch, const float* fil,
                                                const float* sp, const float* ker, float* xout){
  __shared__ float xc[DE][66];
  __shared__ float W[4][DE*3];
  int b = blockIdx.x >> 1, half = blockIdx.x & 1;
  int tid = threadIdx.x;
  int c0 = half * 63;
  for (int p = tid; p < DE*65; p += 256){
    int i = p & 127, c = p >> 7;        // coalesced in i
    xc[i][c] = emb[((size_t)b*L0 + (c0 + c))*DE + i] * ch[b*DE + i];
  }
  float kr[4]; for (int n = 0; n < 4; n++) kr[n] = ker[b*4 + n];
  float spv[3]; for (int j = 0; j < 3; j++) spv[j] = sp[b*4 + j];
  int tq = tid & 63;
  int oq = tid >> 6;
  for (int obase = 0; obase < DE; obase += 4){
    __syncthreads();
    for (int p = tid; p < 4*DE*3; p += 256){
      int oo = p / (DE*3), q = p % (DE*3);
      int o = obase + oo;
      float acc = kr[0]*odw[o*384 + q] + kr[1]*odw[49152 + o*384 + q]
                + kr[2]*odw[98304 + o*384 + q] + kr[3]*odw[147456 + o*384 + q];
      W[oo][q] = acc * spv[q % 3];
    }
    __syncthreads();
    if (tq < 63){
      int t = c0 + tq;
      float acc = 0.f;
      const float* Wp = W[oq];
      for (int i = 0; i < DE; i++){
        acc += Wp[i*3+0]*xc[i][tq] + Wp[i*3+1]*xc[i][tq+1] + Wp[i*3+2]*xc[i][tq+2];
      }
      int o = obase + oq;
      xout[((size_t)b*DE + o)*DM + t] = fil[b*DE + o] * acc;
    }
  }
}

// ---------------- QKV + O weights -> bf16 [n][k] + qkv bias ----------------
__global__ __launch_bounds__(256) void k_wqkv(fp qw, fp qb, fp kw, fp kb, fp vw, fp vb,
                                              fp ow, int layer, u16* wq, float* qbias, u16* wo){
  int i = blockIdx.x*256 + threadIdx.x;
  if (i < 384*128){
    int n = i >> 7, k = i & 127;
    int sec = n >> 7, nn = n & 127;
    const float* w = (sec == 0) ? qw : ((sec == 1) ? kw : vw);
    float v = (nn < DM && k < DM) ? w[((size_t)layer*DM + k)*DM + nn] : 0.f;
    wq[(size_t)n*128 + k] = f2bf(v);
  } else if (i < 384*128 + 384){
    int n = i - 384*128;
    int sec = n >> 7, nn = n & 127;
    const float* bp = (sec == 0) ? qb : ((sec == 1) ? kb : vb);
    qbias[n] = (nn < DM) ? bp[layer*DM + nn] : 0.f;
  } else if (i < 384*128 + 384 + 128*128){
    int j = i - (384*128 + 384);
    int n = j >> 7, k = j & 127;
    float v = (n < DM && k < DM) ? ow[(size_t)layer*DM*DM + k*DM + n] : 0.f;
    wo[(size_t)n*128 + k] = f2bf(v);
  }
}

// ---------------- fused QKV GEMM: qkv[M][384] ----------------
__global__ __launch_bounds__(256) void k_qkv_mfma(const float* xin, const u16* wqkv,
                                                  const float* qkvb, float* qkv){
  __shared__ __align__(16) u16 sX[64*136];
  const int tid = threadIdx.x;
  const int wave = tid >> 6, lane = tid & 63, quad = lane >> 4, l15 = lane & 15;
  const size_t rows0 = (size_t)blockIdx.x * 64;
  for (int p = tid; p < 64*128; p += 256){
    int r = p >> 7, c = p & 127;
    float v = (c < DM) ? xin[(rows0 + r)*DM + c] : 0.f;
    sX[r*136 + c] = f2bf(v);
  }
  __syncthreads();
  const f4v z4 = {0.f,0.f,0.f,0.f};
  f4v acc[24];
  #pragma unroll
  for (int t = 0; t < 24; t++) acc[t] = z4;
  const int m0 = wave * 16;
  #pragma unroll
  for (int ks = 0; ks < 4; ks++){
    s8v a = *reinterpret_cast<const s8v*>(sX + (m0 + l15)*136 + ks*32 + quad*8);
    const u16* wb = wqkv + (size_t)l15*128 + ks*32 + quad*8;
    #pragma unroll
    for (int t = 0; t < 24; t++){
      s8v b = *reinterpret_cast<const s8v*>(wb + (size_t)t*16*128);
      acc[t] = __builtin_amdgcn_mfma_f32_16x16x32_bf16(a, b, acc[t], 0, 0, 0);
    }
  }
  #pragma unroll
  for (int t = 0; t < 24; t++){
    int col = t*16 + l15;
    float bv = qkvb[col];
    #pragma unroll
    for (int r = 0; r < 4; r++){
      int row = m0 + quad*4 + r;
      qkv[(rows0 + row)*384 + col] = acc[t][r] + bv;
    }
  }
}

// ---------------- fused sparse attention (reads qkv[M][384]) ----------------
__global__ __launch_bounds__(128) void k_attn_fused(const float* qkv, const int* idx, int L,
                                                    float* vmean, int* posmap, float* upd){
  __shared__ float sQ[L0*DHd];
  __shared__ float sK[L0*DHd];
  __shared__ float sV[L0*DHd];
  __shared__ float qks[L0*NTOP];
  __shared__ float sM[L0];
  __shared__ float rv[L0];
  __shared__ int   ri[L0];
  __shared__ int   sel[L0];
  __shared__ int   stop[NTOP];
  __shared__ float red[128];
  int bh = blockIdx.x, t = threadIdx.x;
  int b = bh / NH, h = bh - b*NH;
  for (int p = t; p < L*DHd; p += 128){
    int l = p / DHd, d = p - l*DHd;
    const float* base = qkv + ((size_t)(b*L + l))*384 + h*DHd + d;
    sQ[p] = base[0]; sK[p] = base[128]; sV[p] = base[256];
  }
  posmap[bh*L0 + t] = -1;
  sel[t] = 0;
  __syncthreads();
  if (t < DHd){
    float s = 0.f;
    for (int l = 0; l < L; l++) s += sV[l*DHd + t];
    vmean[bh*DHd + t] = s / (float)L;
  }
  for (int p = t; p < L*NTOP; p += 128){
    int l = p / NTOP;
    int kk = idx[p];
    const float* q = sQ + l*DHd;
    const float* k = sK + kk*DHd;
    float acc = 0.f;
    for (int d = 0; d < DHd; d++) acc += q[d]*k[d];
    qks[p] = acc;
  }
  __syncthreads();
  if (t < L){
    float mx = -1e30f, sm = 0.f;
    for (int u = 0; u < NTOP; u++){ float v = qks[t*NTOP + u]; mx = fmaxf(mx, v); sm += v; }
    sM[t] = mx - sm / (float)L;
  } else {
    sM[t] = -1e30f;
  }
  __syncthreads();
  for (int it = 0; it < NTOP; it++){
    rv[t] = sel[t] ? -1e30f : sM[t];
    ri[t] = t;
    __syncthreads();
    for (int off = 64; off > 0; off >>= 1){
      if (t < off){
        float v2 = rv[t+off]; int i2 = ri[t+off];
        if (v2 > rv[t] || (v2 == rv[t] && i2 < ri[t])){ rv[t] = v2; ri[t] = i2; }
      }
      __syncthreads();
    }
    if (t == 0){ int w = ri[0]; sel[w] = 1; stop[it] = w; posmap[bh*L0 + w] = it; }
    __syncthreads();
  }
  for (int u = 0; u < NTOP; u++){
    int ls = stop[u];
    float s = -1e30f;
    if (t < L){
      const float* q = sQ + ls*DHd;
      const float* k = sK + t*DHd;
      float acc = 0.f;
      for (int d = 0; d < DHd; d++) acc += q[d]*k[d];
      s = acc / 4.58257569479392f;   // sqrt(21)
    }
    red[t] = s;
    __syncthreads();
    for (int off = 64; off > 0; off >>= 1){ if (t < off) red[t] = fmaxf(red[t], red[t+off]); __syncthreads(); }
    float mx = red[0];
    __syncthreads();
    float e = (t < L) ? expf(s - mx) : 0.f;
    rv[t] = e; red[t] = e;
    __syncthreads();
    for (int off = 64; off > 0; off >>= 1){ if (t < off) red[t] += red[t+off]; __syncthreads(); }
    float denom = red[0];
    __syncthreads();
    if (t < DHd){
      float acc = 0.f;
      for (int k2 = 0; k2 < L; k2++) acc += rv[k2]*sV[k2*DHd + t];
      upd[((size_t)bh*NTOP + u)*DHd + t] = acc / denom;
    }
    __syncthreads();
  }
}

// ---------------- MFMA O-proj + residual + LN1 (64 rows / block) ----------------
__global__ __launch_bounds__(256) void k_oproj_mfma(const float* xin, const float* vmean,
                                                    const int* posmap, const float* upd,
                                                    const u16* wo, fp ob, fp g, fp bb,
                                                    int layer, int lshift, int lmask, float* xmid){
  __shared__ __align__(16) float sOf[64*129];   // 33 KB; low half doubles as bf16 sX
  __shared__ float prs[128];
  __shared__ float smean[64], srstd[64];
  u16* sX = reinterpret_cast<u16*>(sOf);
  const int tid = threadIdx.x;
  const int wave = tid >> 6, lane = tid & 63, quad = lane >> 4, l15 = lane & 15;
  const int m0 = wave * 16;
  const size_t rows0 = (size_t)blockIdx.x * 64;
  for (int p = tid; p < 64*128; p += 256){
    int r = p >> 7, c = p & 127;
    int gr = (int)rows0 + r, b = gr >> lshift, l = gr & lmask;
    float v = 0.f;
    if (c < DM){
      int h = c / DHd, d = c - h*DHd;
      int bh = b*NH + h;
      int pos = posmap[bh*L0 + l];
      v = (pos >= 0) ? upd[((size_t)bh*NTOP + pos)*DHd + d] : vmean[bh*DHd + d];
    }
    sX[r*136 + c] = f2bf(v);
  }
  __syncthreads();
  const f4v z4 = {0.f,0.f,0.f,0.f};
  f4v acc[8];
  #pragma unroll
  for (int t = 0; t < 8; t++) acc[t] = z4;
  #pragma unroll
  for (int ks = 0; ks < 4; ks++){
    s8v a = *reinterpret_cast<const s8v*>(sX + (m0 + l15)*136 + ks*32 + quad*8);
    const u16* wb = wo + (size_t)l15*128 + ks*32 + quad*8;
    #pragma unroll
    for (int t = 0; t < 8; t++){
      s8v b = *reinterpret_cast<const s8v*>(wb + (size_t)t*16*128);
      acc[t] = __builtin_amdgcn_mfma_f32_16x16x32_bf16(a, b, acc[t], 0, 0, 0);
    }
  }
  __syncthreads();   // done reading sX; sOf aliases it
  #pragma unroll
  for (int t = 0; t < 8; t++){
    int col = t*16 + l15;
    #pragma unroll
    for (int r = 0; r < 4; r++){
      sOf[(m0 + quad*4 + r)*129 + col] = acc[t][r];
    }
  }
  __syncthreads();
  const float* obl = ob + (size_t)layer*DM;
  for (int p = tid; p < 64*DM; p += 256){
    int r = p / DM, c = p - r*DM;
    sOf[r*129 + c] += xin[(rows0 + r)*DM + c] + obl[c];
  }
  __syncthreads();
  if (tid < 128){
    int row = tid >> 1, half = tid & 1;
    float s = 0.f;
    for (int c = half*63; c < half*63 + 63; c++) s += sOf[row*129 + c];
    prs[tid] = s;
  }
  __syncthreads();
  if (tid < 128 && (tid & 1) == 0) smean[tid>>1] = (prs[tid] + prs[tid+1]) / (float)DM;
  __syncthreads();
  if (tid < 128){
    int row = tid >> 1, half = tid & 1;
    float mn = smean[row];
    float s = 0.f;
    for (int c = half*63; c < half*63 + 63; c++){ float d = sOf[row*129 + c] - mn; s += d*d; }
    prs[tid] = s;
  }
  __syncthreads();
  if (tid < 128 && (tid & 1) == 0) srstd[tid>>1] = rsqrtf((prs[tid] + prs[tid+1])/(float)DM + 1e-5f);
  __syncthreads();
  const float* gl = g  + (size_t)layer*DM;
  const float* bl = bb + (size_t)layer*DM;
  for (int p = tid; p < 64*DM; p += 256){
    int r = p / DM, c = p - r*DM;
    xmid[(rows0 + r)*DM + c] = (sOf[r*129 + c] - smean[r])*srstd[r]*gl[c] + bl[c];
  }
}

// ---------------- FFN weights conversion ----------------
__global__ __launch_bounds__(256) void k_wconv(fp w1, fp w2, int layer, u16* w1t, u16* w2t){
  int i = blockIdx.x*256 + threadIdx.x;
  if (i < 2048*128){
    int n = i >> 7, k = i & 127;
    float v = (k < DM) ? w1[((size_t)layer*DM + k)*DFF + n] : 0.f;
    w1t[(size_t)n*128 + k] = f2bf(v);
  } else {
    int j = i - 2048*128;
    int n = j >> 11, f = j & 2047;
    float v = (n < DM) ? w2[((size_t)layer*DFF + f)*DM + n] : 0.f;
    w2t[(size_t)n*2048 + f] = f2bf(v);
  }
}

// GELU exact via Abramowitz-Stegun 7.1.26 erf (max err ~1.5e-7)
__device__ __forceinline__ float gelu_as(float x){
  float z  = 0.7071067811865475f * x;
  float zn = fabsf(z);
  float t  = 1.f / (1.f + 0.3275911f * zn);
  float p  = ((((1.061405429f*t - 1.453152027f)*t + 1.421413741f)*t - 0.284496736f)*t + 0.254829592f)*t;
  float ea = 1.f - p * __expf(-zn*zn);
  float er = (z < 0.f) ? -ea : ea;
  return 0.5f * x * (1.f + er);
}

// ---------------- MFMA FFN + residual + LN2 (64 rows / block) ----------------
__global__ __launch_bounds__(256) void k_ffn_mfma(const float* xmid, const u16* w1t, const u16* w2t,
                                                  fp b1, fp b2w, fp g, fp bb, int layer, float* xout){
  __shared__ __align__(16) u16 sXY[2*64*136];
  __shared__ float prs[128];
  __shared__ float smean[64], srstd[64];
  u16* sX = sXY;
  u16* sY = sXY + 64*136;
  const int tid  = threadIdx.x;
  const int wave = tid >> 6, lane = tid & 63, quad = lane >> 4, l15 = lane & 15;
  const int m0 = wave * 16;
  const size_t rows0 = (size_t)blockIdx.x * 64;

  for (int p = tid; p < 64*128; p += 256){
    int r = p >> 7, c = p & 127;
    float v = (c < DM) ? xmid[(rows0 + r)*DM + c] : 0.f;
    sX[r*136 + c] = f2bf(v);
  }
  __syncthreads();

  const float* b1l = b1 + (size_t)layer*DFF;
  const f4v z4 = {0.f, 0.f, 0.f, 0.f};
  f4v acc2[8];
  #pragma unroll
  for (int t = 0; t < 8; t++) acc2[t] = z4;

  for (int ch = 0; ch < 16; ch++){
    const int f0 = ch * 128;
    f4v acc1[8];
    #pragma unroll
    for (int t = 0; t < 8; t++) acc1[t] = z4;
    #pragma unroll
    for (int ks = 0; ks < 4; ks++){
      s8v a = *reinterpret_cast<const s8v*>(sX + (m0 + l15)*136 + ks*32 + quad*8);
      const u16* wb = w1t + ((size_t)(f0 + l15))*128 + ks*32 + quad*8;
      #pragma unroll
      for (int t = 0; t < 8; t++){
        s8v b = *reinterpret_cast<const s8v*>(wb + (size_t)t*16*128);
        acc1[t] = __builtin_amdgcn_mfma_f32_16x16x32_bf16(a, b, acc1[t], 0, 0, 0);
      }
    }
    #pragma unroll
    for (int t = 0; t < 8; t++){
      float bv = b1l[f0 + t*16 + l15];
      #pragma unroll
      for (int r = 0; r < 4; r++){
        float v = gelu_as(acc1[t][r] + bv);
        sY[(m0 + quad*4 + r)*136 + t*16 + l15] = f2bf(v);
      }
    }
    #pragma unroll
    for (int ks = 0; ks < 4; ks++){
      s8v a2 = *reinterpret_cast<const s8v*>(sY + (m0 + l15)*136 + ks*32 + quad*8);
      const u16* wb2 = w2t + (size_t)l15*2048 + f0 + ks*32 + quad*8;
      #pragma unroll
      for (int t = 0; t < 8; t++){
        s8v b = *reinterpret_cast<const s8v*>(wb2 + (size_t)t*16*2048);
        acc2[t] = __builtin_amdgcn_mfma_f32_16x16x32_bf16(a2, b, acc2[t], 0, 0, 0);
      }
    }
  }

  __syncthreads();
  float* sO = reinterpret_cast<float*>(sXY);   // [64][129]
  #pragma unroll
  for (int t = 0; t < 8; t++){
    int col = t*16 + l15;
    #pragma unroll
    for (int r = 0; r < 4; r++){
      sO[(m0 + quad*4 + r)*129 + col] = acc2[t][r];
    }
  }
  __syncthreads();
  const float* b2l = b2w + (size_t)layer*DM;
  for (int p = tid; p < 64*DM; p += 256){
    int r = p / DM, c = p - r*DM;
    sO[r*129 + c] += b2l[c] + xmid[(rows0 + r)*DM + c];
  }
  __syncthreads();
  if (tid < 128){
    int row = tid >> 1, half = tid & 1;
    float s = 0.f;
    for (int c = half*63; c < half*63 + 63; c++) s += sO[row*129 + c];
    prs[tid] = s;
  }
  __syncthreads();
  if (tid < 128 && (tid & 1) == 0) smean[tid>>1] = (prs[tid] + prs[tid+1]) / (float)DM;
  __syncthreads();
  if (tid < 128){
    int row = tid >> 1, half = tid & 1;
    float mn = smean[row];
    float s = 0.f;
    for (int c = half*63; c < half*63 + 63; c++){ float d = sO[row*129 + c] - mn; s += d*d; }
    prs[tid] = s;
  }
  __syncthreads();
  if (tid < 128 && (tid & 1) == 0) srstd[tid>>1] = rsqrtf((prs[tid] + prs[tid+1])/(float)DM + 1e-5f);
  __syncthreads();
  const float* gl = g  + (size_t)layer*DM;
  const float* bl = bb + (size_t)layer*DM;
  for (int p = tid; p < 64*DM; p += 256){
    int r = p / DM, c = p - r*DM;
    xout[(rows0 + r)*DM + c] = (sO[r*129 + c] - smean[r])*srstd[r]*gl[c] + bl[c];
  }
}

// ---------------- distil weights -> bf16 [n=co][k=q*126+ci] ----------------
__global__ __launch_bounds__(256) void k_wdist(fp clw, u16* wd){
  int i = blockIdx.x*256 + threadIdx.x;
  if (i < 128*384){
    int n = i / 384, k = i - n*384;
    float v = 0.f;
    if (n < DM && k < 378){
      int q = k / 126, ci = k - q*126;
      v = clw[((size_t)n*DM + ci)*3 + q];
    }
    wd[i] = f2bf(v);
  }
}

// ---------------- MFMA distil: conv(K=378) + BN + ELU + maxpool ----------------
__global__ __launch_bounds__(256) void k_distill_mfma(const float* xin, const u16* wdist,
                                                      fp clb, fp bng, fp bnb, float* xout){
  __shared__ __align__(16) u16 sA[128*392];
  const int tid = threadIdx.x;
  const int wave = tid >> 6, lane = tid & 63, quad = lane >> 4, l15 = lane & 15;
  const int b = blockIdx.x;
  for (int row = wave; row < 128; row += 4){
    #pragma unroll
    for (int e = 0; e < 6; e++){
      int kk = lane + e*64;
      float v = 0.f;
      if (kk < 378){
        int q = kk / 126, ci = kk - q*126;
        int sr = (row - 1 + q + 128) & 127;
        v = xin[((size_t)b*128 + sr)*DM + ci];
      }
      sA[row*392 + kk] = f2bf(v);
    }
  }
  __syncthreads();
  const f4v z4 = {0.f,0.f,0.f,0.f};
  f4v acc[2][8];
  #pragma unroll
  for (int m = 0; m < 2; m++)
    #pragma unroll
    for (int t = 0; t < 8; t++) acc[m][t] = z4;
  const int mBase = wave * 32;
  for (int ks = 0; ks < 12; ks++){
    s8v a0 = *reinterpret_cast<const s8v*>(sA + (mBase + l15)*392 + ks*32 + quad*8);
    s8v a1 = *reinterpret_cast<const s8v*>(sA + (mBase + 16 + l15)*392 + ks*32 + quad*8);
    const u16* wb = wdist + (size_t)l15*384 + ks*32 + quad*8;
    #pragma unroll
    for (int t = 0; t < 8; t++){
      s8v bfr = *reinterpret_cast<const s8v*>(wb + (size_t)t*16*384);
      acc[0][t] = __builtin_amdgcn_mfma_f32_16x16x32_bf16(a0, bfr, acc[0][t], 0, 0, 0);
      acc[1][t] = __builtin_amdgcn_mfma_f32_16x16x32_bf16(a1, bfr, acc[1][t], 0, 0, 0);
    }
  }
  __syncthreads();
  float* zsh = reinterpret_cast<float*>(sA);   // [128][130]
  const float bnscale = 1.f / sqrtf(1.f + 1e-5f);
  #pragma unroll
  for (int t = 0; t < 8; t++){
    int co = t*16 + l15;
    if (co < DM){
      float cb = clb[co];
      float gg = bng[co] * bnscale, bv = bnb[co];
      #pragma unroll
      for (int m = 0; m < 2; m++){
        #pragma unroll
        for (int r = 0; r < 4; r++){
          int row = mBase + m*16 + quad*4 + r;
          float z = (acc[m][t][r] + cb)*gg + bv;
          z = (z > 0.f) ? z : expm1f(z);
          zsh[row*130 + co] = z;
        }
      }
    }
  }
  __syncthreads();
  for (int p = tid; p < 64*DM; p += 256){
    int j = p / DM, co = p - j*DM;
    float best = zsh[(2*j)*130 + co];
    if (j > 0) best = fmaxf(best, zsh[(2*j - 1)*130 + co]);
    best = fmaxf(best, zsh[(2*j + 1)*130 + co]);
    xout[((size_t)b*64 + j)*DM + co] = best;
  }
}

// ---------------- final LN + fc ----------------
__global__ __launch_bounds__(128) void k_final(const float* xin, fp g, fp bb,
                                               fp fcw, fp fcb, float* out){
  __shared__ float xs[64][DM];
  __shared__ float mean_s[64], rstd_s[64];
  int b = blockIdx.x, t = threadIdx.x;
  for (int p = t; p < 64*DM; p += 128){ xs[p/DM][p%DM] = xin[(size_t)b*64*DM + p]; }
  __syncthreads();
  if (t < 64){
    float s = 0.f;
    for (int m = 0; m < DM; m++) s += xs[t][m];
    float mn = s / (float)DM;
    float v = 0.f;
    for (int m = 0; m < DM; m++){ float d = xs[t][m] - mn; v += d*d; }
    mean_s[t] = mn; rstd_s[t] = rsqrtf(v / (float)DM + 1e-5f);
  }
  __syncthreads();
  if (t < DM){
    float gv = g[t], bv = bb[t];
    float acc = fcb[0];
    for (int l = 0; l < 64; l++){
      float xn = (xs[l][t] - mean_s[l])*rstd_s[l]*gv + bv;
      acc += xn * fcw[l];
    }
    out[b*DM + t] = acc;
  }
}

// ---------------- host launcher ----------------
extern "C" void kernel_launch(void* const* d_in, const int* in_sizes, int n_in,
                              void* d_out, int out_size, void* d_ws, size_t ws_size,
                              hipStream_t stream) {
  fp x_enc   = (fp)d_in[0];
  fp x_mark  = (fp)d_in[1];
  fp token_w = (fp)d_in[2];
  fp time_w  = (fp)d_in[3];
  fp time_b  = (fp)d_in[4];
  fp od_fc_w = (fp)d_in[5];
  fp od_bn_g = (fp)d_in[6];
  fp od_bn_b = (fp)d_in[7];
  fp od_ch_w = (fp)d_in[8];
  fp od_ch_b = (fp)d_in[9];
  fp od_fil_w= (fp)d_in[10];
  fp od_fil_b= (fp)d_in[11];
  fp od_sp_w = (fp)d_in[12];
  fp od_sp_b = (fp)d_in[13];
  fp od_ker_w= (fp)d_in[14];
  fp od_ker_b= (fp)d_in[15];
  fp od_wt   = (fp)d_in[16];
  fp q_w = (fp)d_in[17]; fp q_b = (fp)d_in[18];
  fp k_w = (fp)d_in[19]; fp k_b = (fp)d_in[20];
  fp v_w = (fp)d_in[21]; fp v_b = (fp)d_in[22];
  fp o_w = (fp)d_in[23]; fp o_b = (fp)d_in[24];
  fp f1w = (fp)d_in[25]; fp f1b = (fp)d_in[26];
  fp f2w = (fp)d_in[27]; fp f2b = (fp)d_in[28];
  fp ln1g= (fp)d_in[29]; fp ln1b= (fp)d_in[30];
  fp ln2g= (fp)d_in[31]; fp ln2b= (fp)d_in[32];
  fp cl_w= (fp)d_in[33]; fp cl_b= (fp)d_in[34];
  fp clbg= (fp)d_in[35]; fp clbb= (fp)d_in[36];
  fp elng= (fp)d_in[37]; fp elnb= (fp)d_in[38];
  fp fc_w= (fp)d_in[39]; fp fc_b= (fp)d_in[40];

  // ---- workspace layout (float units) ----
  const size_t OFF_IDX0 = 0;
  const size_t OFF_IDX1 = OFF_IDX0 + 3200;
  const size_t OFF_CH   = OFF_IDX1 + 1600;
  const size_t OFF_FIL  = OFF_CH  + (size_t)NB*DE;
  const size_t OFF_SP   = OFF_FIL + (size_t)NB*DE;
  const size_t OFF_KER  = OFF_SP  + (size_t)NB*4;
  const size_t OFF_VM   = OFF_KER + (size_t)NB*4;
  const size_t OFF_POS  = OFF_VM  + (size_t)NB*NH*DHd;
  const size_t OFF_UPD  = OFF_POS + (size_t)NB*NH*L0;
  const size_t OFF_WTS  = (OFF_UPD + (size_t)NB*NH*NTOP*DHd + 255) & ~(size_t)255;
  // weights scratch (u16): w1t 262144 + w2t 262144 + wqkv 49152 + wdist 49152 + wo 16384 + wemb 32768
  const size_t WTS_FLOATS = (262144 + 262144 + 49152 + 49152 + 16384 + 32768)/2 + 384;
  const size_t OFF_BIG  = (OFF_WTS + WTS_FLOATS + 255) & ~(size_t)255;
  const size_t SBUF     = (size_t)NB*DE*L0;        // 4,194,304 floats
  const size_t TOTAL    = OFF_BIG + 4*SBUF;

  if (ws_size < TOTAL*sizeof(float)){
    hipLaunchKernelGGL(k_zero, dim3((out_size+255)/256), dim3(256), 0, stream,
                       (float*)d_out, out_size);
    return;
  }

  float* ws = (float*)d_ws;
  int* idx0 = (int*)(ws + OFF_IDX0);
  int* idx1 = (int*)(ws + OFF_IDX1);
  float* chv = ws + OFF_CH;
  float* filv= ws + OFF_FIL;
  float* spv = ws + OFF_SP;
  float* kerv= ws + OFF_KER;
  float* vme = ws + OFF_VM;
  int* posm  = (int*)(ws + OFF_POS);
  float* updb= ws + OFF_UPD;
  u16* w1tb  = (u16*)(ws + OFF_WTS);
  u16* w2tb  = w1tb + 262144;
  u16* wqkvb = w2tb + 262144;
  u16* wdistb= wqkvb + 49152;
  u16* wob   = wdistb + 49152;
  u16* wembb = wob + 16384;
  float* qkvbias = (float*)(wembb + 32768);

  float* X    = ws + OFF_BIG;          // x (odconv out; distil out)
  float* QKV  = X + SBUF;              // 3 SBUF: qkv[M][384]; aliases emb & xmid
  float* emb  = QKV;                   // alias (dead before qkv gemm), layout [b][l][e]
  float* xmid = QKV;                   // alias
  float* ffno = QKV + SBUF;            // ffn out (both layers)

  hipLaunchKernelGGL(k_idx, dim3(1), dim3(256), 0, stream, idx0, idx1);
  hipLaunchKernelGGL(k_wemb, dim3(128), dim3(256), 0, stream, token_w, wembb);
  hipLaunchKernelGGL(k_emb_mfma, dim3(NB), dim3(256), 0, stream,
                     x_enc, x_mark, wembb, time_w, time_b, emb);
  hipLaunchKernelGGL(k_scalars, dim3(NB), dim3(128), 0, stream,
                     emb, od_fc_w, od_bn_g, od_bn_b, od_ch_w, od_ch_b, od_fil_w, od_fil_b,
                     od_sp_w, od_sp_b, od_ker_w, od_ker_b, chv, filv, spv, kerv);
  hipLaunchKernelGGL(k_odconv, dim3(NB*2), dim3(256), 0, stream,
                     emb, od_wt, chv, filv, spv, kerv, X);
  hipLaunchKernelGGL(k_wdist, dim3(192), dim3(256), 0, stream, cl_w, wdistb);

  // ----- layer 0 (L=128) -----
  hipLaunchKernelGGL(k_wqkv, dim3(258), dim3(256), 0, stream,
                     q_w, q_b, k_w, k_b, v_w, v_b, o_w, 0, wqkvb, qkvbias, wob);
  hipLaunchKernelGGL(k_qkv_mfma, dim3(NB*L0/64), dim3(256), 0, stream,
                     X, wqkvb, qkvbias, QKV);
  hipLaunchKernelGGL(k_attn_fused, dim3(NB*NH), dim3(128), 0, stream,
                     QKV, idx0, L0, vme, posm, updb);
  hipLaunchKernelGGL(k_oproj_mfma, dim3(NB*L0/64), dim3(256), 0, stream,
                     X, vme, posm, updb, wob, o_b, ln1g, ln1b, 0, 7, 127, xmid);
  hipLaunchKernelGGL(k_wconv, dim3(2048), dim3(256), 0, stream, f1w, f2w, 0, w1tb, w2tb);
  hipLaunchKernelGGL(k_ffn_mfma, dim3(NB*L0/64), dim3(256), 0, stream,
                     xmid, w1tb, w2tb, f1b, f2b, ln2g, ln2b, 0, ffno);

  // ----- distil -----
  hipLaunchKernelGGL(k_distill_mfma, dim3(NB), dim3(256), 0, stream,
                     ffno, wdistb, cl_b, clbg, clbb, X);

  // ----- layer 1 (L=64) -----
  hipLaunchKernelGGL(k_wqkv, dim3(258), dim3(256), 0, stream,
                     q_w, q_b, k_w, k_b, v_w, v_b, o_w, 1, wqkvb, qkvbias, wob);
  hipLaunchKernelGGL(k_qkv_mfma, dim3(NB*64/64), dim3(256), 0, stream,
                     X, wqkvb, qkvbias, QKV);
  hipLaunchKernelGGL(k_attn_fused, dim3(NB*NH), dim3(128), 0, stream,
                     QKV, idx1, 64, vme, posm, updb);
  hipLaunchKernelGGL(k_oproj_mfma, dim3(NB*64/64), dim3(256), 0, stream,
                     X, vme, posm, updb, wob, o_b, ln1g, ln1b, 1, 6, 63, xmid);
  hipLaunchKernelGGL(k_wconv, dim3(2048), dim3(256), 0, stream, f1w, f2w, 1, w1tb, w2tb);
  hipLaunchKernelGGL(k_ffn_mfma, dim3(NB*64/64), dim3(256), 0, stream,
                     xmid, w1tb, w2tb, f1b, f2b, ln2g, ln2b, 1, ffno);

  hipLaunchKernelGGL(k_final, dim3(NB), dim3(128), 0, stream,
                     ffno, elng, elnb, fc_w, fc_b, (float*)d_out);
  (void)in_sizes; (void)n_in; (void)out_size; (void)ws_size;
}

// Round 7
// 1256.673 us; speedup vs baseline: 3.3108x; 1.3242x over previous
//
#include <hip/hip_runtime.h>
#include <math.h>

// Problem dims
#define NB 256
#define DM 126       // D_MODEL
#define DE 128       // D_EMB
#define NH 6
#define DHd 21
#define DFF 2048
#define CIN 75
#define L0 128
#define NTOP 25

#ifndef IDX_MODE
#define IDX_MODE 0
#endif

typedef const float* fp;
typedef unsigned short u16;
typedef short s8v __attribute__((ext_vector_type(8)));
typedef float f4v __attribute__((ext_vector_type(4)));

__device__ __forceinline__ u16 f2bf(float x){
  unsigned u = __float_as_uint(x);
  unsigned r = (u + 0x7FFFu + ((u >> 16) & 1u)) >> 16;
  return (u16)r;
}

__device__ __forceinline__ void gld_lds16(const u16* g, u16* l){
  __builtin_amdgcn_global_load_lds((const __attribute__((address_space(1))) unsigned int*)(const void*)g,
                                   (__attribute__((address_space(3))) unsigned int*)(void*)l,
                                   16, 0, 0);
}

__device__ __forceinline__ void tf2(unsigned k0, unsigned k1, unsigned x0, unsigned x1,
                                    unsigned &o0, unsigned &o1){
  unsigned ks2 = k0 ^ k1 ^ 0x1BD11BDAu;
  x0 += k0; x1 += k1;
  #define RR(r) { x0 += x1; x1 = (x1 << (r)) | (x1 >> (32 - (r))); x1 ^= x0; }
  RR(13) RR(15) RR(26) RR(6)
  x0 += k1;  x1 += ks2 + 1u;
  RR(17) RR(29) RR(16) RR(24)
  x0 += ks2; x1 += k0 + 2u;
  RR(13) RR(15) RR(26) RR(6)
  x0 += k0;  x1 += k1 + 3u;
  RR(17) RR(29) RR(16) RR(24)
  x0 += k1;  x1 += ks2 + 4u;
  RR(13) RR(15) RR(26) RR(6)
  x0 += ks2; x1 += k0 + 5u;
  #undef RR
  o0 = x0; o1 = x1;
}

// ---------------- fallback: zero output (ws too small diagnostic) ----------------
__global__ __launch_bounds__(256) void k_zero(float* out, int n){
  int i = blockIdx.x*256 + threadIdx.x;
  if (i < n) out[i] = 0.f;
}

// ---------------- idx precompute ----------------
__global__ __launch_bounds__(256) void k_idx(int* idx0, int* idx1){
  int tid = threadIdx.x;
  unsigned a0,a1,c0,c1;
  tf2(0u,42u, 0u,0u, a0,a1);
  tf2(0u,42u, 0u,1u, c0,c1);
  for (int f = tid; f < 3200; f += 256){
    unsigned y0,y1;
#if IDX_MODE==0
    tf2(a0,a1, 0u, (unsigned)(3200+f), y0,y1); idx0[f] = (int)(y1 & 127u);
#elif IDX_MODE==1
    tf2(a0,a1, 0u, (unsigned)(3200+f), y0,y1); idx0[f] = (int)(y0 & 127u);
#elif IDX_MODE==2
    tf2(a0,a1, (unsigned)f, (unsigned)(3200+f), y0,y1); idx0[f] = (int)(y1 & 127u);
#else
    tf2(a0,a1, (unsigned)f, (unsigned)(3200+f), y0,y1); idx0[f] = (int)(y0 & 127u);
#endif
  }
  for (int f = tid; f < 1600; f += 256){
    unsigned y0,y1;
#if IDX_MODE==0
    tf2(c0,c1, 0u, (unsigned)(1600+f), y0,y1); idx1[f] = (int)(y1 & 63u);
#elif IDX_MODE==1
    tf2(c0,c1, 0u, (unsigned)(1600+f), y0,y1); idx1[f] = (int)(y0 & 63u);
#elif IDX_MODE==2
    tf2(c0,c1, (unsigned)f, (unsigned)(1600+f), y0,y1); idx1[f] = (int)(y1 & 63u);
#else
    tf2(c0,c1, (unsigned)f, (unsigned)(1600+f), y0,y1); idx1[f] = (int)(y0 & 63u);
#endif
  }
}

// ---------------- token_w -> bf16 [n=e][k=q*75+c] (K padded to 256) ----------------
__global__ __launch_bounds__(256) void k_wemb(fp token_w, u16* we){
  int i = blockIdx.x*256 + threadIdx.x;
  if (i < 128*256){
    int n = i >> 8, k = i & 255;
    float v = 0.f;
    if (k < 225){
      int q = k / 75, c = k - q*75;
      v = token_w[(size_t)n*225 + c*3 + q];
    }
    we[i] = f2bf(v);
  }
}

// ---------------- MFMA token-embed: conv(K=225) + pos + time, out emb[b][l][e] ----------------
__global__ __launch_bounds__(256) void k_emb_mfma(fp x_enc, fp x_mark, const u16* wemb,
                                                  fp time_w, fp time_b, float* emb){
  __shared__ __align__(16) u16 sA[128*264];   // 67,584 B
  const int tid = threadIdx.x;
  const int wave = tid >> 6, lane = tid & 63, quad = lane >> 4, l15 = lane & 15;
  const int b = blockIdx.x;
  for (int p = tid; p < 128*256; p += 256){
    int kk = p & 255, row = p >> 8;
    float v = 0.f;
    if (kk < 225){
      int q = kk / 75, c = kk - q*75;
      int sr = (row - 1 + q + 128) & 127;
      v = x_enc[((size_t)b*L0 + sr)*CIN + c];
    }
    sA[row*264 + kk] = f2bf(v);
  }
  __syncthreads();
  const f4v z4 = {0.f,0.f,0.f,0.f};
  f4v acc[2][8];
  #pragma unroll
  for (int m = 0; m < 2; m++)
    #pragma unroll
    for (int t = 0; t < 8; t++) acc[m][t] = z4;
  const int mBase = wave * 32;
  for (int ks = 0; ks < 8; ks++){
    s8v a0 = *reinterpret_cast<const s8v*>(sA + (mBase + l15)*264 + ks*32 + quad*8);
    s8v a1 = *reinterpret_cast<const s8v*>(sA + (mBase + 16 + l15)*264 + ks*32 + quad*8);
    const u16* wb = wemb + (size_t)l15*256 + ks*32 + quad*8;
    #pragma unroll
    for (int t = 0; t < 8; t++){
      s8v bfr = *reinterpret_cast<const s8v*>(wb + (size_t)t*16*256);
      acc[0][t] = __builtin_amdgcn_mfma_f32_16x16x32_bf16(a0, bfr, acc[0][t], 0, 0, 0);
      acc[1][t] = __builtin_amdgcn_mfma_f32_16x16x32_bf16(a1, bfr, acc[1][t], 0, 0, 0);
    }
  }
  #pragma unroll
  for (int t = 0; t < 8; t++){
    int col = t*16 + l15;
    int i2 = col >> 1;
    float div = __expf((float)(2*i2) * (-9.210340371976184f / 128.f));
    float tw0 = time_w[col], tw1 = time_w[128 + col], tw2 = time_w[256 + col];
    float tb = time_b[col];
    #pragma unroll
    for (int m = 0; m < 2; m++){
      #pragma unroll
      for (int r = 0; r < 4; r++){
        int row = mBase + m*16 + quad*4 + r;
        float ang = (float)row * div;
        float pe = (col & 1) ? cosf(ang) : sinf(ang);
        const float* mk = x_mark + ((size_t)b*L0 + row)*3;
        float tm = mk[0]*tw0 + mk[1]*tw1 + mk[2]*tw2 + tb;
        emb[((size_t)b*L0 + row)*DE + col] = acc[m][t][r] + pe + tm;
      }
    }
  }
}

// ---------------- per-batch attention scalars (emb layout [b][l][e]) ----------------
__global__ __launch_bounds__(128) void k_scalars(const float* emb, fp fcw, fp bng, fp bnb,
                                                 fp chw, fp chb, fp filw, fp filb,
                                                 fp spw, fp spb, fp kerw, fp kerb,
                                                 float* ch, float* fil, float* sp, float* ker){
  __shared__ float gap[DE];
  __shared__ float a[16];
  int b = blockIdx.x, t = threadIdx.x;
  float s = 0.f;
  for (int l = 0; l < L0; l++) s += emb[((size_t)b*L0 + l)*DE + t];
  gap[t] = s / (float)L0;
  __syncthreads();
  if (t < 16){
    float acc = 0.f;
    for (int e = 0; e < DE; e++) acc += gap[e]*fcw[e*16 + t];
    acc = acc * (bng[t] / sqrtf(1.f + 1e-5f)) + bnb[t];
    a[t] = fmaxf(acc, 0.f);
  }
  __syncthreads();
  float accc = 0.f, accf = 0.f;
  for (int c = 0; c < 16; c++){ accc += a[c]*chw[c*DE + t]; accf += a[c]*filw[c*DE + t]; }
  ch[b*DE + t]  = 1.f/(1.f + expf(-(accc + chb[t])));
  fil[b*DE + t] = 1.f/(1.f + expf(-(accf + filb[t])));
  if (t < 3){
    float acc = 0.f;
    for (int c = 0; c < 16; c++) acc += a[c]*spw[c*3 + t];
    sp[b*4 + t] = 1.f/(1.f + expf(-(acc + spb[t])));
  }
  if (t == 0){
    float v[4]; float mx = -1e30f;
    for (int n = 0; n < 4; n++){
      float acc = 0.f;
      for (int c = 0; c < 16; c++) acc += a[c]*kerw[c*4 + n];
      v[n] = acc + kerb[n]; mx = fmaxf(mx, v[n]);
    }
    float ss = 0.f;
    for (int n = 0; n < 4; n++){ v[n] = expf(v[n]-mx); ss += v[n]; }
    for (int n = 0; n < 4; n++) ker[b*4 + n] = v[n]/ss;
  }
}

// ---------------- ODConv (emb layout [b][l][e]) ----------------
__global__ __launch_bounds__(256) void k_odconv(const float* emb, fp odw,
                                                const float* ch, const float* fil,
                                                const float* sp, const float* ker, float* xout){
  __shared__ float xc[DE][66];
  __shared__ float W[4][DE*3];
  int b = blockIdx.x >> 1, half = blockIdx.x & 1;
  int tid = threadIdx.x;
  int c0 = half * 63;
  for (int p = tid; p < DE*65; p += 256){
    int i = p & 127, c = p >> 7;
    xc[i][c] = emb[((size_t)b*L0 + (c0 + c))*DE + i] * ch[b*DE + i];
  }
  float kr[4]; for (int n = 0; n < 4; n++) kr[n] = ker[b*4 + n];
  float spv[3]; for (int j = 0; j < 3; j++) spv[j] = sp[b*4 + j];
  int tq = tid & 63;
  int oq = tid >> 6;
  for (int obase = 0; obase < DE; obase += 4){
    __syncthreads();
    for (int p = tid; p < 4*DE*3; p += 256){
      int oo = p / (DE*3), q = p % (DE*3);
      int o = obase + oo;
      float acc = kr[0]*odw[o*384 + q] + kr[1]*odw[49152 + o*384 + q]
                + kr[2]*odw[98304 + o*384 + q] + kr[3]*odw[147456 + o*384 + q];
      W[oo][q] = acc * spv[q % 3];
    }
    __syncthreads();
    if (tq < 63){
      int t = c0 + tq;
      float acc = 0.f;
      const float* Wp = W[oq];
      for (int i = 0; i < DE; i++){
        acc += Wp[i*3+0]*xc[i][tq] + Wp[i*3+1]*xc[i][tq+1] + Wp[i*3+2]*xc[i][tq+2];
      }
      int o = obase + oq;
      xout[((size_t)b*DE + o)*DM + t] = fil[b*DE + o] * acc;
    }
  }
}

// ---------------- QKV + O weights -> bf16 [n][k] + qkv bias ----------------
__global__ __launch_bounds__(256) void k_wqkv(fp qw, fp qb, fp kw, fp kb, fp vw, fp vb,
                                              fp ow, int layer, u16* wq, float* qbias, u16* wo){
  int i = blockIdx.x*256 + threadIdx.x;
  if (i < 384*128){
    int n = i >> 7, k = i & 127;
    int sec = n >> 7, nn = n & 127;
    const float* w = (sec == 0) ? qw : ((sec == 1) ? kw : vw);
    float v = (nn < DM && k < DM) ? w[((size_t)layer*DM + k)*DM + nn] : 0.f;
    wq[(size_t)n*128 + k] = f2bf(v);
  } else if (i < 384*128 + 384){
    int n = i - 384*128;
    int sec = n >> 7, nn = n & 127;
    const float* bp = (sec == 0) ? qb : ((sec == 1) ? kb : vb);
    qbias[n] = (nn < DM) ? bp[layer*DM + nn] : 0.f;
  } else if (i < 384*128 + 384 + 128*128){
    int j = i - (384*128 + 384);
    int n = j >> 7, k = j & 127;
    float v = (n < DM && k < DM) ? ow[(size_t)layer*DM*DM + k*DM + n] : 0.f;
    wo[(size_t)n*128 + k] = f2bf(v);
  }
}

// ---------------- fused QKV GEMM: qkv[M][384] ----------------
__global__ __launch_bounds__(256) void k_qkv_mfma(const float* xin, const u16* wqkv,
                                                  const float* qkvb, float* qkv){
  __shared__ __align__(16) u16 sX[64*136];
  const int tid = threadIdx.x;
  const int wave = tid >> 6, lane = tid & 63, quad = lane >> 4, l15 = lane & 15;
  const size_t rows0 = (size_t)blockIdx.x * 64;
  for (int p = tid; p < 64*128; p += 256){
    int r = p >> 7, c = p & 127;
    float v = (c < DM) ? xin[(rows0 + r)*DM + c] : 0.f;
    sX[r*136 + c] = f2bf(v);
  }
  __syncthreads();
  const f4v z4 = {0.f,0.f,0.f,0.f};
  f4v acc[24];
  #pragma unroll
  for (int t = 0; t < 24; t++) acc[t] = z4;
  const int m0 = wave * 16;
  #pragma unroll
  for (int ks = 0; ks < 4; ks++){
    s8v a = *reinterpret_cast<const s8v*>(sX + (m0 + l15)*136 + ks*32 + quad*8);
    const u16* wb = wqkv + (size_t)l15*128 + ks*32 + quad*8;
    #pragma unroll
    for (int t = 0; t < 24; t++){
      s8v b = *reinterpret_cast<const s8v*>(wb + (size_t)t*16*128);
      acc[t] = __builtin_amdgcn_mfma_f32_16x16x32_bf16(a, b, acc[t], 0, 0, 0);
    }
  }
  #pragma unroll
  for (int t = 0; t < 24; t++){
    int col = t*16 + l15;
    float bv = qkvb[col];
    #pragma unroll
    for (int r = 0; r < 4; r++){
      int row = m0 + quad*4 + r;
      qkv[(rows0 + row)*384 + col] = acc[t][r] + bv;
    }
  }
}

// ---------------- fused sparse attention (reads qkv[M][384]) ----------------
__global__ __launch_bounds__(128) void k_attn_fused(const float* qkv, const int* idx, int L,
                                                    float* vmean, int* posmap, float* upd){
  __shared__ float sQ[L0*DHd];
  __shared__ float sK[L0*DHd];
  __shared__ float sV[L0*DHd];
  __shared__ float qks[L0*NTOP];
  __shared__ float sM[L0];
  __shared__ float rv[L0];
  __shared__ int   ri[L0];
  __shared__ int   sel[L0];
  __shared__ int   stop[NTOP];
  __shared__ float red[128];
  int bh = blockIdx.x, t = threadIdx.x;
  int b = bh / NH, h = bh - b*NH;
  for (int p = t; p < L*DHd; p += 128){
    int l = p / DHd, d = p - l*DHd;
    const float* base = qkv + ((size_t)(b*L + l))*384 + h*DHd + d;
    sQ[p] = base[0]; sK[p] = base[128]; sV[p] = base[256];
  }
  posmap[bh*L0 + t] = -1;
  sel[t] = 0;
  __syncthreads();
  if (t < DHd){
    float s = 0.f;
    for (int l = 0; l < L; l++) s += sV[l*DHd + t];
    vmean[bh*DHd + t] = s / (float)L;
  }
  for (int p = t; p < L*NTOP; p += 128){
    int l = p / NTOP;
    int kk = idx[p];
    const float* q = sQ + l*DHd;
    const float* k = sK + kk*DHd;
    float acc = 0.f;
    for (int d = 0; d < DHd; d++) acc += q[d]*k[d];
    qks[p] = acc;
  }
  __syncthreads();
  if (t < L){
    float mx = -1e30f, sm = 0.f;
    for (int u = 0; u < NTOP; u++){ float v = qks[t*NTOP + u]; mx = fmaxf(mx, v); sm += v; }
    sM[t] = mx - sm / (float)L;
  } else {
    sM[t] = -1e30f;
  }
  __syncthreads();
  for (int it = 0; it < NTOP; it++){
    rv[t] = sel[t] ? -1e30f : sM[t];
    ri[t] = t;
    __syncthreads();
    for (int off = 64; off > 0; off >>= 1){
      if (t < off){
        float v2 = rv[t+off]; int i2 = ri[t+off];
        if (v2 > rv[t] || (v2 == rv[t] && i2 < ri[t])){ rv[t] = v2; ri[t] = i2; }
      }
      __syncthreads();
    }
    if (t == 0){ int w = ri[0]; sel[w] = 1; stop[it] = w; posmap[bh*L0 + w] = it; }
    __syncthreads();
  }
  for (int u = 0; u < NTOP; u++){
    int ls = stop[u];
    float s = -1e30f;
    if (t < L){
      const float* q = sQ + ls*DHd;
      const float* k = sK + t*DHd;
      float acc = 0.f;
      for (int d = 0; d < DHd; d++) acc += q[d]*k[d];
      s = acc / 4.58257569479392f;   // sqrt(21)
    }
    red[t] = s;
    __syncthreads();
    for (int off = 64; off > 0; off >>= 1){ if (t < off) red[t] = fmaxf(red[t], red[t+off]); __syncthreads(); }
    float mx = red[0];
    __syncthreads();
    float e = (t < L) ? expf(s - mx) : 0.f;
    rv[t] = e; red[t] = e;
    __syncthreads();
    for (int off = 64; off > 0; off >>= 1){ if (t < off) red[t] += red[t+off]; __syncthreads(); }
    float denom = red[0];
    __syncthreads();
    if (t < DHd){
      float acc = 0.f;
      for (int k2 = 0; k2 < L; k2++) acc += rv[k2]*sV[k2*DHd + t];
      upd[((size_t)bh*NTOP + u)*DHd + t] = acc / denom;
    }
    __syncthreads();
  }
}

// ---------------- MFMA O-proj + residual + LN1 (64 rows / block) ----------------
__global__ __launch_bounds__(256) void k_oproj_mfma(const float* xin, const float* vmean,
                                                    const int* posmap, const float* upd,
                                                    const u16* wo, fp ob, fp g, fp bb,
                                                    int layer, int lshift, int lmask, float* xmid){
  __shared__ __align__(16) float sOf[64*129];
  __shared__ float prs[128];
  __shared__ float smean[64], srstd[64];
  u16* sX = reinterpret_cast<u16*>(sOf);
  const int tid = threadIdx.x;
  const int wave = tid >> 6, lane = tid & 63, quad = lane >> 4, l15 = lane & 15;
  const int m0 = wave * 16;
  const size_t rows0 = (size_t)blockIdx.x * 64;
  for (int p = tid; p < 64*128; p += 256){
    int r = p >> 7, c = p & 127;
    int gr = (int)rows0 + r, b = gr >> lshift, l = gr & lmask;
    float v = 0.f;
    if (c < DM){
      int h = c / DHd, d = c - h*DHd;
      int bh = b*NH + h;
      int pos = posmap[bh*L0 + l];
      v = (pos >= 0) ? upd[((size_t)bh*NTOP + pos)*DHd + d] : vmean[bh*DHd + d];
    }
    sX[r*136 + c] = f2bf(v);
  }
  __syncthreads();
  const f4v z4 = {0.f,0.f,0.f,0.f};
  f4v acc[8];
  #pragma unroll
  for (int t = 0; t < 8; t++) acc[t] = z4;
  #pragma unroll
  for (int ks = 0; ks < 4; ks++){
    s8v a = *reinterpret_cast<const s8v*>(sX + (m0 + l15)*136 + ks*32 + quad*8);
    const u16* wb = wo + (size_t)l15*128 + ks*32 + quad*8;
    #pragma unroll
    for (int t = 0; t < 8; t++){
      s8v b = *reinterpret_cast<const s8v*>(wb + (size_t)t*16*128);
      acc[t] = __builtin_amdgcn_mfma_f32_16x16x32_bf16(a, b, acc[t], 0, 0, 0);
    }
  }
  __syncthreads();
  #pragma unroll
  for (int t = 0; t < 8; t++){
    int col = t*16 + l15;
    #pragma unroll
    for (int r = 0; r < 4; r++){
      sOf[(m0 + quad*4 + r)*129 + col] = acc[t][r];
    }
  }
  __syncthreads();
  const float* obl = ob + (size_t)layer*DM;
  for (int p = tid; p < 64*DM; p += 256){
    int r = p / DM, c = p - r*DM;
    sOf[r*129 + c] += xin[(rows0 + r)*DM + c] + obl[c];
  }
  __syncthreads();
  if (tid < 128){
    int row = tid >> 1, half = tid & 1;
    float s = 0.f;
    for (int c = half*63; c < half*63 + 63; c++) s += sOf[row*129 + c];
    prs[tid] = s;
  }
  __syncthreads();
  if (tid < 128 && (tid & 1) == 0) smean[tid>>1] = (prs[tid] + prs[tid+1]) / (float)DM;
  __syncthreads();
  if (tid < 128){
    int row = tid >> 1, half = tid & 1;
    float mn = smean[row];
    float s = 0.f;
    for (int c = half*63; c < half*63 + 63; c++){ float d = sOf[row*129 + c] - mn; s += d*d; }
    prs[tid] = s;
  }
  __syncthreads();
  if (tid < 128 && (tid & 1) == 0) srstd[tid>>1] = rsqrtf((prs[tid] + prs[tid+1])/(float)DM + 1e-5f);
  __syncthreads();
  const float* gl = g  + (size_t)layer*DM;
  const float* bl = bb + (size_t)layer*DM;
  for (int p = tid; p < 64*DM; p += 256){
    int r = p / DM, c = p - r*DM;
    xmid[(rows0 + r)*DM + c] = (sOf[r*129 + c] - smean[r])*srstd[r]*gl[c] + bl[c];
  }
}

// ---------------- FFN weights conversion ----------------
__global__ __launch_bounds__(256) void k_wconv(fp w1, fp w2, int layer, u16* w1t, u16* w2t){
  int i = blockIdx.x*256 + threadIdx.x;
  if (i < 2048*128){
    int n = i >> 7, k = i & 127;
    float v = (k < DM) ? w1[((size_t)layer*DM + k)*DFF + n] : 0.f;
    w1t[(size_t)n*128 + k] = f2bf(v);
  } else {
    int j = i - 2048*128;
    int n = j >> 11, f = j & 2047;
    float v = (n < DM) ? w2[((size_t)layer*DFF + f)*DM + n] : 0.f;
    w2t[(size_t)n*2048 + f] = f2bf(v);
  }
}

// GELU exact via Abramowitz-Stegun 7.1.26 erf (max err ~1.5e-7)
__device__ __forceinline__ float gelu_as(float x){
  float z  = 0.7071067811865475f * x;
  float zn = fabsf(z);
  float t  = 1.f / (1.f + 0.3275911f * zn);
  float p  = ((((1.061405429f*t - 1.453152027f)*t + 1.421413741f)*t - 0.284496736f)*t + 0.254829592f)*t;
  float ea = 1.f - p * __expf(-zn*zn);
  float er = (z < 0.f) ? -ea : ea;
  return 0.5f * x * (1.f + er);
}

// ---------------- MFMA FFN + residual + LN2 — LDS-pipelined weights ----------------
// smem carve (u16 units): sX 64*136=8704 | sY 4*16*72=4608 | wA0 8192 | wA1 8192 | wB 8192
#define FFN_SMEM_U16 (8704 + 4608 + 3*8192)

// stage a 64x128-u16 w1 chunk (swizzled colgroup^=(row&7)), 16 units/row
__device__ __forceinline__ void stage_w1(const u16* w1t, int j, u16* buf, int wave, int lane){
  #pragma unroll
  for (int r = 0; r < 4; r++){
    int p = r*256 + wave*64 + lane;
    int n = p >> 4, c = p & 15;
    int cg = c ^ (n & 7);
    const u16* g = w1t + (((size_t)(j*64 + n)) << 7) + cg*8;
    u16* l = buf + (size_t)(r*256 + wave*64)*8;   // wave-uniform; lane offset implicit (lane*16B)
    gld_lds16(g, l);
  }
}
// stage a 128x64-u16 w2 chunk (swizzled), 8 units/row
__device__ __forceinline__ void stage_w2(const u16* w2t, int j, u16* buf, int wave, int lane){
  #pragma unroll
  for (int r = 0; r < 4; r++){
    int p = r*256 + wave*64 + lane;
    int n = p >> 3, c = p & 7;
    int cg = c ^ (n & 7);
    const u16* g = w2t + (size_t)n*2048 + j*64 + cg*8;
    u16* l = buf + (size_t)(r*256 + wave*64)*8;
    gld_lds16(g, l);
  }
}

__global__ __launch_bounds__(256) void k_ffn_mfma(const float* xmid, const u16* w1t, const u16* w2t,
                                                  fp b1, fp b2w, fp g, fp bb, int layer, float* xout){
  __shared__ __align__(16) u16 smem[FFN_SMEM_U16];
  __shared__ float prs[128];
  __shared__ float smean[64], srstd[64];
  u16* sX  = smem;
  u16* wA0 = smem + 8704 + 4608;
  u16* wA1 = wA0 + 8192;
  u16* wBf = wA1 + 8192;
  const int tid  = threadIdx.x;
  const int wave = tid >> 6, lane = tid & 63, quad = lane >> 4, l15 = lane & 15;
  const int m0 = wave * 16;
  u16* sYw = smem + 8704 + wave*1152;   // 16 rows x 72 stride, wave-private
  const size_t rows0 = (size_t)blockIdx.x * 64;

  for (int p = tid; p < 64*128; p += 256){
    int r = p >> 7, c = p & 127;
    float v = (c < DM) ? xmid[(rows0 + r)*DM + c] : 0.f;
    sX[r*136 + c] = f2bf(v);
  }
  stage_w1(w1t, 0, wA0, wave, lane);
  stage_w2(w2t, 0, wBf, wave, lane);
  __syncthreads();

  const float* b1l = b1 + (size_t)layer*DFF;
  const f4v z4 = {0.f, 0.f, 0.f, 0.f};
  f4v acc2[8];
  #pragma unroll
  for (int t = 0; t < 8; t++) acc2[t] = z4;

  for (int j = 0; j < 32; j++){
    u16* wAcur = (j & 1) ? wA1 : wA0;
    u16* wAnext = (j & 1) ? wA0 : wA1;
    if (j < 31) stage_w1(w1t, j+1, wAnext, wave, lane);
    // GEMM1: 16 rows x 64 cols, K=128
    f4v acc1[4];
    #pragma unroll
    for (int t = 0; t < 4; t++) acc1[t] = z4;
    #pragma unroll
    for (int ks = 0; ks < 4; ks++){
      s8v a = *reinterpret_cast<const s8v*>(sX + (m0 + l15)*136 + ks*32 + quad*8);
      #pragma unroll
      for (int t = 0; t < 4; t++){
        int nloc = t*16 + l15;
        int cg = (ks*4 + quad) ^ (nloc & 7);
        s8v b = *reinterpret_cast<const s8v*>(wAcur + nloc*128 + cg*8);
        acc1[t] = __builtin_amdgcn_mfma_f32_16x16x32_bf16(a, b, acc1[t], 0, 0, 0);
      }
    }
    // bias + GELU -> sY (wave-private rows)
    #pragma unroll
    for (int t = 0; t < 4; t++){
      float bv = b1l[j*64 + t*16 + l15];
      #pragma unroll
      for (int r = 0; r < 4; r++){
        float v = gelu_as(acc1[t][r] + bv);
        sYw[(quad*4 + r)*72 + t*16 + l15] = f2bf(v);
      }
    }
    __syncthreads();   // drains w1[j+1] & ensures wB holds w2[j]
    // GEMM2: K=64 from sY, N=128, accumulate
    #pragma unroll
    for (int ks = 0; ks < 2; ks++){
      s8v a2 = *reinterpret_cast<const s8v*>(sYw + l15*72 + ks*32 + quad*8);
      #pragma unroll
      for (int t = 0; t < 8; t++){
        int nloc = t*16 + l15;
        int cg = (ks*4 + quad) ^ (nloc & 7);
        s8v b = *reinterpret_cast<const s8v*>(wBf + nloc*64 + cg*8);
        acc2[t] = __builtin_amdgcn_mfma_f32_16x16x32_bf16(a2, b, acc2[t], 0, 0, 0);
      }
    }
    __syncthreads();   // all waves done reading wB
    if (j < 31) stage_w2(w2t, j+1, wBf, wave, lane);
  }

  // epilogue: reuse smem as fp32 [64][129]
  float* sO = reinterpret_cast<float*>(smem);
  #pragma unroll
  for (int t = 0; t < 8; t++){
    int col = t*16 + l15;
    #pragma unroll
    for (int r = 0; r < 4; r++){
      sO[(m0 + quad*4 + r)*129 + col] = acc2[t][r];
    }
  }
  __syncthreads();
  const float* b2l = b2w + (size_t)layer*DM;
  for (int p = tid; p < 64*DM; p += 256){
    int r = p / DM, c = p - r*DM;
    sO[r*129 + c] += b2l[c] + xmid[(rows0 + r)*DM + c];
  }
  __syncthreads();
  if (tid < 128){
    int row = tid >> 1, half = tid & 1;
    float s = 0.f;
    for (int c = half*63; c < half*63 + 63; c++) s += sO[row*129 + c];
    prs[tid] = s;
  }
  __syncthreads();
  if (tid < 128 && (tid & 1) == 0) smean[tid>>1] = (prs[tid] + prs[tid+1]) / (float)DM;
  __syncthreads();
  if (tid < 128){
    int row = tid >> 1, half = tid & 1;
    float mn = smean[row];
    float s = 0.f;
    for (int c = half*63; c < half*63 + 63; c++){ float d = sO[row*129 + c] - mn; s += d*d; }
    prs[tid] = s;
  }
  __syncthreads();
  if (tid < 128 && (tid & 1) == 0) srstd[tid>>1] = rsqrtf((prs[tid] + prs[tid+1])/(float)DM + 1e-5f);
  __syncthreads();
  const float* gl = g  + (size_t)layer*DM;
  const float* bl = bb + (size_t)layer*DM;
  for (int p = tid; p < 64*DM; p += 256){
    int r = p / DM, c = p - r*DM;
    xout[(rows0 + r)*DM + c] = (sO[r*129 + c] - smean[r])*srstd[r]*gl[c] + bl[c];
  }
}

// ---------------- distil weights -> bf16 [n=co][k=q*126+ci] ----------------
__global__ __launch_bounds__(256) void k_wdist(fp clw, u16* wd){
  int i = blockIdx.x*256 + threadIdx.x;
  if (i < 128*384){
    int n = i / 384, k = i - n*384;
    float v = 0.f;
    if (n < DM && k < 378){
      int q = k / 126, ci = k - q*126;
      v = clw[((size_t)n*DM + ci)*3 + q];
    }
    wd[i] = f2bf(v);
  }
}

// ---------------- MFMA distil: conv(K=378) + BN + ELU + maxpool ----------------
__global__ __launch_bounds__(256) void k_distill_mfma(const float* xin, const u16* wdist,
                                                      fp clb, fp bng, fp bnb, float* xout){
  __shared__ __align__(16) u16 sA[128*392];
  const int tid = threadIdx.x;
  const int wave = tid >> 6, lane = tid & 63, quad = lane >> 4, l15 = lane & 15;
  const int b = blockIdx.x;
  for (int row = wave; row < 128; row += 4){
    #pragma unroll
    for (int e = 0; e < 6; e++){
      int kk = lane + e*64;
      float v = 0.f;
      if (kk < 378){
        int q = kk / 126, ci = kk - q*126;
        int sr = (row - 1 + q + 128) & 127;
        v = xin[((size_t)b*128 + sr)*DM + ci];
      }
      sA[row*392 + kk] = f2bf(v);
    }
  }
  __syncthreads();
  const f4v z4 = {0.f,0.f,0.f,0.f};
  f4v acc[2][8];
  #pragma unroll
  for (int m = 0; m < 2; m++)
    #pragma unroll
    for (int t = 0; t < 8; t++) acc[m][t] = z4;
  const int mBase = wave * 32;
  for (int ks = 0; ks < 12; ks++){
    s8v a0 = *reinterpret_cast<const s8v*>(sA + (mBase + l15)*392 + ks*32 + quad*8);
    s8v a1 = *reinterpret_cast<const s8v*>(sA + (mBase + 16 + l15)*392 + ks*32 + quad*8);
    const u16* wb = wdist + (size_t)l15*384 + ks*32 + quad*8;
    #pragma unroll
    for (int t = 0; t < 8; t++){
      s8v bfr = *reinterpret_cast<const s8v*>(wb + (size_t)t*16*384);
      acc[0][t] = __builtin_amdgcn_mfma_f32_16x16x32_bf16(a0, bfr, acc[0][t], 0, 0, 0);
      acc[1][t] = __builtin_amdgcn_mfma_f32_16x16x32_bf16(a1, bfr, acc[1][t], 0, 0, 0);
    }
  }
  __syncthreads();
  float* zsh = reinterpret_cast<float*>(sA);   // [128][130]
  const float bnscale = 1.f / sqrtf(1.f + 1e-5f);
  #pragma unroll
  for (int t = 0; t < 8; t++){
    int co = t*16 + l15;
    if (co < DM){
      float cb = clb[co];
      float gg = bng[co] * bnscale, bv = bnb[co];
      #pragma unroll
      for (int m = 0; m < 2; m++){
        #pragma unroll
        for (int r = 0; r < 4; r++){
          int row = mBase + m*16 + quad*4 + r;
          float z = (acc[m][t][r] + cb)*gg + bv;
          z = (z > 0.f) ? z : expm1f(z);
          zsh[row*130 + co] = z;
        }
      }
    }
  }
  __syncthreads();
  for (int p = tid; p < 64*DM; p += 256){
    int j = p / DM, co = p - j*DM;
    float best = zsh[(2*j)*130 + co];
    if (j > 0) best = fmaxf(best, zsh[(2*j - 1)*130 + co]);
    best = fmaxf(best, zsh[(2*j + 1)*130 + co]);
    xout[((size_t)b*64 + j)*DM + co] = best;
  }
}

// ---------------- final LN + fc ----------------
__global__ __launch_bounds__(128) void k_final(const float* xin, fp g, fp bb,
                                               fp fcw, fp fcb, float* out){
  __shared__ float xs[64][DM];
  __shared__ float mean_s[64], rstd_s[64];
  int b = blockIdx.x, t = threadIdx.x;
  for (int p = t; p < 64*DM; p += 128){ xs[p/DM][p%DM] = xin[(size_t)b*64*DM + p]; }
  __syncthreads();
  if (t < 64){
    float s = 0.f;
    for (int m = 0; m < DM; m++) s += xs[t][m];
    float mn = s / (float)DM;
    float v = 0.f;
    for (int m = 0; m < DM; m++){ float d = xs[t][m] - mn; v += d*d; }
    mean_s[t] = mn; rstd_s[t] = rsqrtf(v / (float)DM + 1e-5f);
  }
  __syncthreads();
  if (t < DM){
    float gv = g[t], bv = bb[t];
    float acc = fcb[0];
    for (int l = 0; l < 64; l++){
      float xn = (xs[l][t] - mean_s[l])*rstd_s[l]*gv + bv;
      acc += xn * fcw[l];
    }
    out[b*DM + t] = acc;
  }
}

// ---------------- host launcher ----------------
extern "C" void kernel_launch(void* const* d_in, const int* in_sizes, int n_in,
                              void* d_out, int out_size, void* d_ws, size_t ws_size,
                              hipStream_t stream) {
  fp x_enc   = (fp)d_in[0];
  fp x_mark  = (fp)d_in[1];
  fp token_w = (fp)d_in[2];
  fp time_w  = (fp)d_in[3];
  fp time_b  = (fp)d_in[4];
  fp od_fc_w = (fp)d_in[5];
  fp od_bn_g = (fp)d_in[6];
  fp od_bn_b = (fp)d_in[7];
  fp od_ch_w = (fp)d_in[8];
  fp od_ch_b = (fp)d_in[9];
  fp od_fil_w= (fp)d_in[10];
  fp od_fil_b= (fp)d_in[11];
  fp od_sp_w = (fp)d_in[12];
  fp od_sp_b = (fp)d_in[13];
  fp od_ker_w= (fp)d_in[14];
  fp od_ker_b= (fp)d_in[15];
  fp od_wt   = (fp)d_in[16];
  fp q_w = (fp)d_in[17]; fp q_b = (fp)d_in[18];
  fp k_w = (fp)d_in[19]; fp k_b = (fp)d_in[20];
  fp v_w = (fp)d_in[21]; fp v_b = (fp)d_in[22];
  fp o_w = (fp)d_in[23]; fp o_b = (fp)d_in[24];
  fp f1w = (fp)d_in[25]; fp f1b = (fp)d_in[26];
  fp f2w = (fp)d_in[27]; fp f2b = (fp)d_in[28];
  fp ln1g= (fp)d_in[29]; fp ln1b= (fp)d_in[30];
  fp ln2g= (fp)d_in[31]; fp ln2b= (fp)d_in[32];
  fp cl_w= (fp)d_in[33]; fp cl_b= (fp)d_in[34];
  fp clbg= (fp)d_in[35]; fp clbb= (fp)d_in[36];
  fp elng= (fp)d_in[37]; fp elnb= (fp)d_in[38];
  fp fc_w= (fp)d_in[39]; fp fc_b= (fp)d_in[40];

  // ---- workspace layout (float units) ----
  const size_t OFF_IDX0 = 0;
  const size_t OFF_IDX1 = OFF_IDX0 + 3200;
  const size_t OFF_CH   = OFF_IDX1 + 1600;
  const size_t OFF_FIL  = OFF_CH  + (size_t)NB*DE;
  const size_t OFF_SP   = OFF_FIL + (size_t)NB*DE;
  const size_t OFF_KER  = OFF_SP  + (size_t)NB*4;
  const size_t OFF_VM   = OFF_KER + (size_t)NB*4;
  const size_t OFF_POS  = OFF_VM  + (size_t)NB*NH*DHd;
  const size_t OFF_UPD  = OFF_POS + (size_t)NB*NH*L0;
  const size_t OFF_WTS  = (OFF_UPD + (size_t)NB*NH*NTOP*DHd + 255) & ~(size_t)255;
  const size_t WTS_FLOATS = (262144 + 262144 + 49152 + 49152 + 16384 + 32768)/2 + 384;
  const size_t OFF_BIG  = (OFF_WTS + WTS_FLOATS + 255) & ~(size_t)255;
  const size_t SBUF     = (size_t)NB*DE*L0;
  const size_t TOTAL    = OFF_BIG + 4*SBUF;

  if (ws_size < TOTAL*sizeof(float)){
    hipLaunchKernelGGL(k_zero, dim3((out_size+255)/256), dim3(256), 0, stream,
                       (float*)d_out, out_size);
    return;
  }

  float* ws = (float*)d_ws;
  int* idx0 = (int*)(ws + OFF_IDX0);
  int* idx1 = (int*)(ws + OFF_IDX1);
  float* chv = ws + OFF_CH;
  float* filv= ws + OFF_FIL;
  float* spv = ws + OFF_SP;
  float* kerv= ws + OFF_KER;
  float* vme = ws + OFF_VM;
  int* posm  = (int*)(ws + OFF_POS);
  float* updb= ws + OFF_UPD;
  u16* w1tb  = (u16*)(ws + OFF_WTS);
  u16* w2tb  = w1tb + 262144;
  u16* wqkvb = w2tb + 262144;
  u16* wdistb= wqkvb + 49152;
  u16* wob   = wdistb + 49152;
  u16* wembb = wob + 16384;
  float* qkvbias = (float*)(wembb + 32768);

  float* X    = ws + OFF_BIG;
  float* QKV  = X + SBUF;
  float* emb  = QKV;
  float* xmid = QKV;
  float* ffno = QKV + SBUF;

  hipLaunchKernelGGL(k_idx, dim3(1), dim3(256), 0, stream, idx0, idx1);
  hipLaunchKernelGGL(k_wemb, dim3(128), dim3(256), 0, stream, token_w, wembb);
  hipLaunchKernelGGL(k_emb_mfma, dim3(NB), dim3(256), 0, stream,
                     x_enc, x_mark, wembb, time_w, time_b, emb);
  hipLaunchKernelGGL(k_scalars, dim3(NB), dim3(128), 0, stream,
                     emb, od_fc_w, od_bn_g, od_bn_b, od_ch_w, od_ch_b, od_fil_w, od_fil_b,
                     od_sp_w, od_sp_b, od_ker_w, od_ker_b, chv, filv, spv, kerv);
  hipLaunchKernelGGL(k_odconv, dim3(NB*2), dim3(256), 0, stream,
                     emb, od_wt, chv, filv, spv, kerv, X);
  hipLaunchKernelGGL(k_wdist, dim3(192), dim3(256), 0, stream, cl_w, wdistb);

  // ----- layer 0 (L=128) -----
  hipLaunchKernelGGL(k_wqkv, dim3(258), dim3(256), 0, stream,
                     q_w, q_b, k_w, k_b, v_w, v_b, o_w, 0, wqkvb, qkvbias, wob);
  hipLaunchKernelGGL(k_qkv_mfma, dim3(NB*L0/64), dim3(256), 0, stream,
                     X, wqkvb, qkvbias, QKV);
  hipLaunchKernelGGL(k_attn_fused, dim3(NB*NH), dim3(128), 0, stream,
                     QKV, idx0, L0, vme, posm, updb);
  hipLaunchKernelGGL(k_oproj_mfma, dim3(NB*L0/64), dim3(256), 0, stream,
                     X, vme, posm, updb, wob, o_b, ln1g, ln1b, 0, 7, 127, xmid);
  hipLaunchKernelGGL(k_wconv, dim3(2048), dim3(256), 0, stream, f1w, f2w, 0, w1tb, w2tb);
  hipLaunchKernelGGL(k_ffn_mfma, dim3(NB*L0/64), dim3(256), 0, stream,
                     xmid, w1tb, w2tb, f1b, f2b, ln2g, ln2b, 0, ffno);

  // ----- distil -----
  hipLaunchKernelGGL(k_distill_mfma, dim3(NB), dim3(256), 0, stream,
                     ffno, wdistb, cl_b, clbg, clbb, X);

  // ----- layer 1 (L=64) -----
  hipLaunchKernelGGL(k_wqkv, dim3(258), dim3(256), 0, stream,
                     q_w, q_b, k_w, k_b, v_w, v_b, o_w, 1, wqkvb, qkvbias, wob);
  hipLaunchKernelGGL(k_qkv_mfma, dim3(NB*64/64), dim3(256), 0, stream,
                     X, wqkvb, qkvbias, QKV);
  hipLaunchKernelGGL(k_attn_fused, dim3(NB*NH), dim3(128), 0, stream,
                     QKV, idx1, 64, vme, posm, updb);
  hipLaunchKernelGGL(k_oproj_mfma, dim3(NB*64/64), dim3(256), 0, stream,
                     X, vme, posm, updb, wob, o_b, ln1g, ln1b, 1, 6, 63, xmid);
  hipLaunchKernelGGL(k_wconv, dim3(2048), dim3(256), 0, stream, f1w, f2w, 1, w1tb, w2tb);
  hipLaunchKernelGGL(k_ffn_mfma, dim3(NB*64/64), dim3(256), 0, stream,
                     xmid, w1tb, w2tb, f1b, f2b, ln2g, ln2b, 1, ffno);

  hipLaunchKernelGGL(k_final, dim3(NB), dim3(128), 0, stream,
                     ffno, elng, elnb, fc_w, fc_b, (float*)d_out);
  (void)in_sizes; (void)n_in; (void)out_size; (void)ws_size;
}

// Round 8
// 1089.466 us; speedup vs baseline: 3.8190x; 1.1535x over previous
//
#include <hip/hip_runtime.h>
#include <math.h>

// Problem dims
#define NB 256
#define DM 126       // D_MODEL
#define DE 128       // D_EMB
#define NH 6
#define DHd 21
#define DFF 2048
#define CIN 75
#define L0 128
#define NTOP 25

#ifndef IDX_MODE
#define IDX_MODE 0
#endif

typedef const float* fp;
typedef unsigned short u16;
typedef short s8v __attribute__((ext_vector_type(8)));
typedef float f4v __attribute__((ext_vector_type(4)));

__device__ __forceinline__ u16 f2bf(float x){
  unsigned u = __float_as_uint(x);
  unsigned r = (u + 0x7FFFu + ((u >> 16) & 1u)) >> 16;
  return (u16)r;
}

__device__ __forceinline__ void gld_lds16(const u16* g, u16* l){
  __builtin_amdgcn_global_load_lds((const __attribute__((address_space(1))) unsigned int*)(const void*)g,
                                   (__attribute__((address_space(3))) unsigned int*)(void*)l,
                                   16, 0, 0);
}

__device__ __forceinline__ void tf2(unsigned k0, unsigned k1, unsigned x0, unsigned x1,
                                    unsigned &o0, unsigned &o1){
  unsigned ks2 = k0 ^ k1 ^ 0x1BD11BDAu;
  x0 += k0; x1 += k1;
  #define RR(r) { x0 += x1; x1 = (x1 << (r)) | (x1 >> (32 - (r))); x1 ^= x0; }
  RR(13) RR(15) RR(26) RR(6)
  x0 += k1;  x1 += ks2 + 1u;
  RR(17) RR(29) RR(16) RR(24)
  x0 += ks2; x1 += k0 + 2u;
  RR(13) RR(15) RR(26) RR(6)
  x0 += k0;  x1 += k1 + 3u;
  RR(17) RR(29) RR(16) RR(24)
  x0 += k1;  x1 += ks2 + 4u;
  RR(13) RR(15) RR(26) RR(6)
  x0 += ks2; x1 += k0 + 5u;
  #undef RR
  o0 = x0; o1 = x1;
}

// ---------------- fallback: zero output (ws too small diagnostic) ----------------
__global__ __launch_bounds__(256) void k_zero(float* out, int n){
  int i = blockIdx.x*256 + threadIdx.x;
  if (i < n) out[i] = 0.f;
}

// ---------------- idx precompute ----------------
__global__ __launch_bounds__(256) void k_idx(int* idx0, int* idx1){
  int tid = threadIdx.x;
  unsigned a0,a1,c0,c1;
  tf2(0u,42u, 0u,0u, a0,a1);
  tf2(0u,42u, 0u,1u, c0,c1);
  for (int f = tid; f < 3200; f += 256){
    unsigned y0,y1;
#if IDX_MODE==0
    tf2(a0,a1, 0u, (unsigned)(3200+f), y0,y1); idx0[f] = (int)(y1 & 127u);
#elif IDX_MODE==1
    tf2(a0,a1, 0u, (unsigned)(3200+f), y0,y1); idx0[f] = (int)(y0 & 127u);
#elif IDX_MODE==2
    tf2(a0,a1, (unsigned)f, (unsigned)(3200+f), y0,y1); idx0[f] = (int)(y1 & 127u);
#else
    tf2(a0,a1, (unsigned)f, (unsigned)(3200+f), y0,y1); idx0[f] = (int)(y0 & 127u);
#endif
  }
  for (int f = tid; f < 1600; f += 256){
    unsigned y0,y1;
#if IDX_MODE==0
    tf2(c0,c1, 0u, (unsigned)(1600+f), y0,y1); idx1[f] = (int)(y1 & 63u);
#elif IDX_MODE==1
    tf2(c0,c1, 0u, (unsigned)(1600+f), y0,y1); idx1[f] = (int)(y0 & 63u);
#elif IDX_MODE==2
    tf2(c0,c1, (unsigned)f, (unsigned)(1600+f), y0,y1); idx1[f] = (int)(y1 & 63u);
#else
    tf2(c0,c1, (unsigned)f, (unsigned)(1600+f), y0,y1); idx1[f] = (int)(y0 & 63u);
#endif
  }
}

// ---------------- token_w -> bf16 [n=e][k=q*75+c] (K padded to 256) ----------------
__global__ __launch_bounds__(256) void k_wemb(fp token_w, u16* we){
  int i = blockIdx.x*256 + threadIdx.x;
  if (i < 128*256){
    int n = i >> 8, k = i & 255;
    float v = 0.f;
    if (k < 225){
      int q = k / 75, c = k - q*75;
      v = token_w[(size_t)n*225 + c*3 + q];
    }
    we[i] = f2bf(v);
  }
}

// ---------------- MFMA token-embed: conv(K=225) + pos + time, out emb[b][l][e] ----------------
__global__ __launch_bounds__(256) void k_emb_mfma(fp x_enc, fp x_mark, const u16* wemb,
                                                  fp time_w, fp time_b, float* emb){
  __shared__ __align__(16) u16 sA[128*264];   // 67,584 B
  const int tid = threadIdx.x;
  const int wave = tid >> 6, lane = tid & 63, quad = lane >> 4, l15 = lane & 15;
  const int b = blockIdx.x;
  for (int p = tid; p < 128*256; p += 256){
    int kk = p & 255, row = p >> 8;
    float v = 0.f;
    if (kk < 225){
      int q = kk / 75, c = kk - q*75;
      int sr = (row - 1 + q + 128) & 127;
      v = x_enc[((size_t)b*L0 + sr)*CIN + c];
    }
    sA[row*264 + kk] = f2bf(v);
  }
  __syncthreads();
  const f4v z4 = {0.f,0.f,0.f,0.f};
  f4v acc[2][8];
  #pragma unroll
  for (int m = 0; m < 2; m++)
    #pragma unroll
    for (int t = 0; t < 8; t++) acc[m][t] = z4;
  const int mBase = wave * 32;
  for (int ks = 0; ks < 8; ks++){
    s8v a0 = *reinterpret_cast<const s8v*>(sA + (mBase + l15)*264 + ks*32 + quad*8);
    s8v a1 = *reinterpret_cast<const s8v*>(sA + (mBase + 16 + l15)*264 + ks*32 + quad*8);
    const u16* wb = wemb + (size_t)l15*256 + ks*32 + quad*8;
    #pragma unroll
    for (int t = 0; t < 8; t++){
      s8v bfr = *reinterpret_cast<const s8v*>(wb + (size_t)t*16*256);
      acc[0][t] = __builtin_amdgcn_mfma_f32_16x16x32_bf16(a0, bfr, acc[0][t], 0, 0, 0);
      acc[1][t] = __builtin_amdgcn_mfma_f32_16x16x32_bf16(a1, bfr, acc[1][t], 0, 0, 0);
    }
  }
  #pragma unroll
  for (int t = 0; t < 8; t++){
    int col = t*16 + l15;
    int i2 = col >> 1;
    float div = __expf((float)(2*i2) * (-9.210340371976184f / 128.f));
    float tw0 = time_w[col], tw1 = time_w[128 + col], tw2 = time_w[256 + col];
    float tb = time_b[col];
    #pragma unroll
    for (int m = 0; m < 2; m++){
      #pragma unroll
      for (int r = 0; r < 4; r++){
        int row = mBase + m*16 + quad*4 + r;
        float ang = (float)row * div;
        float pe = (col & 1) ? cosf(ang) : sinf(ang);
        const float* mk = x_mark + ((size_t)b*L0 + row)*3;
        float tm = mk[0]*tw0 + mk[1]*tw1 + mk[2]*tw2 + tb;
        emb[((size_t)b*L0 + row)*DE + col] = acc[m][t][r] + pe + tm;
      }
    }
  }
}

// ---------------- per-batch attention scalars (emb layout [b][l][e]) ----------------
__global__ __launch_bounds__(128) void k_scalars(const float* emb, fp fcw, fp bng, fp bnb,
                                                 fp chw, fp chb, fp filw, fp filb,
                                                 fp spw, fp spb, fp kerw, fp kerb,
                                                 float* ch, float* fil, float* sp, float* ker){
  __shared__ float gap[DE];
  __shared__ float a[16];
  int b = blockIdx.x, t = threadIdx.x;
  float s = 0.f;
  for (int l = 0; l < L0; l++) s += emb[((size_t)b*L0 + l)*DE + t];
  gap[t] = s / (float)L0;
  __syncthreads();
  if (t < 16){
    float acc = 0.f;
    for (int e = 0; e < DE; e++) acc += gap[e]*fcw[e*16 + t];
    acc = acc * (bng[t] / sqrtf(1.f + 1e-5f)) + bnb[t];
    a[t] = fmaxf(acc, 0.f);
  }
  __syncthreads();
  float accc = 0.f, accf = 0.f;
  for (int c = 0; c < 16; c++){ accc += a[c]*chw[c*DE + t]; accf += a[c]*filw[c*DE + t]; }
  ch[b*DE + t]  = 1.f/(1.f + expf(-(accc + chb[t])));
  fil[b*DE + t] = 1.f/(1.f + expf(-(accf + filb[t])));
  if (t < 3){
    float acc = 0.f;
    for (int c = 0; c < 16; c++) acc += a[c]*spw[c*3 + t];
    sp[b*4 + t] = 1.f/(1.f + expf(-(acc + spb[t])));
  }
  if (t == 0){
    float v[4]; float mx = -1e30f;
    for (int n = 0; n < 4; n++){
      float acc = 0.f;
      for (int c = 0; c < 16; c++) acc += a[c]*kerw[c*4 + n];
      v[n] = acc + kerb[n]; mx = fmaxf(mx, v[n]);
    }
    float ss = 0.f;
    for (int n = 0; n < 4; n++){ v[n] = expf(v[n]-mx); ss += v[n]; }
    for (int n = 0; n < 4; n++) ker[b*4 + n] = v[n]/ss;
  }
}

// ---------------- MFMA ODConv: per-batch dyn weights, C[o][t]=sum_q Wq[o][:]*xcT[t+q][:] ----------------
__global__ __launch_bounds__(256) void k_odconv_mfma(const float* emb, fp odw,
                                                     const float* ch, const float* fil,
                                                     const float* sp, const float* ker, float* xout){
  __shared__ __align__(16) u16 sXT[130*136];     // xcT[l][i], rows 128/129 zero  (35,360 B)
  __shared__ __align__(16) u16 sW[3*128*136];    // Wq[o][i]                      (104,448 B)
  const int tid = threadIdx.x;
  const int wave = tid >> 6, lane = tid & 63, quad = lane >> 4, l15 = lane & 15;
  const int b = blockIdx.x;
  // stage xcT (coalesced in i)
  for (int p = tid; p < 130*128; p += 256){
    int l = p >> 7, i = p & 127;
    float v = 0.f;
    if (l < 128) v = emb[((size_t)b*L0 + l)*DE + i] * ch[b*DE + i];
    sXT[l*136 + i] = f2bf(v);
  }
  // build Wq[o][i] = sp[q] * sum_n ker[n]*odw[n][o][i][q], via coalesced float4 reads
  float kr0 = ker[b*4+0], kr1 = ker[b*4+1], kr2 = ker[b*4+2], kr3 = ker[b*4+3];
  float spv[3]; spv[0] = sp[b*4+0]; spv[1] = sp[b*4+1]; spv[2] = sp[b*4+2];
  const float4* od4 = (const float4*)odw;
  for (int p4 = tid; p4 < 128*384/4; p4 += 256){
    float4 w0 = od4[p4];
    float4 w1 = od4[12288 + p4];
    float4 w2 = od4[24576 + p4];
    float4 w3 = od4[36864 + p4];
    float vv[4] = { kr0*w0.x + kr1*w1.x + kr2*w2.x + kr3*w3.x,
                    kr0*w0.y + kr1*w1.y + kr2*w2.y + kr3*w3.y,
                    kr0*w0.z + kr1*w1.z + kr2*w2.z + kr3*w3.z,
                    kr0*w0.w + kr1*w1.w + kr2*w2.w + kr3*w3.w };
    int e0 = p4*4;
    #pragma unroll
    for (int j = 0; j < 4; j++){
      int e = e0 + j;
      int o = e / 384, rem = e - o*384;
      int i = rem / 3, q = rem - i*3;
      sW[(q*128 + o)*136 + i] = f2bf(vv[j] * spv[q]);
    }
  }
  __syncthreads();
  const f4v z4 = {0.f,0.f,0.f,0.f};
  f4v acc[2][8];
  #pragma unroll
  for (int m = 0; m < 2; m++)
    #pragma unroll
    for (int t = 0; t < 8; t++) acc[m][t] = z4;
  const int mBase = wave * 32;
  for (int q = 0; q < 3; q++){
    const u16* wq = sW + q*128*136;
    #pragma unroll
    for (int ks = 0; ks < 4; ks++){
      s8v a0 = *reinterpret_cast<const s8v*>(wq + (mBase + l15)*136 + ks*32 + quad*8);
      s8v a1 = *reinterpret_cast<const s8v*>(wq + (mBase + 16 + l15)*136 + ks*32 + quad*8);
      #pragma unroll
      for (int t = 0; t < 8; t++){
        s8v bfr = *reinterpret_cast<const s8v*>(sXT + (t*16 + l15 + q)*136 + ks*32 + quad*8);
        acc[0][t] = __builtin_amdgcn_mfma_f32_16x16x32_bf16(a0, bfr, acc[0][t], 0, 0, 0);
        acc[1][t] = __builtin_amdgcn_mfma_f32_16x16x32_bf16(a1, bfr, acc[1][t], 0, 0, 0);
      }
    }
  }
  // epilogue: xout[b][o][t] = fil[o]*acc ; C row=o (quad*4+r), col=t (l15)
  #pragma unroll
  for (int t = 0; t < 8; t++){
    int tt = t*16 + l15;
    if (tt < DM){
      #pragma unroll
      for (int m = 0; m < 2; m++){
        #pragma unroll
        for (int r = 0; r < 4; r++){
          int o = mBase + m*16 + quad*4 + r;
          xout[((size_t)b*DE + o)*DM + tt] = fil[b*DE + o] * acc[m][t][r];
        }
      }
    }
  }
}

// ---------------- QKV + O weights -> bf16 [n][k] + qkv bias ----------------
__global__ __launch_bounds__(256) void k_wqkv(fp qw, fp qb, fp kw, fp kb, fp vw, fp vb,
                                              fp ow, int layer, u16* wq, float* qbias, u16* wo){
  int i = blockIdx.x*256 + threadIdx.x;
  if (i < 384*128){
    int n = i >> 7, k = i & 127;
    int sec = n >> 7, nn = n & 127;
    const float* w = (sec == 0) ? qw : ((sec == 1) ? kw : vw);
    float v = (nn < DM && k < DM) ? w[((size_t)layer*DM + k)*DM + nn] : 0.f;
    wq[(size_t)n*128 + k] = f2bf(v);
  } else if (i < 384*128 + 384){
    int n = i - 384*128;
    int sec = n >> 7, nn = n & 127;
    const float* bp = (sec == 0) ? qb : ((sec == 1) ? kb : vb);
    qbias[n] = (nn < DM) ? bp[layer*DM + nn] : 0.f;
  } else if (i < 384*128 + 384 + 128*128){
    int j = i - (384*128 + 384);
    int n = j >> 7, k = j & 127;
    float v = (n < DM && k < DM) ? ow[(size_t)layer*DM*DM + k*DM + n] : 0.f;
    wo[(size_t)n*128 + k] = f2bf(v);
  }
}

// ---------------- fused QKV GEMM: qkv[M][384] ----------------
__global__ __launch_bounds__(256) void k_qkv_mfma(const float* xin, const u16* wqkv,
                                                  const float* qkvb, float* qkv){
  __shared__ __align__(16) u16 sX[64*136];
  const int tid = threadIdx.x;
  const int wave = tid >> 6, lane = tid & 63, quad = lane >> 4, l15 = lane & 15;
  const size_t rows0 = (size_t)blockIdx.x * 64;
  for (int p = tid; p < 64*128; p += 256){
    int r = p >> 7, c = p & 127;
    float v = (c < DM) ? xin[(rows0 + r)*DM + c] : 0.f;
    sX[r*136 + c] = f2bf(v);
  }
  __syncthreads();
  const f4v z4 = {0.f,0.f,0.f,0.f};
  f4v acc[24];
  #pragma unroll
  for (int t = 0; t < 24; t++) acc[t] = z4;
  const int m0 = wave * 16;
  #pragma unroll
  for (int ks = 0; ks < 4; ks++){
    s8v a = *reinterpret_cast<const s8v*>(sX + (m0 + l15)*136 + ks*32 + quad*8);
    const u16* wb = wqkv + (size_t)l15*128 + ks*32 + quad*8;
    #pragma unroll
    for (int t = 0; t < 24; t++){
      s8v b = *reinterpret_cast<const s8v*>(wb + (size_t)t*16*128);
      acc[t] = __builtin_amdgcn_mfma_f32_16x16x32_bf16(a, b, acc[t], 0, 0, 0);
    }
  }
  #pragma unroll
  for (int t = 0; t < 24; t++){
    int col = t*16 + l15;
    float bv = qkvb[col];
    #pragma unroll
    for (int r = 0; r < 4; r++){
      int row = m0 + quad*4 + r;
      qkv[(rows0 + row)*384 + col] = acc[t][r] + bv;
    }
  }
}

// ---------------- fused sparse attention (reads qkv[M][384]) ----------------
__global__ __launch_bounds__(128) void k_attn_fused(const float* qkv, const int* idx, int L,
                                                    float* vmean, int* posmap, float* upd){
  __shared__ float sQ[L0*DHd];
  __shared__ float sK[L0*DHd];
  __shared__ float sV[L0*DHd];
  __shared__ float qks[L0*NTOP];
  __shared__ float sM[L0];
  __shared__ float rv[L0];
  __shared__ int   ri[L0];
  __shared__ int   sel[L0];
  __shared__ int   stop[NTOP];
  __shared__ float red[128];
  int bh = blockIdx.x, t = threadIdx.x;
  int b = bh / NH, h = bh - b*NH;
  for (int p = t; p < L*DHd; p += 128){
    int l = p / DHd, d = p - l*DHd;
    const float* base = qkv + ((size_t)(b*L + l))*384 + h*DHd + d;
    sQ[p] = base[0]; sK[p] = base[128]; sV[p] = base[256];
  }
  posmap[bh*L0 + t] = -1;
  sel[t] = 0;
  __syncthreads();
  if (t < DHd){
    float s = 0.f;
    for (int l = 0; l < L; l++) s += sV[l*DHd + t];
    vmean[bh*DHd + t] = s / (float)L;
  }
  for (int p = t; p < L*NTOP; p += 128){
    int l = p / NTOP;
    int kk = idx[p];
    const float* q = sQ + l*DHd;
    const float* k = sK + kk*DHd;
    float acc = 0.f;
    for (int d = 0; d < DHd; d++) acc += q[d]*k[d];
    qks[p] = acc;
  }
  __syncthreads();
  if (t < L){
    float mx = -1e30f, sm = 0.f;
    for (int u = 0; u < NTOP; u++){ float v = qks[t*NTOP + u]; mx = fmaxf(mx, v); sm += v; }
    sM[t] = mx - sm / (float)L;
  } else {
    sM[t] = -1e30f;
  }
  __syncthreads();
  for (int it = 0; it < NTOP; it++){
    rv[t] = sel[t] ? -1e30f : sM[t];
    ri[t] = t;
    __syncthreads();
    for (int off = 64; off > 0; off >>= 1){
      if (t < off){
        float v2 = rv[t+off]; int i2 = ri[t+off];
        if (v2 > rv[t] || (v2 == rv[t] && i2 < ri[t])){ rv[t] = v2; ri[t] = i2; }
      }
      __syncthreads();
    }
    if (t == 0){ int w = ri[0]; sel[w] = 1; stop[it] = w; posmap[bh*L0 + w] = it; }
    __syncthreads();
  }
  for (int u = 0; u < NTOP; u++){
    int ls = stop[u];
    float s = -1e30f;
    if (t < L){
      const float* q = sQ + ls*DHd;
      const float* k = sK + t*DHd;
      float acc = 0.f;
      for (int d = 0; d < DHd; d++) acc += q[d]*k[d];
      s = acc / 4.58257569479392f;   // sqrt(21)
    }
    red[t] = s;
    __syncthreads();
    for (int off = 64; off > 0; off >>= 1){ if (t < off) red[t] = fmaxf(red[t], red[t+off]); __syncthreads(); }
    float mx = red[0];
    __syncthreads();
    float e = (t < L) ? expf(s - mx) : 0.f;
    rv[t] = e; red[t] = e;
    __syncthreads();
    for (int off = 64; off > 0; off >>= 1){ if (t < off) red[t] += red[t+off]; __syncthreads(); }
    float denom = red[0];
    __syncthreads();
    if (t < DHd){
      float acc = 0.f;
      for (int k2 = 0; k2 < L; k2++) acc += rv[k2]*sV[k2*DHd + t];
      upd[((size_t)bh*NTOP + u)*DHd + t] = acc / denom;
    }
    __syncthreads();
  }
}

// ---------------- MFMA O-proj + residual + LN1 (64 rows / block) ----------------
__global__ __launch_bounds__(256) void k_oproj_mfma(const float* xin, const float* vmean,
                                                    const int* posmap, const float* upd,
                                                    const u16* wo, fp ob, fp g, fp bb,
                                                    int layer, int lshift, int lmask, float* xmid){
  __shared__ __align__(16) float sOf[64*129];
  __shared__ float prs[128];
  __shared__ float smean[64], srstd[64];
  u16* sX = reinterpret_cast<u16*>(sOf);
  const int tid = threadIdx.x;
  const int wave = tid >> 6, lane = tid & 63, quad = lane >> 4, l15 = lane & 15;
  const int m0 = wave * 16;
  const size_t rows0 = (size_t)blockIdx.x * 64;
  for (int p = tid; p < 64*128; p += 256){
    int r = p >> 7, c = p & 127;
    int gr = (int)rows0 + r, b = gr >> lshift, l = gr & lmask;
    float v = 0.f;
    if (c < DM){
      int h = c / DHd, d = c - h*DHd;
      int bh = b*NH + h;
      int pos = posmap[bh*L0 + l];
      v = (pos >= 0) ? upd[((size_t)bh*NTOP + pos)*DHd + d] : vmean[bh*DHd + d];
    }
    sX[r*136 + c] = f2bf(v);
  }
  __syncthreads();
  const f4v z4 = {0.f,0.f,0.f,0.f};
  f4v acc[8];
  #pragma unroll
  for (int t = 0; t < 8; t++) acc[t] = z4;
  #pragma unroll
  for (int ks = 0; ks < 4; ks++){
    s8v a = *reinterpret_cast<const s8v*>(sX + (m0 + l15)*136 + ks*32 + quad*8);
    const u16* wb = wo + (size_t)l15*128 + ks*32 + quad*8;
    #pragma unroll
    for (int t = 0; t < 8; t++){
      s8v b = *reinterpret_cast<const s8v*>(wb + (size_t)t*16*128);
      acc[t] = __builtin_amdgcn_mfma_f32_16x16x32_bf16(a, b, acc[t], 0, 0, 0);
    }
  }
  __syncthreads();
  #pragma unroll
  for (int t = 0; t < 8; t++){
    int col = t*16 + l15;
    #pragma unroll
    for (int r = 0; r < 4; r++){
      sOf[(m0 + quad*4 + r)*129 + col] = acc[t][r];
    }
  }
  __syncthreads();
  const float* obl = ob + (size_t)layer*DM;
  for (int p = tid; p < 64*DM; p += 256){
    int r = p / DM, c = p - r*DM;
    sOf[r*129 + c] += xin[(rows0 + r)*DM + c] + obl[c];
  }
  __syncthreads();
  if (tid < 128){
    int row = tid >> 1, half = tid & 1;
    float s = 0.f;
    for (int c = half*63; c < half*63 + 63; c++) s += sOf[row*129 + c];
    prs[tid] = s;
  }
  __syncthreads();
  if (tid < 128 && (tid & 1) == 0) smean[tid>>1] = (prs[tid] + prs[tid+1]) / (float)DM;
  __syncthreads();
  if (tid < 128){
    int row = tid >> 1, half = tid & 1;
    float mn = smean[row];
    float s = 0.f;
    for (int c = half*63; c < half*63 + 63; c++){ float d = sOf[row*129 + c] - mn; s += d*d; }
    prs[tid] = s;
  }
  __syncthreads();
  if (tid < 128 && (tid & 1) == 0) srstd[tid>>1] = rsqrtf((prs[tid] + prs[tid+1])/(float)DM + 1e-5f);
  __syncthreads();
  const float* gl = g  + (size_t)layer*DM;
  const float* bl = bb + (size_t)layer*DM;
  for (int p = tid; p < 64*DM; p += 256){
    int r = p / DM, c = p - r*DM;
    xmid[(rows0 + r)*DM + c] = (sOf[r*129 + c] - smean[r])*srstd[r]*gl[c] + bl[c];
  }
}

// ---------------- FFN weights conversion ----------------
__global__ __launch_bounds__(256) void k_wconv(fp w1, fp w2, int layer, u16* w1t, u16* w2t){
  int i = blockIdx.x*256 + threadIdx.x;
  if (i < 2048*128){
    int n = i >> 7, k = i & 127;
    float v = (k < DM) ? w1[((size_t)layer*DM + k)*DFF + n] : 0.f;
    w1t[(size_t)n*128 + k] = f2bf(v);
  } else {
    int j = i - 2048*128;
    int n = j >> 11, f = j & 2047;
    float v = (n < DM) ? w2[((size_t)layer*DFF + f)*DM + n] : 0.f;
    w2t[(size_t)n*2048 + f] = f2bf(v);
  }
}

// GELU exact via Abramowitz-Stegun 7.1.26 erf (max err ~1.5e-7)
__device__ __forceinline__ float gelu_as(float x){
  float z  = 0.7071067811865475f * x;
  float zn = fabsf(z);
  float t  = 1.f / (1.f + 0.3275911f * zn);
  float p  = ((((1.061405429f*t - 1.453152027f)*t + 1.421413741f)*t - 0.284496736f)*t + 0.254829592f)*t;
  float ea = 1.f - p * __expf(-zn*zn);
  float er = (z < 0.f) ? -ea : ea;
  return 0.5f * x * (1.f + er);
}

// ---------------- MFMA FFN + residual + LN2 — LDS-pipelined weights ----------------
#define FFN_SMEM_U16 (8704 + 4608 + 3*8192)

__device__ __forceinline__ void stage_w1(const u16* w1t, int j, u16* buf, int wave, int lane){
  #pragma unroll
  for (int r = 0; r < 4; r++){
    int p = r*256 + wave*64 + lane;
    int n = p >> 4, c = p & 15;
    int cg = c ^ (n & 7);
    const u16* g = w1t + (((size_t)(j*64 + n)) << 7) + cg*8;
    u16* l = buf + (size_t)(r*256 + wave*64)*8;
    gld_lds16(g, l);
  }
}
__device__ __forceinline__ void stage_w2(const u16* w2t, int j, u16* buf, int wave, int lane){
  #pragma unroll
  for (int r = 0; r < 4; r++){
    int p = r*256 + wave*64 + lane;
    int n = p >> 3, c = p & 7;
    int cg = c ^ (n & 7);
    const u16* g = w2t + (size_t)n*2048 + j*64 + cg*8;
    u16* l = buf + (size_t)(r*256 + wave*64)*8;
    gld_lds16(g, l);
  }
}

__global__ __launch_bounds__(256) void k_ffn_mfma(const float* xmid, const u16* w1t, const u16* w2t,
                                                  fp b1, fp b2w, fp g, fp bb, int layer, float* xout){
  __shared__ __align__(16) u16 smem[FFN_SMEM_U16];
  __shared__ float prs[128];
  __shared__ float smean[64], srstd[64];
  u16* sX  = smem;
  u16* wA0 = smem + 8704 + 4608;
  u16* wA1 = wA0 + 8192;
  u16* wBf = wA1 + 8192;
  const int tid  = threadIdx.x;
  const int wave = tid >> 6, lane = tid & 63, quad = lane >> 4, l15 = lane & 15;
  const int m0 = wave * 16;
  u16* sYw = smem + 8704 + wave*1152;
  const size_t rows0 = (size_t)blockIdx.x * 64;

  for (int p = tid; p < 64*128; p += 256){
    int r = p >> 7, c = p & 127;
    float v = (c < DM) ? xmid[(rows0 + r)*DM + c] : 0.f;
    sX[r*136 + c] = f2bf(v);
  }
  stage_w1(w1t, 0, wA0, wave, lane);
  stage_w2(w2t, 0, wBf, wave, lane);
  __syncthreads();

  const float* b1l = b1 + (size_t)layer*DFF;
  const f4v z4 = {0.f, 0.f, 0.f, 0.f};
  f4v acc2[8];
  #pragma unroll
  for (int t = 0; t < 8; t++) acc2[t] = z4;

  for (int j = 0; j < 32; j++){
    u16* wAcur = (j & 1) ? wA1 : wA0;
    u16* wAnext = (j & 1) ? wA0 : wA1;
    if (j < 31) stage_w1(w1t, j+1, wAnext, wave, lane);
    f4v acc1[4];
    #pragma unroll
    for (int t = 0; t < 4; t++) acc1[t] = z4;
    #pragma unroll
    for (int ks = 0; ks < 4; ks++){
      s8v a = *reinterpret_cast<const s8v*>(sX + (m0 + l15)*136 + ks*32 + quad*8);
      #pragma unroll
      for (int t = 0; t < 4; t++){
        int nloc = t*16 + l15;
        int cg = (ks*4 + quad) ^ (nloc & 7);
        s8v b = *reinterpret_cast<const s8v*>(wAcur + nloc*128 + cg*8);
        acc1[t] = __builtin_amdgcn_mfma_f32_16x16x32_bf16(a, b, acc1[t], 0, 0, 0);
      }
    }
    #pragma unroll
    for (int t = 0; t < 4; t++){
      float bv = b1l[j*64 + t*16 + l15];
      #pragma unroll
      for (int r = 0; r < 4; r++){
        float v = gelu_as(acc1[t][r] + bv);
        sYw[(quad*4 + r)*72 + t*16 + l15] = f2bf(v);
      }
    }
    __syncthreads();
    #pragma unroll
    for (int ks = 0; ks < 2; ks++){
      s8v a2 = *reinterpret_cast<const s8v*>(sYw + l15*72 + ks*32 + quad*8);
      #pragma unroll
      for (int t = 0; t < 8; t++){
        int nloc = t*16 + l15;
        int cg = (ks*4 + quad) ^ (nloc & 7);
        s8v b = *reinterpret_cast<const s8v*>(wBf + nloc*64 + cg*8);
        acc2[t] = __builtin_amdgcn_mfma_f32_16x16x32_bf16(a2, b, acc2[t], 0, 0, 0);
      }
    }
    __syncthreads();
    if (j < 31) stage_w2(w2t, j+1, wBf, wave, lane);
  }

  float* sO = reinterpret_cast<float*>(smem);
  #pragma unroll
  for (int t = 0; t < 8; t++){
    int col = t*16 + l15;
    #pragma unroll
    for (int r = 0; r < 4; r++){
      sO[(m0 + quad*4 + r)*129 + col] = acc2[t][r];
    }
  }
  __syncthreads();
  const float* b2l = b2w + (size_t)layer*DM;
  for (int p = tid; p < 64*DM; p += 256){
    int r = p / DM, c = p - r*DM;
    sO[r*129 + c] += b2l[c] + xmid[(rows0 + r)*DM + c];
  }
  __syncthreads();
  if (tid < 128){
    int row = tid >> 1, half = tid & 1;
    float s = 0.f;
    for (int c = half*63; c < half*63 + 63; c++) s += sO[row*129 + c];
    prs[tid] = s;
  }
  __syncthreads();
  if (tid < 128 && (tid & 1) == 0) smean[tid>>1] = (prs[tid] + prs[tid+1]) / (float)DM;
  __syncthreads();
  if (tid < 128){
    int row = tid >> 1, half = tid & 1;
    float mn = smean[row];
    float s = 0.f;
    for (int c = half*63; c < half*63 + 63; c++){ float d = sO[row*129 + c] - mn; s += d*d; }
    prs[tid] = s;
  }
  __syncthreads();
  if (tid < 128 && (tid & 1) == 0) srstd[tid>>1] = rsqrtf((prs[tid] + prs[tid+1])/(float)DM + 1e-5f);
  __syncthreads();
  const float* gl = g  + (size_t)layer*DM;
  const float* bl = bb + (size_t)layer*DM;
  for (int p = tid; p < 64*DM; p += 256){
    int r = p / DM, c = p - r*DM;
    xout[(rows0 + r)*DM + c] = (sO[r*129 + c] - smean[r])*srstd[r]*gl[c] + bl[c];
  }
}

// ---------------- distil weights -> bf16 [n=co][k=q*126+ci] ----------------
__global__ __launch_bounds__(256) void k_wdist(fp clw, u16* wd){
  int i = blockIdx.x*256 + threadIdx.x;
  if (i < 128*384){
    int n = i / 384, k = i - n*384;
    float v = 0.f;
    if (n < DM && k < 378){
      int q = k / 126, ci = k - q*126;
      v = clw[((size_t)n*DM + ci)*3 + q];
    }
    wd[i] = f2bf(v);
  }
}

// ---------------- MFMA distil: conv(K=378) + BN + ELU + maxpool ----------------
__global__ __launch_bounds__(256) void k_distill_mfma(const float* xin, const u16* wdist,
                                                      fp clb, fp bng, fp bnb, float* xout){
  __shared__ __align__(16) u16 sA[128*392];
  const int tid = threadIdx.x;
  const int wave = tid >> 6, lane = tid & 63, quad = lane >> 4, l15 = lane & 15;
  const int b = blockIdx.x;
  for (int row = wave; row < 128; row += 4){
    #pragma unroll
    for (int e = 0; e < 6; e++){
      int kk = lane + e*64;
      float v = 0.f;
      if (kk < 378){
        int q = kk / 126, ci = kk - q*126;
        int sr = (row - 1 + q + 128) & 127;
        v = xin[((size_t)b*128 + sr)*DM + ci];
      }
      sA[row*392 + kk] = f2bf(v);
    }
  }
  __syncthreads();
  const f4v z4 = {0.f,0.f,0.f,0.f};
  f4v acc[2][8];
  #pragma unroll
  for (int m = 0; m < 2; m++)
    #pragma unroll
    for (int t = 0; t < 8; t++) acc[m][t] = z4;
  const int mBase = wave * 32;
  for (int ks = 0; ks < 12; ks++){
    s8v a0 = *reinterpret_cast<const s8v*>(sA + (mBase + l15)*392 + ks*32 + quad*8);
    s8v a1 = *reinterpret_cast<const s8v*>(sA + (mBase + 16 + l15)*392 + ks*32 + quad*8);
    const u16* wb = wdist + (size_t)l15*384 + ks*32 + quad*8;
    #pragma unroll
    for (int t = 0; t < 8; t++){
      s8v bfr = *reinterpret_cast<const s8v*>(wb + (size_t)t*16*384);
      acc[0][t] = __builtin_amdgcn_mfma_f32_16x16x32_bf16(a0, bfr, acc[0][t], 0, 0, 0);
      acc[1][t] = __builtin_amdgcn_mfma_f32_16x16x32_bf16(a1, bfr, acc[1][t], 0, 0, 0);
    }
  }
  __syncthreads();
  float* zsh = reinterpret_cast<float*>(sA);   // [128][130]
  const float bnscale = 1.f / sqrtf(1.f + 1e-5f);
  #pragma unroll
  for (int t = 0; t < 8; t++){
    int co = t*16 + l15;
    if (co < DM){
      float cb = clb[co];
      float gg = bng[co] * bnscale, bv = bnb[co];
      #pragma unroll
      for (int m = 0; m < 2; m++){
        #pragma unroll
        for (int r = 0; r < 4; r++){
          int row = mBase + m*16 + quad*4 + r;
          float z = (acc[m][t][r] + cb)*gg + bv;
          z = (z > 0.f) ? z : expm1f(z);
          zsh[row*130 + co] = z;
        }
      }
    }
  }
  __syncthreads();
  for (int p = tid; p < 64*DM; p += 256){
    int j = p / DM, co = p - j*DM;
    float best = zsh[(2*j)*130 + co];
    if (j > 0) best = fmaxf(best, zsh[(2*j - 1)*130 + co]);
    best = fmaxf(best, zsh[(2*j + 1)*130 + co]);
    xout[((size_t)b*64 + j)*DM + co] = best;
  }
}

// ---------------- final LN + fc ----------------
__global__ __launch_bounds__(128) void k_final(const float* xin, fp g, fp bb,
                                               fp fcw, fp fcb, float* out){
  __shared__ float xs[64][DM];
  __shared__ float mean_s[64], rstd_s[64];
  int b = blockIdx.x, t = threadIdx.x;
  for (int p = t; p < 64*DM; p += 128){ xs[p/DM][p%DM] = xin[(size_t)b*64*DM + p]; }
  __syncthreads();
  if (t < 64){
    float s = 0.f;
    for (int m = 0; m < DM; m++) s += xs[t][m];
    float mn = s / (float)DM;
    float v = 0.f;
    for (int m = 0; m < DM; m++){ float d = xs[t][m] - mn; v += d*d; }
    mean_s[t] = mn; rstd_s[t] = rsqrtf(v / (float)DM + 1e-5f);
  }
  __syncthreads();
  if (t < DM){
    float gv = g[t], bv = bb[t];
    float acc = fcb[0];
    for (int l = 0; l < 64; l++){
      float xn = (xs[l][t] - mean_s[l])*rstd_s[l]*gv + bv;
      acc += xn * fcw[l];
    }
    out[b*DM + t] = acc;
  }
}

// ---------------- host launcher ----------------
extern "C" void kernel_launch(void* const* d_in, const int* in_sizes, int n_in,
                              void* d_out, int out_size, void* d_ws, size_t ws_size,
                              hipStream_t stream) {
  fp x_enc   = (fp)d_in[0];
  fp x_mark  = (fp)d_in[1];
  fp token_w = (fp)d_in[2];
  fp time_w  = (fp)d_in[3];
  fp time_b  = (fp)d_in[4];
  fp od_fc_w = (fp)d_in[5];
  fp od_bn_g = (fp)d_in[6];
  fp od_bn_b = (fp)d_in[7];
  fp od_ch_w = (fp)d_in[8];
  fp od_ch_b = (fp)d_in[9];
  fp od_fil_w= (fp)d_in[10];
  fp od_fil_b= (fp)d_in[11];
  fp od_sp_w = (fp)d_in[12];
  fp od_sp_b = (fp)d_in[13];
  fp od_ker_w= (fp)d_in[14];
  fp od_ker_b= (fp)d_in[15];
  fp od_wt   = (fp)d_in[16];
  fp q_w = (fp)d_in[17]; fp q_b = (fp)d_in[18];
  fp k_w = (fp)d_in[19]; fp k_b = (fp)d_in[20];
  fp v_w = (fp)d_in[21]; fp v_b = (fp)d_in[22];
  fp o_w = (fp)d_in[23]; fp o_b = (fp)d_in[24];
  fp f1w = (fp)d_in[25]; fp f1b = (fp)d_in[26];
  fp f2w = (fp)d_in[27]; fp f2b = (fp)d_in[28];
  fp ln1g= (fp)d_in[29]; fp ln1b= (fp)d_in[30];
  fp ln2g= (fp)d_in[31]; fp ln2b= (fp)d_in[32];
  fp cl_w= (fp)d_in[33]; fp cl_b= (fp)d_in[34];
  fp clbg= (fp)d_in[35]; fp clbb= (fp)d_in[36];
  fp elng= (fp)d_in[37]; fp elnb= (fp)d_in[38];
  fp fc_w= (fp)d_in[39]; fp fc_b= (fp)d_in[40];

  // ---- workspace layout (float units) ----
  const size_t OFF_IDX0 = 0;
  const size_t OFF_IDX1 = OFF_IDX0 + 3200;
  const size_t OFF_CH   = OFF_IDX1 + 1600;
  const size_t OFF_FIL  = OFF_CH  + (size_t)NB*DE;
  const size_t OFF_SP   = OFF_FIL + (size_t)NB*DE;
  const size_t OFF_KER  = OFF_SP  + (size_t)NB*4;
  const size_t OFF_VM   = OFF_KER + (size_t)NB*4;
  const size_t OFF_POS  = OFF_VM  + (size_t)NB*NH*DHd;
  const size_t OFF_UPD  = OFF_POS + (size_t)NB*NH*L0;
  const size_t OFF_WTS  = (OFF_UPD + (size_t)NB*NH*NTOP*DHd + 255) & ~(size_t)255;
  const size_t WTS_FLOATS = (262144 + 262144 + 49152 + 49152 + 16384 + 32768)/2 + 384;
  const size_t OFF_BIG  = (OFF_WTS + WTS_FLOATS + 255) & ~(size_t)255;
  const size_t SBUF     = (size_t)NB*DE*L0;
  const size_t TOTAL    = OFF_BIG + 4*SBUF;

  if (ws_size < TOTAL*sizeof(float)){
    hipLaunchKernelGGL(k_zero, dim3((out_size+255)/256), dim3(256), 0, stream,
                       (float*)d_out, out_size);
    return;
  }

  float* ws = (float*)d_ws;
  int* idx0 = (int*)(ws + OFF_IDX0);
  int* idx1 = (int*)(ws + OFF_IDX1);
  float* chv = ws + OFF_CH;
  float* filv= ws + OFF_FIL;
  float* spv = ws + OFF_SP;
  float* kerv= ws + OFF_KER;
  float* vme = ws + OFF_VM;
  int* posm  = (int*)(ws + OFF_POS);
  float* updb= ws + OFF_UPD;
  u16* w1tb  = (u16*)(ws + OFF_WTS);
  u16* w2tb  = w1tb + 262144;
  u16* wqkvb = w2tb + 262144;
  u16* wdistb= wqkvb + 49152;
  u16* wob   = wdistb + 49152;
  u16* wembb = wob + 16384;
  float* qkvbias = (float*)(wembb + 32768);

  float* X    = ws + OFF_BIG;
  float* QKV  = X + SBUF;
  float* emb  = QKV;
  float* xmid = QKV;
  float* ffno = QKV + SBUF;

  hipLaunchKernelGGL(k_idx, dim3(1), dim3(256), 0, stream, idx0, idx1);
  hipLaunchKernelGGL(k_wemb, dim3(128), dim3(256), 0, stream, token_w, wembb);
  hipLaunchKernelGGL(k_emb_mfma, dim3(NB), dim3(256), 0, stream,
                     x_enc, x_mark, wembb, time_w, time_b, emb);
  hipLaunchKernelGGL(k_scalars, dim3(NB), dim3(128), 0, stream,
                     emb, od_fc_w, od_bn_g, od_bn_b, od_ch_w, od_ch_b, od_fil_w, od_fil_b,
                     od_sp_w, od_sp_b, od_ker_w, od_ker_b, chv, filv, spv, kerv);
  hipLaunchKernelGGL(k_odconv_mfma, dim3(NB), dim3(256), 0, stream,
                     emb, od_wt, chv, filv, spv, kerv, X);
  hipLaunchKernelGGL(k_wdist, dim3(192), dim3(256), 0, stream, cl_w, wdistb);

  // ----- layer 0 (L=128) -----
  hipLaunchKernelGGL(k_wqkv, dim3(258), dim3(256), 0, stream,
                     q_w, q_b, k_w, k_b, v_w, v_b, o_w, 0, wqkvb, qkvbias, wob);
  hipLaunchKernelGGL(k_qkv_mfma, dim3(NB*L0/64), dim3(256), 0, stream,
                     X, wqkvb, qkvbias, QKV);
  hipLaunchKernelGGL(k_attn_fused, dim3(NB*NH), dim3(128), 0, stream,
                     QKV, idx0, L0, vme, posm, updb);
  hipLaunchKernelGGL(k_oproj_mfma, dim3(NB*L0/64), dim3(256), 0, stream,
                     X, vme, posm, updb, wob, o_b, ln1g, ln1b, 0, 7, 127, xmid);
  hipLaunchKernelGGL(k_wconv, dim3(2048), dim3(256), 0, stream, f1w, f2w, 0, w1tb, w2tb);
  hipLaunchKernelGGL(k_ffn_mfma, dim3(NB*L0/64), dim3(256), 0, stream,
                     xmid, w1tb, w2tb, f1b, f2b, ln2g, ln2b, 0, ffno);

  // ----- distil -----
  hipLaunchKernelGGL(k_distill_mfma, dim3(NB), dim3(256), 0, stream,
                     ffno, wdistb, cl_b, clbg, clbb, X);

  // ----- layer 1 (L=64) -----
  hipLaunchKernelGGL(k_wqkv, dim3(258), dim3(256), 0, stream,
                     q_w, q_b, k_w, k_b, v_w, v_b, o_w, 1, wqkvb, qkvbias, wob);
  hipLaunchKernelGGL(k_qkv_mfma, dim3(NB*64/64), dim3(256), 0, stream,
                     X, wqkvb, qkvbias, QKV);
  hipLaunchKernelGGL(k_attn_fused, dim3(NB*NH), dim3(128), 0, stream,
                     QKV, idx1, 64, vme, posm, updb);
  hipLaunchKernelGGL(k_oproj_mfma, dim3(NB*64/64), dim3(256), 0, stream,
                     X, vme, posm, updb, wob, o_b, ln1g, ln1b, 1, 6, 63, xmid);
  hipLaunchKernelGGL(k_wconv, dim3(2048), dim3(256), 0, stream, f1w, f2w, 1, w1tb, w2tb);
  hipLaunchKernelGGL(k_ffn_mfma, dim3(NB*64/64), dim3(256), 0, stream,
                     xmid, w1tb, w2tb, f1b, f2b, ln2g, ln2b, 1, ffno);

  hipLaunchKernelGGL(k_final, dim3(NB), dim3(128), 0, stream,
                     ffno, elng, elnb, fc_w, fc_b, (float*)d_out);
  (void)in_sizes; (void)n_in; (void)out_size; (void)ws_size;
}

// Round 9
// 915.138 us; speedup vs baseline: 4.5464x; 1.1905x over previous
//
#include <hip/hip_runtime.h>
#include <math.h>

// Problem dims
#define NB 256
#define DM 126       // D_MODEL
#define DE 128       // D_EMB
#define NH 6
#define DHd 21
#define DFF 2048
#define CIN 75
#define L0 128
#define NTOP 25

#ifndef IDX_MODE
#define IDX_MODE 0
#endif

typedef const float* fp;
typedef unsigned short u16;
typedef short s8v __attribute__((ext_vector_type(8)));
typedef float f4v __attribute__((ext_vector_type(4)));

__device__ __forceinline__ u16 f2bf(float x){
  unsigned u = __float_as_uint(x);
  unsigned r = (u + 0x7FFFu + ((u >> 16) & 1u)) >> 16;
  return (u16)r;
}
__device__ __forceinline__ float bf2f(u16 v){
  unsigned uu = ((unsigned)v) << 16;
  return __uint_as_float(uu);
}

__device__ __forceinline__ void gld_lds16(const u16* g, u16* l){
  __builtin_amdgcn_global_load_lds((const __attribute__((address_space(1))) unsigned int*)(const void*)g,
                                   (__attribute__((address_space(3))) unsigned int*)(void*)l,
                                   16, 0, 0);
}

__device__ __forceinline__ void tf2(unsigned k0, unsigned k1, unsigned x0, unsigned x1,
                                    unsigned &o0, unsigned &o1){
  unsigned ks2 = k0 ^ k1 ^ 0x1BD11BDAu;
  x0 += k0; x1 += k1;
  #define RR(r) { x0 += x1; x1 = (x1 << (r)) | (x1 >> (32 - (r))); x1 ^= x0; }
  RR(13) RR(15) RR(26) RR(6)
  x0 += k1;  x1 += ks2 + 1u;
  RR(17) RR(29) RR(16) RR(24)
  x0 += ks2; x1 += k0 + 2u;
  RR(13) RR(15) RR(26) RR(6)
  x0 += k0;  x1 += k1 + 3u;
  RR(17) RR(29) RR(16) RR(24)
  x0 += k1;  x1 += ks2 + 4u;
  RR(13) RR(15) RR(26) RR(6)
  x0 += ks2; x1 += k0 + 5u;
  #undef RR
  o0 = x0; o1 = x1;
}

// ---------------- fallback: zero output (ws too small diagnostic) ----------------
__global__ __launch_bounds__(256) void k_zero(float* out, int n){
  int i = blockIdx.x*256 + threadIdx.x;
  if (i < n) out[i] = 0.f;
}

// ---------------- idx precompute ----------------
__global__ __launch_bounds__(256) void k_idx(int* idx0, int* idx1){
  int tid = threadIdx.x;
  unsigned a0,a1,c0,c1;
  tf2(0u,42u, 0u,0u, a0,a1);
  tf2(0u,42u, 0u,1u, c0,c1);
  for (int f = tid; f < 3200; f += 256){
    unsigned y0,y1;
#if IDX_MODE==0
    tf2(a0,a1, 0u, (unsigned)(3200+f), y0,y1); idx0[f] = (int)(y1 & 127u);
#elif IDX_MODE==1
    tf2(a0,a1, 0u, (unsigned)(3200+f), y0,y1); idx0[f] = (int)(y0 & 127u);
#elif IDX_MODE==2
    tf2(a0,a1, (unsigned)f, (unsigned)(3200+f), y0,y1); idx0[f] = (int)(y1 & 127u);
#else
    tf2(a0,a1, (unsigned)f, (unsigned)(3200+f), y0,y1); idx0[f] = (int)(y0 & 127u);
#endif
  }
  for (int f = tid; f < 1600; f += 256){
    unsigned y0,y1;
#if IDX_MODE==0
    tf2(c0,c1, 0u, (unsigned)(1600+f), y0,y1); idx1[f] = (int)(y1 & 63u);
#elif IDX_MODE==1
    tf2(c0,c1, 0u, (unsigned)(1600+f), y0,y1); idx1[f] = (int)(y0 & 63u);
#elif IDX_MODE==2
    tf2(c0,c1, (unsigned)f, (unsigned)(1600+f), y0,y1); idx1[f] = (int)(y1 & 63u);
#else
    tf2(c0,c1, (unsigned)f, (unsigned)(1600+f), y0,y1); idx1[f] = (int)(y0 & 63u);
#endif
  }
}

// ---------------- token_w -> bf16 [n=e][k=q*75+c] (K padded to 256) ----------------
__global__ __launch_bounds__(256) void k_wemb(fp token_w, u16* we){
  int i = blockIdx.x*256 + threadIdx.x;
  if (i < 128*256){
    int n = i >> 8, k = i & 255;
    float v = 0.f;
    if (k < 225){
      int q = k / 75, c = k - q*75;
      v = token_w[(size_t)n*225 + c*3 + q];
    }
    we[i] = f2bf(v);
  }
}

// ---------------- MFMA token-embed: conv(K=225) + pos + time, out emb[b][l][e] ----------------
__global__ __launch_bounds__(256) void k_emb_mfma(fp x_enc, fp x_mark, const u16* wemb,
                                                  fp time_w, fp time_b, float* emb){
  __shared__ __align__(16) u16 sA[128*264];   // 67,584 B
  const int tid = threadIdx.x;
  const int wave = tid >> 6, lane = tid & 63, quad = lane >> 4, l15 = lane & 15;
  const int b = blockIdx.x;
  for (int p = tid; p < 128*256; p += 256){
    int kk = p & 255, row = p >> 8;
    float v = 0.f;
    if (kk < 225){
      int q = kk / 75, c = kk - q*75;
      int sr = (row - 1 + q + 128) & 127;
      v = x_enc[((size_t)b*L0 + sr)*CIN + c];
    }
    sA[row*264 + kk] = f2bf(v);
  }
  __syncthreads();
  const f4v z4 = {0.f,0.f,0.f,0.f};
  f4v acc[2][8];
  #pragma unroll
  for (int m = 0; m < 2; m++)
    #pragma unroll
    for (int t = 0; t < 8; t++) acc[m][t] = z4;
  const int mBase = wave * 32;
  for (int ks = 0; ks < 8; ks++){
    s8v a0 = *reinterpret_cast<const s8v*>(sA + (mBase + l15)*264 + ks*32 + quad*8);
    s8v a1 = *reinterpret_cast<const s8v*>(sA + (mBase + 16 + l15)*264 + ks*32 + quad*8);
    const u16* wb = wemb + (size_t)l15*256 + ks*32 + quad*8;
    #pragma unroll
    for (int t = 0; t < 8; t++){
      s8v bfr = *reinterpret_cast<const s8v*>(wb + (size_t)t*16*256);
      acc[0][t] = __builtin_amdgcn_mfma_f32_16x16x32_bf16(a0, bfr, acc[0][t], 0, 0, 0);
      acc[1][t] = __builtin_amdgcn_mfma_f32_16x16x32_bf16(a1, bfr, acc[1][t], 0, 0, 0);
    }
  }
  #pragma unroll
  for (int t = 0; t < 8; t++){
    int col = t*16 + l15;
    int i2 = col >> 1;
    float div = __expf((float)(2*i2) * (-9.210340371976184f / 128.f));
    float tw0 = time_w[col], tw1 = time_w[128 + col], tw2 = time_w[256 + col];
    float tb = time_b[col];
    #pragma unroll
    for (int m = 0; m < 2; m++){
      #pragma unroll
      for (int r = 0; r < 4; r++){
        int row = mBase + m*16 + quad*4 + r;
        float ang = (float)row * div;
        float pe = (col & 1) ? cosf(ang) : sinf(ang);
        const float* mk = x_mark + ((size_t)b*L0 + row)*3;
        float tm = mk[0]*tw0 + mk[1]*tw1 + mk[2]*tw2 + tb;
        emb[((size_t)b*L0 + row)*DE + col] = acc[m][t][r] + pe + tm;
      }
    }
  }
}

// ---------------- per-batch attention scalars (emb layout [b][l][e]) ----------------
__global__ __launch_bounds__(128) void k_scalars(const float* emb, fp fcw, fp bng, fp bnb,
                                                 fp chw, fp chb, fp filw, fp filb,
                                                 fp spw, fp spb, fp kerw, fp kerb,
                                                 float* ch, float* fil, float* sp, float* ker){
  __shared__ float gap[DE];
  __shared__ float a[16];
  int b = blockIdx.x, t = threadIdx.x;
  float s = 0.f;
  for (int l = 0; l < L0; l++) s += emb[((size_t)b*L0 + l)*DE + t];
  gap[t] = s / (float)L0;
  __syncthreads();
  if (t < 16){
    float acc = 0.f;
    for (int e = 0; e < DE; e++) acc += gap[e]*fcw[e*16 + t];
    acc = acc * (bng[t] / sqrtf(1.f + 1e-5f)) + bnb[t];
    a[t] = fmaxf(acc, 0.f);
  }
  __syncthreads();
  float accc = 0.f, accf = 0.f;
  for (int c = 0; c < 16; c++){ accc += a[c]*chw[c*DE + t]; accf += a[c]*filw[c*DE + t]; }
  ch[b*DE + t]  = 1.f/(1.f + expf(-(accc + chb[t])));
  fil[b*DE + t] = 1.f/(1.f + expf(-(accf + filb[t])));
  if (t < 3){
    float acc = 0.f;
    for (int c = 0; c < 16; c++) acc += a[c]*spw[c*3 + t];
    sp[b*4 + t] = 1.f/(1.f + expf(-(acc + spb[t])));
  }
  if (t == 0){
    float v[4]; float mx = -1e30f;
    for (int n = 0; n < 4; n++){
      float acc = 0.f;
      for (int c = 0; c < 16; c++) acc += a[c]*kerw[c*4 + n];
      v[n] = acc + kerb[n]; mx = fmaxf(mx, v[n]);
    }
    float ss = 0.f;
    for (int n = 0; n < 4; n++){ v[n] = expf(v[n]-mx); ss += v[n]; }
    for (int n = 0; n < 4; n++) ker[b*4 + n] = v[n]/ss;
  }
}

// ---------------- MFMA ODConv ----------------
__global__ __launch_bounds__(256) void k_odconv_mfma(const float* emb, fp odw,
                                                     const float* ch, const float* fil,
                                                     const float* sp, const float* ker, float* xout){
  __shared__ __align__(16) u16 sXT[130*136];
  __shared__ __align__(16) u16 sW[3*128*136];
  const int tid = threadIdx.x;
  const int wave = tid >> 6, lane = tid & 63, quad = lane >> 4, l15 = lane & 15;
  const int b = blockIdx.x;
  for (int p = tid; p < 130*128; p += 256){
    int l = p >> 7, i = p & 127;
    float v = 0.f;
    if (l < 128) v = emb[((size_t)b*L0 + l)*DE + i] * ch[b*DE + i];
    sXT[l*136 + i] = f2bf(v);
  }
  float kr0 = ker[b*4+0], kr1 = ker[b*4+1], kr2 = ker[b*4+2], kr3 = ker[b*4+3];
  float spv[3]; spv[0] = sp[b*4+0]; spv[1] = sp[b*4+1]; spv[2] = sp[b*4+2];
  const float4* od4 = (const float4*)odw;
  for (int p4 = tid; p4 < 128*384/4; p4 += 256){
    float4 w0 = od4[p4];
    float4 w1 = od4[12288 + p4];
    float4 w2 = od4[24576 + p4];
    float4 w3 = od4[36864 + p4];
    float vv[4] = { kr0*w0.x + kr1*w1.x + kr2*w2.x + kr3*w3.x,
                    kr0*w0.y + kr1*w1.y + kr2*w2.y + kr3*w3.y,
                    kr0*w0.z + kr1*w1.z + kr2*w2.z + kr3*w3.z,
                    kr0*w0.w + kr1*w1.w + kr2*w2.w + kr3*w3.w };
    int e0 = p4*4;
    #pragma unroll
    for (int j = 0; j < 4; j++){
      int e = e0 + j;
      int o = e / 384, rem = e - o*384;
      int i = rem / 3, q = rem - i*3;
      sW[(q*128 + o)*136 + i] = f2bf(vv[j] * spv[q]);
    }
  }
  __syncthreads();
  const f4v z4 = {0.f,0.f,0.f,0.f};
  f4v acc[2][8];
  #pragma unroll
  for (int m = 0; m < 2; m++)
    #pragma unroll
    for (int t = 0; t < 8; t++) acc[m][t] = z4;
  const int mBase = wave * 32;
  for (int q = 0; q < 3; q++){
    const u16* wq = sW + q*128*136;
    #pragma unroll
    for (int ks = 0; ks < 4; ks++){
      s8v a0 = *reinterpret_cast<const s8v*>(wq + (mBase + l15)*136 + ks*32 + quad*8);
      s8v a1 = *reinterpret_cast<const s8v*>(wq + (mBase + 16 + l15)*136 + ks*32 + quad*8);
      #pragma unroll
      for (int t = 0; t < 8; t++){
        s8v bfr = *reinterpret_cast<const s8v*>(sXT + (t*16 + l15 + q)*136 + ks*32 + quad*8);
        acc[0][t] = __builtin_amdgcn_mfma_f32_16x16x32_bf16(a0, bfr, acc[0][t], 0, 0, 0);
        acc[1][t] = __builtin_amdgcn_mfma_f32_16x16x32_bf16(a1, bfr, acc[1][t], 0, 0, 0);
      }
    }
  }
  #pragma unroll
  for (int t = 0; t < 8; t++){
    int tt = t*16 + l15;
    if (tt < DM){
      #pragma unroll
      for (int m = 0; m < 2; m++){
        #pragma unroll
        for (int r = 0; r < 4; r++){
          int o = mBase + m*16 + quad*4 + r;
          xout[((size_t)b*DE + o)*DM + tt] = fil[b*DE + o] * acc[m][t][r];
        }
      }
    }
  }
}

// ---------------- QKV + O weights -> bf16 [n][k] + qkv bias ----------------
__global__ __launch_bounds__(256) void k_wqkv(fp qw, fp qb, fp kw, fp kb, fp vw, fp vb,
                                              fp ow, int layer, u16* wq, float* qbias, u16* wo){
  int i = blockIdx.x*256 + threadIdx.x;
  if (i < 384*128){
    int n = i >> 7, k = i & 127;
    int sec = n >> 7, nn = n & 127;
    const float* w = (sec == 0) ? qw : ((sec == 1) ? kw : vw);
    float v = (nn < DM && k < DM) ? w[((size_t)layer*DM + k)*DM + nn] : 0.f;
    wq[(size_t)n*128 + k] = f2bf(v);
  } else if (i < 384*128 + 384){
    int n = i - 384*128;
    int sec = n >> 7, nn = n & 127;
    const float* bp = (sec == 0) ? qb : ((sec == 1) ? kb : vb);
    qbias[n] = (nn < DM) ? bp[layer*DM + nn] : 0.f;
  } else if (i < 384*128 + 384 + 128*128){
    int j = i - (384*128 + 384);
    int n = j >> 7, k = j & 127;
    float v = (n < DM && k < DM) ? ow[(size_t)layer*DM*DM + k*DM + n] : 0.f;
    wo[(size_t)n*128 + k] = f2bf(v);
  }
}

// ---------------- fused QKV GEMM: qkv[M][384] ----------------
__global__ __launch_bounds__(256) void k_qkv_mfma(const float* xin, const u16* wqkv,
                                                  const float* qkvb, float* qkv){
  __shared__ __align__(16) u16 sX[64*136];
  const int tid = threadIdx.x;
  const int wave = tid >> 6, lane = tid & 63, quad = lane >> 4, l15 = lane & 15;
  const size_t rows0 = (size_t)blockIdx.x * 64;
  for (int p = tid; p < 64*128; p += 256){
    int r = p >> 7, c = p & 127;
    float v = (c < DM) ? xin[(rows0 + r)*DM + c] : 0.f;
    sX[r*136 + c] = f2bf(v);
  }
  __syncthreads();
  const f4v z4 = {0.f,0.f,0.f,0.f};
  f4v acc[24];
  #pragma unroll
  for (int t = 0; t < 24; t++) acc[t] = z4;
  const int m0 = wave * 16;
  #pragma unroll
  for (int ks = 0; ks < 4; ks++){
    s8v a = *reinterpret_cast<const s8v*>(sX + (m0 + l15)*136 + ks*32 + quad*8);
    const u16* wb = wqkv + (size_t)l15*128 + ks*32 + quad*8;
    #pragma unroll
    for (int t = 0; t < 24; t++){
      s8v b = *reinterpret_cast<const s8v*>(wb + (size_t)t*16*128);
      acc[t] = __builtin_amdgcn_mfma_f32_16x16x32_bf16(a, b, acc[t], 0, 0, 0);
    }
  }
  #pragma unroll
  for (int t = 0; t < 24; t++){
    int col = t*16 + l15;
    float bv = qkvb[col];
    #pragma unroll
    for (int r = 0; r < 4; r++){
      int row = m0 + quad*4 + r;
      qkv[(rows0 + row)*384 + col] = acc[t][r] + bv;
    }
  }
}

// ---------------- fused sparse attention: one wave per (b,h), shuffle reductions ----------------
// slice (u16): sK f32 [L*21] @0 (5376) | sM f32 [128] @5376 (256) | VT bf16 [32][136] @5632 | Pb bf16 [32][136] @9984
#define ATT_SLICE 14336

__global__ __launch_bounds__(256) void k_attn_fused(const float* qkv, const int* idx, int L,
                                                    float* vmean, int* posmap, float* upd){
  __shared__ __align__(16) u16 smem[4*ATT_SLICE];   // 114,688 B
  const int tid = threadIdx.x;
  const int wave = tid >> 6, lane = tid & 63, quad = lane >> 4, l15 = lane & 15;
  const int bh = blockIdx.x*4 + wave;
  const int b = bh / NH, h = bh - b*NH;
  u16* slice = smem + wave*ATT_SLICE;
  float* sK = (float*)slice;
  float* sM = (float*)(slice + 5376);
  u16*  sVT = slice + 5632;
  u16*  sPb = slice + 9984;

  const float* qbase = qkv + (size_t)(b*L)*384 + h*DHd;

  // stage K (f32) + V (bf16, transposed)
  for (int p = lane; p < L*DHd; p += 64){
    int l = p / DHd, d = p - l*DHd;
    const float* rowp = qbase + (size_t)l*384;
    sK[p] = rowp[128 + d];
    sVT[d*136 + l] = f2bf(rowp[256 + d]);
  }
  posmap[bh*L0 + lane] = -1;
  if (L == 128) posmap[bh*L0 + 64 + lane] = -1;
  __syncthreads();

  // vmean (from bf16 V)
  if (lane < DHd){
    float s = 0.f;
    for (int l = 0; l < L; l++) s += bf2f(sVT[lane*136 + l]);
    vmean[bh*DHd + lane] = s / (float)L;
  }

  // phase 1: sparsity measure M (f32, same math as passing version)
  int nr = (L == 128) ? 2 : 1;
  for (int rr = 0; rr < nr; rr++){
    int l = lane + rr*64;
    const float* qg = qbase + (size_t)l*384;
    float qr[DHd];
    #pragma unroll
    for (int d = 0; d < DHd; d++) qr[d] = qg[d];
    int kks[NTOP];
    #pragma unroll
    for (int u = 0; u < NTOP; u++) kks[u] = idx[l*NTOP + u];
    float mx = -1e30f, sm = 0.f;
    #pragma unroll
    for (int u = 0; u < NTOP; u++){
      const float* kp = sK + kks[u]*DHd;
      float acc = 0.f;
      #pragma unroll
      for (int d = 0; d < DHd; d++) acc += qr[d]*kp[d];
      mx = fmaxf(mx, acc); sm += acc;
    }
    sM[l] = mx - sm/(float)L;
  }
  __syncthreads();

  // top-k (ties -> smaller index) fused with per-row softmax
  const float inv21 = 0.21821789023599236f;   // 1/sqrt(21)
  for (int it = 0; it < NTOP; it++){
    float bv = sM[lane]; int bi = lane;
    if (L == 128){
      float v1 = sM[lane + 64];
      if (v1 > bv){ bv = v1; bi = lane + 64; }
    }
    #pragma unroll
    for (int off = 32; off > 0; off >>= 1){
      float ov = __shfl_xor(bv, off);
      int   oi = __shfl_xor(bi, off);
      if (ov > bv || (ov == bv && oi < bi)){ bv = ov; bi = oi; }
    }
    int r = bi;
    if (lane == 0){ sM[r] = -1e30f; posmap[bh*L0 + r] = it; }
    const float* qg = qbase + (size_t)r*384;
    float qr[DHd];
    #pragma unroll
    for (int d = 0; d < DHd; d++) qr[d] = qg[d];
    float s0, s1;
    {
      const float* kp = sK + lane*DHd;
      float a = 0.f;
      #pragma unroll
      for (int d = 0; d < DHd; d++) a += qr[d]*kp[d];
      s0 = a * inv21;
    }
    if (L == 128){
      const float* kp = sK + (lane+64)*DHd;
      float a = 0.f;
      #pragma unroll
      for (int d = 0; d < DHd; d++) a += qr[d]*kp[d];
      s1 = a * inv21;
    } else {
      s1 = -1e30f;
    }
    float mx = fmaxf(s0, s1);
    #pragma unroll
    for (int off = 32; off > 0; off >>= 1) mx = fmaxf(mx, __shfl_xor(mx, off));
    float e0 = expf(s0 - mx);
    float e1 = (L == 128) ? expf(s1 - mx) : 0.f;
    float ss = e0 + e1;
    #pragma unroll
    for (int off = 32; off > 0; off >>= 1) ss += __shfl_xor(ss, off);
    float dn = 1.f / ss;
    sPb[it*136 + lane] = f2bf(e0*dn);
    if (L == 128) sPb[it*136 + 64 + lane] = f2bf(e1*dn);
    __syncthreads();   // orders sM update for next iteration (uniform count)
  }

  // ctx = P @ V via MFMA (per-wave); garbage pad rows only hit discarded C rows/cols
  const f4v z4 = {0.f,0.f,0.f,0.f};
  f4v acc[2][2];
  acc[0][0]=z4; acc[0][1]=z4; acc[1][0]=z4; acc[1][1]=z4;
  int kSteps = L >> 5;
  for (int ks = 0; ks < kSteps; ks++){
    #pragma unroll
    for (int mt = 0; mt < 2; mt++){
      s8v a = *reinterpret_cast<const s8v*>(sPb + (mt*16 + l15)*136 + ks*32 + quad*8);
      #pragma unroll
      for (int nt = 0; nt < 2; nt++){
        s8v bb = *reinterpret_cast<const s8v*>(sVT + (nt*16 + l15)*136 + ks*32 + quad*8);
        acc[mt][nt] = __builtin_amdgcn_mfma_f32_16x16x32_bf16(a, bb, acc[mt][nt], 0, 0, 0);
      }
    }
  }
  #pragma unroll
  for (int mt = 0; mt < 2; mt++){
    #pragma unroll
    for (int nt = 0; nt < 2; nt++){
      #pragma unroll
      for (int r4 = 0; r4 < 4; r4++){
        int u = mt*16 + quad*4 + r4;
        int d = nt*16 + l15;
        if (u < NTOP && d < DHd)
          upd[((size_t)bh*NTOP + u)*DHd + d] = acc[mt][nt][r4];
      }
    }
  }
}

// ---------------- MFMA O-proj + residual + LN1 (64 rows / block) ----------------
__global__ __launch_bounds__(256) void k_oproj_mfma(const float* xin, const float* vmean,
                                                    const int* posmap, const float* upd,
                                                    const u16* wo, fp ob, fp g, fp bb,
                                                    int layer, int lshift, int lmask, float* xmid){
  __shared__ __align__(16) float sOf[64*129];
  __shared__ float prs[128];
  __shared__ float smean[64], srstd[64];
  u16* sX = reinterpret_cast<u16*>(sOf);
  const int tid = threadIdx.x;
  const int wave = tid >> 6, lane = tid & 63, quad = lane >> 4, l15 = lane & 15;
  const int m0 = wave * 16;
  const size_t rows0 = (size_t)blockIdx.x * 64;
  for (int p = tid; p < 64*128; p += 256){
    int r = p >> 7, c = p & 127;
    int gr = (int)rows0 + r, b = gr >> lshift, l = gr & lmask;
    float v = 0.f;
    if (c < DM){
      int h = c / DHd, d = c - h*DHd;
      int bh = b*NH + h;
      int pos = posmap[bh*L0 + l];
      v = (pos >= 0) ? upd[((size_t)bh*NTOP + pos)*DHd + d] : vmean[bh*DHd + d];
    }
    sX[r*136 + c] = f2bf(v);
  }
  __syncthreads();
  const f4v z4 = {0.f,0.f,0.f,0.f};
  f4v acc[8];
  #pragma unroll
  for (int t = 0; t < 8; t++) acc[t] = z4;
  #pragma unroll
  for (int ks = 0; ks < 4; ks++){
    s8v a = *reinterpret_cast<const s8v*>(sX + (m0 + l15)*136 + ks*32 + quad*8);
    const u16* wb = wo + (size_t)l15*128 + ks*32 + quad*8;
    #pragma unroll
    for (int t = 0; t < 8; t++){
      s8v b = *reinterpret_cast<const s8v*>(wb + (size_t)t*16*128);
      acc[t] = __builtin_amdgcn_mfma_f32_16x16x32_bf16(a, b, acc[t], 0, 0, 0);
    }
  }
  __syncthreads();
  #pragma unroll
  for (int t = 0; t < 8; t++){
    int col = t*16 + l15;
    #pragma unroll
    for (int r = 0; r < 4; r++){
      sOf[(m0 + quad*4 + r)*129 + col] = acc[t][r];
    }
  }
  __syncthreads();
  const float* obl = ob + (size_t)layer*DM;
  for (int p = tid; p < 64*DM; p += 256){
    int r = p / DM, c = p - r*DM;
    sOf[r*129 + c] += xin[(rows0 + r)*DM + c] + obl[c];
  }
  __syncthreads();
  if (tid < 128){
    int row = tid >> 1, half = tid & 1;
    float s = 0.f;
    for (int c = half*63; c < half*63 + 63; c++) s += sOf[row*129 + c];
    prs[tid] = s;
  }
  __syncthreads();
  if (tid < 128 && (tid & 1) == 0) smean[tid>>1] = (prs[tid] + prs[tid+1]) / (float)DM;
  __syncthreads();
  if (tid < 128){
    int row = tid >> 1, half = tid & 1;
    float mn = smean[row];
    float s = 0.f;
    for (int c = half*63; c < half*63 + 63; c++){ float d = sOf[row*129 + c] - mn; s += d*d; }
    prs[tid] = s;
  }
  __syncthreads();
  if (tid < 128 && (tid & 1) == 0) srstd[tid>>1] = rsqrtf((prs[tid] + prs[tid+1])/(float)DM + 1e-5f);
  __syncthreads();
  const float* gl = g  + (size_t)layer*DM;
  const float* bl = bb + (size_t)layer*DM;
  for (int p = tid; p < 64*DM; p += 256){
    int r = p / DM, c = p - r*DM;
    xmid[(rows0 + r)*DM + c] = (sOf[r*129 + c] - smean[r])*srstd[r]*gl[c] + bl[c];
  }
}

// ---------------- FFN weights conversion ----------------
__global__ __launch_bounds__(256) void k_wconv(fp w1, fp w2, int layer, u16* w1t, u16* w2t){
  int i = blockIdx.x*256 + threadIdx.x;
  if (i < 2048*128){
    int n = i >> 7, k = i & 127;
    float v = (k < DM) ? w1[((size_t)layer*DM + k)*DFF + n] : 0.f;
    w1t[(size_t)n*128 + k] = f2bf(v);
  } else {
    int j = i - 2048*128;
    int n = j >> 11, f = j & 2047;
    float v = (n < DM) ? w2[((size_t)layer*DFF + f)*DM + n] : 0.f;
    w2t[(size_t)n*2048 + f] = f2bf(v);
  }
}

// GELU exact via Abramowitz-Stegun 7.1.26 erf (max err ~1.5e-7)
__device__ __forceinline__ float gelu_as(float x){
  float z  = 0.7071067811865475f * x;
  float zn = fabsf(z);
  float t  = 1.f / (1.f + 0.3275911f * zn);
  float p  = ((((1.061405429f*t - 1.453152027f)*t + 1.421413741f)*t - 0.284496736f)*t + 0.254829592f)*t;
  float ea = 1.f - p * __expf(-zn*zn);
  float er = (z < 0.f) ? -ea : ea;
  return 0.5f * x * (1.f + er);
}

// ---------------- MFMA FFN + residual + LN2 — LDS-pipelined weights ----------------
#define FFN_SMEM_U16 (8704 + 4608 + 3*8192)

__device__ __forceinline__ void stage_w1(const u16* w1t, int j, u16* buf, int wave, int lane){
  #pragma unroll
  for (int r = 0; r < 4; r++){
    int p = r*256 + wave*64 + lane;
    int n = p >> 4, c = p & 15;
    int cg = c ^ (n & 7);
    const u16* g = w1t + (((size_t)(j*64 + n)) << 7) + cg*8;
    u16* l = buf + (size_t)(r*256 + wave*64)*8;
    gld_lds16(g, l);
  }
}
__device__ __forceinline__ void stage_w2(const u16* w2t, int j, u16* buf, int wave, int lane){
  #pragma unroll
  for (int r = 0; r < 4; r++){
    int p = r*256 + wave*64 + lane;
    int n = p >> 3, c = p & 7;
    int cg = c ^ (n & 7);
    const u16* g = w2t + (size_t)n*2048 + j*64 + cg*8;
    u16* l = buf + (size_t)(r*256 + wave*64)*8;
    gld_lds16(g, l);
  }
}

__global__ __launch_bounds__(256) void k_ffn_mfma(const float* xmid, const u16* w1t, const u16* w2t,
                                                  fp b1, fp b2w, fp g, fp bb, int layer, float* xout){
  __shared__ __align__(16) u16 smem[FFN_SMEM_U16];
  __shared__ float prs[128];
  __shared__ float smean[64], srstd[64];
  u16* sX  = smem;
  u16* wA0 = smem + 8704 + 4608;
  u16* wA1 = wA0 + 8192;
  u16* wBf = wA1 + 8192;
  const int tid  = threadIdx.x;
  const int wave = tid >> 6, lane = tid & 63, quad = lane >> 4, l15 = lane & 15;
  const int m0 = wave * 16;
  u16* sYw = smem + 8704 + wave*1152;
  const size_t rows0 = (size_t)blockIdx.x * 64;

  for (int p = tid; p < 64*128; p += 256){
    int r = p >> 7, c = p & 127;
    float v = (c < DM) ? xmid[(rows0 + r)*DM + c] : 0.f;
    sX[r*136 + c] = f2bf(v);
  }
  stage_w1(w1t, 0, wA0, wave, lane);
  stage_w2(w2t, 0, wBf, wave, lane);
  __syncthreads();

  const float* b1l = b1 + (size_t)layer*DFF;
  const f4v z4 = {0.f, 0.f, 0.f, 0.f};
  f4v acc2[8];
  #pragma unroll
  for (int t = 0; t < 8; t++) acc2[t] = z4;

  for (int j = 0; j < 32; j++){
    u16* wAcur = (j & 1) ? wA1 : wA0;
    u16* wAnext = (j & 1) ? wA0 : wA1;
    if (j < 31) stage_w1(w1t, j+1, wAnext, wave, lane);
    f4v acc1[4];
    #pragma unroll
    for (int t = 0; t < 4; t++) acc1[t] = z4;
    #pragma unroll
    for (int ks = 0; ks < 4; ks++){
      s8v a = *reinterpret_cast<const s8v*>(sX + (m0 + l15)*136 + ks*32 + quad*8);
      #pragma unroll
      for (int t = 0; t < 4; t++){
        int nloc = t*16 + l15;
        int cg = (ks*4 + quad) ^ (nloc & 7);
        s8v b = *reinterpret_cast<const s8v*>(wAcur + nloc*128 + cg*8);
        acc1[t] = __builtin_amdgcn_mfma_f32_16x16x32_bf16(a, b, acc1[t], 0, 0, 0);
      }
    }
    #pragma unroll
    for (int t = 0; t < 4; t++){
      float bv = b1l[j*64 + t*16 + l15];
      #pragma unroll
      for (int r = 0; r < 4; r++){
        float v = gelu_as(acc1[t][r] + bv);
        sYw[(quad*4 + r)*72 + t*16 + l15] = f2bf(v);
      }
    }
    __syncthreads();
    #pragma unroll
    for (int ks = 0; ks < 2; ks++){
      s8v a2 = *reinterpret_cast<const s8v*>(sYw + l15*72 + ks*32 + quad*8);
      #pragma unroll
      for (int t = 0; t < 8; t++){
        int nloc = t*16 + l15;
        int cg = (ks*4 + quad) ^ (nloc & 7);
        s8v b = *reinterpret_cast<const s8v*>(wBf + nloc*64 + cg*8);
        acc2[t] = __builtin_amdgcn_mfma_f32_16x16x32_bf16(a2, b, acc2[t], 0, 0, 0);
      }
    }
    __syncthreads();
    if (j < 31) stage_w2(w2t, j+1, wBf, wave, lane);
  }

  float* sO = reinterpret_cast<float*>(smem);
  #pragma unroll
  for (int t = 0; t < 8; t++){
    int col = t*16 + l15;
    #pragma unroll
    for (int r = 0; r < 4; r++){
      sO[(m0 + quad*4 + r)*129 + col] = acc2[t][r];
    }
  }
  __syncthreads();
  const float* b2l = b2w + (size_t)layer*DM;
  for (int p = tid; p < 64*DM; p += 256){
    int r = p / DM, c = p - r*DM;
    sO[r*129 + c] += b2l[c] + xmid[(rows0 + r)*DM + c];
  }
  __syncthreads();
  if (tid < 128){
    int row = tid >> 1, half = tid & 1;
    float s = 0.f;
    for (int c = half*63; c < half*63 + 63; c++) s += sO[row*129 + c];
    prs[tid] = s;
  }
  __syncthreads();
  if (tid < 128 && (tid & 1) == 0) smean[tid>>1] = (prs[tid] + prs[tid+1]) / (float)DM;
  __syncthreads();
  if (tid < 128){
    int row = tid >> 1, half = tid & 1;
    float mn = smean[row];
    float s = 0.f;
    for (int c = half*63; c < half*63 + 63; c++){ float d = sO[row*129 + c] - mn; s += d*d; }
    prs[tid] = s;
  }
  __syncthreads();
  if (tid < 128 && (tid & 1) == 0) srstd[tid>>1] = rsqrtf((prs[tid] + prs[tid+1])/(float)DM + 1e-5f);
  __syncthreads();
  const float* gl = g  + (size_t)layer*DM;
  const float* bl = bb + (size_t)layer*DM;
  for (int p = tid; p < 64*DM; p += 256){
    int r = p / DM, c = p - r*DM;
    xout[(rows0 + r)*DM + c] = (sO[r*129 + c] - smean[r])*srstd[r]*gl[c] + bl[c];
  }
}

// ---------------- distil weights -> bf16 [n=co][k=q*126+ci] ----------------
__global__ __launch_bounds__(256) void k_wdist(fp clw, u16* wd){
  int i = blockIdx.x*256 + threadIdx.x;
  if (i < 128*384){
    int n = i / 384, k = i - n*384;
    float v = 0.f;
    if (n < DM && k < 378){
      int q = k / 126, ci = k - q*126;
      v = clw[((size_t)n*DM + ci)*3 + q];
    }
    wd[i] = f2bf(v);
  }
}

// ---------------- MFMA distil: conv(K=378) + BN + ELU + maxpool ----------------
__global__ __launch_bounds__(256) void k_distill_mfma(const float* xin, const u16* wdist,
                                                      fp clb, fp bng, fp bnb, float* xout){
  __shared__ __align__(16) u16 sA[128*392];
  const int tid = threadIdx.x;
  const int wave = tid >> 6, lane = tid & 63, quad = lane >> 4, l15 = lane & 15;
  const int b = blockIdx.x;
  for (int row = wave; row < 128; row += 4){
    #pragma unroll
    for (int e = 0; e < 6; e++){
      int kk = lane + e*64;
      float v = 0.f;
      if (kk < 378){
        int q = kk / 126, ci = kk - q*126;
        int sr = (row - 1 + q + 128) & 127;
        v = xin[((size_t)b*128 + sr)*DM + ci];
      }
      sA[row*392 + kk] = f2bf(v);
    }
  }
  __syncthreads();
  const f4v z4 = {0.f,0.f,0.f,0.f};
  f4v acc[2][8];
  #pragma unroll
  for (int m = 0; m < 2; m++)
    #pragma unroll
    for (int t = 0; t < 8; t++) acc[m][t] = z4;
  const int mBase = wave * 32;
  for (int ks = 0; ks < 12; ks++){
    s8v a0 = *reinterpret_cast<const s8v*>(sA + (mBase + l15)*392 + ks*32 + quad*8);
    s8v a1 = *reinterpret_cast<const s8v*>(sA + (mBase + 16 + l15)*392 + ks*32 + quad*8);
    const u16* wb = wdist + (size_t)l15*384 + ks*32 + quad*8;
    #pragma unroll
    for (int t = 0; t < 8; t++){
      s8v bfr = *reinterpret_cast<const s8v*>(wb + (size_t)t*16*384);
      acc[0][t] = __builtin_amdgcn_mfma_f32_16x16x32_bf16(a0, bfr, acc[0][t], 0, 0, 0);
      acc[1][t] = __builtin_amdgcn_mfma_f32_16x16x32_bf16(a1, bfr, acc[1][t], 0, 0, 0);
    }
  }
  __syncthreads();
  float* zsh = reinterpret_cast<float*>(sA);   // [128][130]
  const float bnscale = 1.f / sqrtf(1.f + 1e-5f);
  #pragma unroll
  for (int t = 0; t < 8; t++){
    int co = t*16 + l15;
    if (co < DM){
      float cb = clb[co];
      float gg = bng[co] * bnscale, bv = bnb[co];
      #pragma unroll
      for (int m = 0; m < 2; m++){
        #pragma unroll
        for (int r = 0; r < 4; r++){
          int row = mBase + m*16 + quad*4 + r;
          float z = (acc[m][t][r] + cb)*gg + bv;
          z = (z > 0.f) ? z : expm1f(z);
          zsh[row*130 + co] = z;
        }
      }
    }
  }
  __syncthreads();
  for (int p = tid; p < 64*DM; p += 256){
    int j = p / DM, co = p - j*DM;
    float best = zsh[(2*j)*130 + co];
    if (j > 0) best = fmaxf(best, zsh[(2*j - 1)*130 + co]);
    best = fmaxf(best, zsh[(2*j + 1)*130 + co]);
    xout[((size_t)b*64 + j)*DM + co] = best;
  }
}

// ---------------- final LN + fc ----------------
__global__ __launch_bounds__(128) void k_final(const float* xin, fp g, fp bb,
                                               fp fcw, fp fcb, float* out){
  __shared__ float xs[64][DM];
  __shared__ float mean_s[64], rstd_s[64];
  int b = blockIdx.x, t = threadIdx.x;
  for (int p = t; p < 64*DM; p += 128){ xs[p/DM][p%DM] = xin[(size_t)b*64*DM + p]; }
  __syncthreads();
  if (t < 64){
    float s = 0.f;
    for (int m = 0; m < DM; m++) s += xs[t][m];
    float mn = s / (float)DM;
    float v = 0.f;
    for (int m = 0; m < DM; m++){ float d = xs[t][m] - mn; v += d*d; }
    mean_s[t] = mn; rstd_s[t] = rsqrtf(v / (float)DM + 1e-5f);
  }
  __syncthreads();
  if (t < DM){
    float gv = g[t], bv = bb[t];
    float acc = fcb[0];
    for (int l = 0; l < 64; l++){
      float xn = (xs[l][t] - mean_s[l])*rstd_s[l]*gv + bv;
      acc += xn * fcw[l];
    }
    out[b*DM + t] = acc;
  }
}

// ---------------- host launcher ----------------
extern "C" void kernel_launch(void* const* d_in, const int* in_sizes, int n_in,
                              void* d_out, int out_size, void* d_ws, size_t ws_size,
                              hipStream_t stream) {
  fp x_enc   = (fp)d_in[0];
  fp x_mark  = (fp)d_in[1];
  fp token_w = (fp)d_in[2];
  fp time_w  = (fp)d_in[3];
  fp time_b  = (fp)d_in[4];
  fp od_fc_w = (fp)d_in[5];
  fp od_bn_g = (fp)d_in[6];
  fp od_bn_b = (fp)d_in[7];
  fp od_ch_w = (fp)d_in[8];
  fp od_ch_b = (fp)d_in[9];
  fp od_fil_w= (fp)d_in[10];
  fp od_fil_b= (fp)d_in[11];
  fp od_sp_w = (fp)d_in[12];
  fp od_sp_b = (fp)d_in[13];
  fp od_ker_w= (fp)d_in[14];
  fp od_ker_b= (fp)d_in[15];
  fp od_wt   = (fp)d_in[16];
  fp q_w = (fp)d_in[17]; fp q_b = (fp)d_in[18];
  fp k_w = (fp)d_in[19]; fp k_b = (fp)d_in[20];
  fp v_w = (fp)d_in[21]; fp v_b = (fp)d_in[22];
  fp o_w = (fp)d_in[23]; fp o_b = (fp)d_in[24];
  fp f1w = (fp)d_in[25]; fp f1b = (fp)d_in[26];
  fp f2w = (fp)d_in[27]; fp f2b = (fp)d_in[28];
  fp ln1g= (fp)d_in[29]; fp ln1b= (fp)d_in[30];
  fp ln2g= (fp)d_in[31]; fp ln2b= (fp)d_in[32];
  fp cl_w= (fp)d_in[33]; fp cl_b= (fp)d_in[34];
  fp clbg= (fp)d_in[35]; fp clbb= (fp)d_in[36];
  fp elng= (fp)d_in[37]; fp elnb= (fp)d_in[38];
  fp fc_w= (fp)d_in[39]; fp fc_b= (fp)d_in[40];

  // ---- workspace layout (float units) ----
  const size_t OFF_IDX0 = 0;
  const size_t OFF_IDX1 = OFF_IDX0 + 3200;
  const size_t OFF_CH   = OFF_IDX1 + 1600;
  const size_t OFF_FIL  = OFF_CH  + (size_t)NB*DE;
  const size_t OFF_SP   = OFF_FIL + (size_t)NB*DE;
  const size_t OFF_KER  = OFF_SP  + (size_t)NB*4;
  const size_t OFF_VM   = OFF_KER + (size_t)NB*4;
  const size_t OFF_POS  = OFF_VM  + (size_t)NB*NH*DHd;
  const size_t OFF_UPD  = OFF_POS + (size_t)NB*NH*L0;
  const size_t OFF_WTS  = (OFF_UPD + (size_t)NB*NH*NTOP*DHd + 255) & ~(size_t)255;
  const size_t WTS_FLOATS = (262144 + 262144 + 49152 + 49152 + 16384 + 32768)/2 + 384;
  const size_t OFF_BIG  = (OFF_WTS + WTS_FLOATS + 255) & ~(size_t)255;
  const size_t SBUF     = (size_t)NB*DE*L0;
  const size_t TOTAL    = OFF_BIG + 4*SBUF;

  if (ws_size < TOTAL*sizeof(float)){
    hipLaunchKernelGGL(k_zero, dim3((out_size+255)/256), dim3(256), 0, stream,
                       (float*)d_out, out_size);
    return;
  }

  float* ws = (float*)d_ws;
  int* idx0 = (int*)(ws + OFF_IDX0);
  int* idx1 = (int*)(ws + OFF_IDX1);
  float* chv = ws + OFF_CH;
  float* filv= ws + OFF_FIL;
  float* spv = ws + OFF_SP;
  float* kerv= ws + OFF_KER;
  float* vme = ws + OFF_VM;
  int* posm  = (int*)(ws + OFF_POS);
  float* updb= ws + OFF_UPD;
  u16* w1tb  = (u16*)(ws + OFF_WTS);
  u16* w2tb  = w1tb + 262144;
  u16* wqkvb = w2tb + 262144;
  u16* wdistb= wqkvb + 49152;
  u16* wob   = wdistb + 49152;
  u16* wembb = wob + 16384;
  float* qkvbias = (float*)(wembb + 32768);

  float* X    = ws + OFF_BIG;
  float* QKV  = X + SBUF;
  float* emb  = QKV;
  float* xmid = QKV;
  float* ffno = QKV + SBUF;

  hipLaunchKernelGGL(k_idx, dim3(1), dim3(256), 0, stream, idx0, idx1);
  hipLaunchKernelGGL(k_wemb, dim3(128), dim3(256), 0, stream, token_w, wembb);
  hipLaunchKernelGGL(k_emb_mfma, dim3(NB), dim3(256), 0, stream,
                     x_enc, x_mark, wembb, time_w, time_b, emb);
  hipLaunchKernelGGL(k_scalars, dim3(NB), dim3(128), 0, stream,
                     emb, od_fc_w, od_bn_g, od_bn_b, od_ch_w, od_ch_b, od_fil_w, od_fil_b,
                     od_sp_w, od_sp_b, od_ker_w, od_ker_b, chv, filv, spv, kerv);
  hipLaunchKernelGGL(k_odconv_mfma, dim3(NB), dim3(256), 0, stream,
                     emb, od_wt, chv, filv, spv, kerv, X);
  hipLaunchKernelGGL(k_wdist, dim3(192), dim3(256), 0, stream, cl_w, wdistb);

  // ----- layer 0 (L=128) -----
  hipLaunchKernelGGL(k_wqkv, dim3(258), dim3(256), 0, stream,
                     q_w, q_b, k_w, k_b, v_w, v_b, o_w, 0, wqkvb, qkvbias, wob);
  hipLaunchKernelGGL(k_qkv_mfma, dim3(NB*L0/64), dim3(256), 0, stream,
                     X, wqkvb, qkvbias, QKV);
  hipLaunchKernelGGL(k_attn_fused, dim3(NB*NH/4), dim3(256), 0, stream,
                     QKV, idx0, L0, vme, posm, updb);
  hipLaunchKernelGGL(k_oproj_mfma, dim3(NB*L0/64), dim3(256), 0, stream,
                     X, vme, posm, updb, wob, o_b, ln1g, ln1b, 0, 7, 127, xmid);
  hipLaunchKernelGGL(k_wconv, dim3(2048), dim3(256), 0, stream, f1w, f2w, 0, w1tb, w2tb);
  hipLaunchKernelGGL(k_ffn_mfma, dim3(NB*L0/64), dim3(256), 0, stream,
                     xmid, w1tb, w2tb, f1b, f2b, ln2g, ln2b, 0, ffno);

  // ----- distil -----
  hipLaunchKernelGGL(k_distill_mfma, dim3(NB), dim3(256), 0, stream,
                     ffno, wdistb, cl_b, clbg, clbb, X);

  // ----- layer 1 (L=64) -----
  hipLaunchKernelGGL(k_wqkv, dim3(258), dim3(256), 0, stream,
                     q_w, q_b, k_w, k_b, v_w, v_b, o_w, 1, wqkvb, qkvbias, wob);
  hipLaunchKernelGGL(k_qkv_mfma, dim3(NB*64/64), dim3(256), 0, stream,
                     X, wqkvb, qkvbias, QKV);
  hipLaunchKernelGGL(k_attn_fused, dim3(NB*NH/4), dim3(256), 0, stream,
                     QKV, idx1, 64, vme, posm, updb);
  hipLaunchKernelGGL(k_oproj_mfma, dim3(NB*64/64), dim3(256), 0, stream,
                     X, vme, posm, updb, wob, o_b, ln1g, ln1b, 1, 6, 63, xmid);
  hipLaunchKernelGGL(k_wconv, dim3(2048), dim3(256), 0, stream, f1w, f2w, 1, w1tb, w2tb);
  hipLaunchKernelGGL(k_ffn_mfma, dim3(NB*64/64), dim3(256), 0, stream,
                     xmid, w1tb, w2tb, f1b, f2b, ln2g, ln2b, 1, ffno);

  hipLaunchKernelGGL(k_final, dim3(NB), dim3(128), 0, stream,
                     ffno, elng, elnb, fc_w, fc_b, (float*)d_out);
  (void)in_sizes; (void)n_in; (void)out_size; (void)ws_size;
}